// Round 6
// baseline (5759.681 us; speedup 1.0000x reference)
//
#include <hip/hip_runtime.h>
#include <hip/hip_bf16.h>

#define NTOK 32768
#define TSEQ 4096
#define DM   1024
#define NHEAD 16
#define NEXP 8
#define CAPE 5120
#define HIDN 4096
#define GTOK 8192         // tokens per batch-group (2 sequences)
#define KSPL 5120         // split-GEMM K (3*1024 + 2*1024)

#ifndef __has_builtin
#define __has_builtin(x) 0
#endif
#if __has_builtin(__builtin_amdgcn_global_load_lds)
#define HAVE_GLOAD 1
#else
#define HAVE_GLOAD 0
#endif

typedef __attribute__((ext_vector_type(8))) short bf16x8;
typedef __attribute__((ext_vector_type(4))) float f32x4;

__device__ __forceinline__ float phi_f(float v) { return v > 0.f ? v + 1.f : expf(v); }

__device__ __forceinline__ unsigned short f2bf_bits(float f) {
    __hip_bfloat16 h = __float2bfloat16(f);
    union { __hip_bfloat16 h; unsigned short s; } u;
    u.h = h;
    return u.s;
}
__device__ __forceinline__ float bf_to_f(unsigned short s) {
    unsigned int u = ((unsigned int)s) << 16;
    union { unsigned int u; float f; } w; w.u = u;
    return w.f;
}

__global__ void k_ws_flag(float* out, float v) { if (threadIdx.x == 0) out[0] = v; }

__global__ void k_zero(int* p, int n) {
    int i = blockIdx.x * 256 + threadIdx.x;
    if (i < n) p[i] = 0;
}

// ---------------- rope table ----------------
__global__ __launch_bounds__(256) void k_rope_table(float* __restrict__ ct, float* __restrict__ st)
{
    const int idx = blockIdx.x * 256 + threadIdx.x;
    const int t = idx >> 5, j = idx & 31;
    const float inv = (float)(1.0 / pow(10000.0, (double)j / 32.0));
    float sn, cn;
    sincosf((float)t * inv, &sn, &cn);
    ct[idx] = cn; st[idx] = sn;
}

// ---------------- build W stacks: BT[n, k] bf16, k-> (seg, d); seg<3: w0, else w1 ----------------
struct WPack { const float* W[5]; };
__global__ __launch_bounds__(256) void k_build_wstack(WPack P, __hip_bfloat16* __restrict__ BTbase)
{
    __shared__ float t_[32][33];
    const int z = blockIdx.z;
    const float* Wm = P.W[z];
    __hip_bfloat16* BT = BTbase + (size_t)z * DM * KSPL;
    const int n0 = blockIdx.x * 32, k0 = blockIdx.y * 32;
    const int c = threadIdx.x & 31, r0 = (threadIdx.x >> 5);   // 32 x 8
#pragma unroll
    for (int i = 0; i < 4; ++i) { int r = r0 + i * 8; t_[r][c] = Wm[(size_t)(k0 + r) * DM + n0 + c]; }
    __syncthreads();
#pragma unroll
    for (int i = 0; i < 4; ++i) {
        int r = r0 + i * 8;                       // local n
        float val = t_[c][r];                     // W[k0+c][n0+r]
        unsigned short b0 = f2bf_bits(val);
        float res = val - bf_to_f(b0);
        unsigned short b1 = f2bf_bits(res);
        __hip_bfloat16 h0, h1;
        union { __hip_bfloat16 h; unsigned short s; } u0, u1;
        u0.s = b0; u1.s = b1; h0 = u0.h; h1 = u1.h;
        const size_t nrow = (size_t)(n0 + r) * KSPL + (k0 + c);
        BT[nrow]            = h0;
        BT[nrow + 1024]     = h0;
        BT[nrow + 2048]     = h0;
        BT[nrow + 3072]     = h1;
        BT[nrow + 4096]     = h1;
    }
}

// ---------------- split rows into 3 bf16 planes (rmsnorm-scaled) ----------------
template<bool NORM>
__global__ __launch_bounds__(256) void k_rms_split(const float* __restrict__ X,
                                                   const float* __restrict__ nscale,
                                                   __hip_bfloat16* __restrict__ Xs)
{
    const int row = blockIdx.x;
    const int tid = threadIdx.x;
    const float* xr = X + (size_t)row * DM;
    float4 v = ((const float4*)xr)[tid];
    float r = 1.f;
    if (NORM) {
        float s = v.x * v.x + v.y * v.y + v.z * v.z + v.w * v.w;
        for (int off = 32; off; off >>= 1) s += __shfl_xor(s, off);
        __shared__ float redw[4];
        __shared__ float rbc;
        if ((tid & 63) == 0) redw[tid >> 6] = s;
        __syncthreads();
        if (tid == 0) {
            float tot = redw[0] + redw[1] + redw[2] + redw[3];
            rbc = (float)(1.0 / sqrt((double)tot * (1.0 / 1024.0)));
        }
        __syncthreads();
        r = rbc;
    }
    float c[4] = {v.x, v.y, v.z, v.w};
    if (NORM) {
        float4 ns = ((const float4*)nscale)[tid];
        c[0] *= r * ns.x; c[1] *= r * ns.y; c[2] *= r * ns.z; c[3] *= r * ns.w;
    }
    ushort4 p0, p1, p2;
    unsigned short* q0 = (unsigned short*)&p0;
    unsigned short* q1 = (unsigned short*)&p1;
    unsigned short* q2 = (unsigned short*)&p2;
#pragma unroll
    for (int i = 0; i < 4; ++i) {
        float x = c[i];
        unsigned short b0 = f2bf_bits(x);
        float r1 = x - bf_to_f(b0);
        unsigned short b1 = f2bf_bits(r1);
        float r2 = r1 - bf_to_f(b1);
        unsigned short b2 = f2bf_bits(r2);
        q0[i] = b0; q1[i] = b1; q2[i] = b2;
    }
    __hip_bfloat16* base = Xs + (size_t)row * 3072;
    ((ushort4*)(base))[tid] = p0;
    ((ushort4*)(base + 1024))[tid] = p1;
    ((ushort4*)(base + 2048))[tid] = p2;
}

// ---------------- rmsnorm stats + bf16 normalized rows ----------------
__global__ __launch_bounds__(256) void k_rmsnorm_stats(const float* __restrict__ X,
                                                       float* __restrict__ rn,
                                                       const float* __restrict__ nscale,
                                                       __hip_bfloat16* __restrict__ xbf)
{
    const int row = blockIdx.x;
    const int tid = threadIdx.x;
    const float* xr = X + (size_t)row * DM;
    float4 v = ((const float4*)xr)[tid];
    float s = v.x * v.x + v.y * v.y + v.z * v.z + v.w * v.w;
    for (int off = 32; off; off >>= 1) s += __shfl_xor(s, off);
    __shared__ float redw[4];
    __shared__ float rbc;
    if ((tid & 63) == 0) redw[tid >> 6] = s;
    __syncthreads();
    if (tid == 0) {
        float tot = redw[0] + redw[1] + redw[2] + redw[3];
        float r = (float)(1.0 / sqrt((double)tot * (1.0 / 1024.0)));
        rn[row] = r; rbc = r;
    }
    __syncthreads();
    float r = rbc;
    float4 ns = ((const float4*)nscale)[tid];
    ushort4 o;
    o.x = f2bf_bits(v.x * r * ns.x);
    o.y = f2bf_bits(v.y * r * ns.y);
    o.z = f2bf_bits(v.z * r * ns.z);
    o.w = f2bf_bits(v.w * r * ns.w);
    ((ushort4*)(xbf + (size_t)row * DM))[tid] = o;
}

#if HAVE_GLOAD
__device__ __forceinline__ void gload16(const __hip_bfloat16* g, __hip_bfloat16* l)
{
    __builtin_amdgcn_global_load_lds((const __attribute__((address_space(1))) unsigned int*)g,
                                     (__attribute__((address_space(3))) unsigned int*)l, 16, 0, 0);
}
#endif

// ================= unified fragment-linear BK=64 GEMM cores =================
// LDS layout: As[pair][frag][512 bf16]; frag f = i*2+kk holds, at lane*8,
// elements (row = base + (f>>1)*16 + (lane&15), k = (f&1)*32 + (lane>>4)*8 .. +7).
// ds_read_b128 at [p][f][lane*8] is 64 consecutive 16B chunks: conflict-free.

// ---------------- split-precision projection GEMM ----------------
struct ProjPack {
    const __hip_bfloat16* BT[4];
    const float* bias[4];
    float* C[4];
};

template<int NMAT, bool RESID>
__global__ __launch_bounds__(256) void k_gemm_proj(const __hip_bfloat16* __restrict__ A,
                                                   ProjPack P,
                                                   const float* __restrict__ resid)
{
    const int z = (NMAT == 4) ? blockIdx.z : 0;
    const __hip_bfloat16* BT = P.BT[z];
    const float* bias = P.bias[z];
    float* C = P.C[z];
    const int m0 = blockIdx.y * 128;
    const int n0 = blockIdx.x * 128;
    const int tid = threadIdx.x;
    __shared__ alignas(16) __hip_bfloat16 As[2][8][512];
    __shared__ alignas(16) __hip_bfloat16 Bs[2][8][512];

    const int lane = tid & 63, wv = tid >> 6;
    const int p = wv >> 1, q = wv & 1;
    const int lr = lane & 15, lgp = lane >> 4;

    const __hip_bfloat16* srcA[4];
    const __hip_bfloat16* srcB[4];
    __hip_bfloat16* dstA[4];
    __hip_bfloat16* dstB[4];
#pragma unroll
    for (int f4 = 0; f4 < 4; ++f4) {
        const int fA = q * 4 + f4;
        const int arow = m0 + p * 64 + (fA >> 1) * 16 + lr;
        srcA[f4] = A + (size_t)arow * 3072 + (fA & 1) * 32 + lgp * 8;
        dstA[f4] = &As[p][fA][0];
        const int fB = p * 4 + f4;
        const int brow = n0 + q * 64 + (fB >> 1) * 16 + lr;
        srcB[f4] = BT + (size_t)brow * KSPL + (fB & 1) * 32 + lgp * 8;
        dstB[f4] = &Bs[q][fB][0];
    }

    f32x4 acc[4][4];
#pragma unroll
    for (int i = 0; i < 4; ++i)
#pragma unroll
        for (int j = 0; j < 4; ++j) acc[i][j] = (f32x4){0.f, 0.f, 0.f, 0.f};

    for (int k0 = 0; k0 < KSPL; k0 += 64) {
        const int acol = (k0 < 3072) ? k0 : (k0 - 3072);
        __syncthreads();
#if HAVE_GLOAD
#pragma unroll
        for (int f4 = 0; f4 < 4; ++f4) {
            gload16(srcA[f4] + acol, dstA[f4]);
            gload16(srcB[f4] + k0, dstB[f4]);
        }
#else
#pragma unroll
        for (int f4 = 0; f4 < 4; ++f4) {
            *(uint4*)(dstA[f4] + (size_t)lane * 8) = *(const uint4*)(srcA[f4] + acol);
            *(uint4*)(dstB[f4] + (size_t)lane * 8) = *(const uint4*)(srcB[f4] + k0);
        }
#endif
        __syncthreads();
#pragma unroll
        for (int kk = 0; kk < 2; ++kk) {
            bf16x8 af[4], bfr[4];
#pragma unroll
            for (int i = 0; i < 4; ++i) af[i] = *(const bf16x8*)&As[p][i * 2 + kk][lane * 8];
#pragma unroll
            for (int j = 0; j < 4; ++j) bfr[j] = *(const bf16x8*)&Bs[q][j * 2 + kk][lane * 8];
#pragma unroll
            for (int i = 0; i < 4; ++i)
#pragma unroll
                for (int j = 0; j < 4; ++j)
                    acc[i][j] = __builtin_amdgcn_mfma_f32_16x16x32_bf16(af[i], bfr[j], acc[i][j], 0, 0, 0);
        }
    }

    const int wm = p * 64, wn = q * 64;
#pragma unroll
    for (int i = 0; i < 4; ++i)
#pragma unroll
        for (int j = 0; j < 4; ++j) {
            const int col = n0 + wn + j * 16 + lr;
            const float bval = bias[col];
#pragma unroll
            for (int r = 0; r < 4; ++r) {
                const int rloc = wm + i * 16 + lgp * 4 + r;
                float v = acc[i][j][r] + bval;
                if (RESID) v += resid[(size_t)(m0 + rloc) * DM + col];
                C[(size_t)(m0 + rloc) * DM + col] = v;
            }
        }
}

// ---------------- bf16 MFMA GEMM for experts ----------------
// MODE 0: Hbuf[le][slot] = gelu(xn2bf[tok] @ W1T[e]^T + b1[e])   (K=1024, Nout=4096)
// MODE 1: out[tok] += gate * (Hbuf[le][slot] @ W2T[e]^T + b2[e]) (K=4096, Nout=1024)
template<int MODE>
__global__ __launch_bounds__(256) void k_gemm_bf16(const __hip_bfloat16* __restrict__ A,
                                                   const __hip_bfloat16* __restrict__ BT,
                                                   const float* __restrict__ bias,
                                                   __hip_bfloat16* __restrict__ Hout,
                                                   float* __restrict__ Fout,
                                                   const int* __restrict__ tokslot,
                                                   const float* __restrict__ gateslot,
                                                   int K, int Nout, int e0)
{
    const int le = blockIdx.z;
    const int e = e0 + le;
    const int m0 = blockIdx.y * 128;
    const int n0 = blockIdx.x * 128;
    const int tid = threadIdx.x;
    __shared__ alignas(16) __hip_bfloat16 As[2][8][512];
    __shared__ alignas(16) __hip_bfloat16 Bs[2][8][512];
    __shared__ int s_tok[128];
    __shared__ float s_gate[128];
    if (tid < 128) {
        s_tok[tid] = tokslot[e * CAPE + m0 + tid];
        s_gate[tid] = gateslot[e * CAPE + m0 + tid];
    }
    __syncthreads();

    const int lane = tid & 63, wv = tid >> 6;
    const int p = wv >> 1, q = wv & 1;
    const int lr = lane & 15, lgp = lane >> 4;

    const __hip_bfloat16* srcA[4];
    const __hip_bfloat16* srcB[4];
    __hip_bfloat16* dstA[4];
    __hip_bfloat16* dstB[4];
#pragma unroll
    for (int f4 = 0; f4 < 4; ++f4) {
        const int fA = q * 4 + f4;
        const int arl = p * 64 + (fA >> 1) * 16 + lr;
        if (MODE == 0) srcA[f4] = A + (size_t)s_tok[arl] * K + (fA & 1) * 32 + lgp * 8;
        else           srcA[f4] = A + ((size_t)le * CAPE + m0 + arl) * K + (fA & 1) * 32 + lgp * 8;
        dstA[f4] = &As[p][fA][0];
        const int fB = p * 4 + f4;
        const int brow = n0 + q * 64 + (fB >> 1) * 16 + lr;
        srcB[f4] = BT + ((size_t)e * Nout + brow) * K + (fB & 1) * 32 + lgp * 8;
        dstB[f4] = &Bs[q][fB][0];
    }

    f32x4 acc[4][4];
#pragma unroll
    for (int i = 0; i < 4; ++i)
#pragma unroll
        for (int j = 0; j < 4; ++j) acc[i][j] = (f32x4){0.f, 0.f, 0.f, 0.f};

    for (int k0 = 0; k0 < K; k0 += 64) {
        __syncthreads();
#if HAVE_GLOAD
#pragma unroll
        for (int f4 = 0; f4 < 4; ++f4) {
            gload16(srcA[f4] + k0, dstA[f4]);
            gload16(srcB[f4] + k0, dstB[f4]);
        }
#else
#pragma unroll
        for (int f4 = 0; f4 < 4; ++f4) {
            *(uint4*)(dstA[f4] + (size_t)lane * 8) = *(const uint4*)(srcA[f4] + k0);
            *(uint4*)(dstB[f4] + (size_t)lane * 8) = *(const uint4*)(srcB[f4] + k0);
        }
#endif
        __syncthreads();
#pragma unroll
        for (int kk = 0; kk < 2; ++kk) {
            bf16x8 af[4], bfr[4];
#pragma unroll
            for (int i = 0; i < 4; ++i) af[i] = *(const bf16x8*)&As[p][i * 2 + kk][lane * 8];
#pragma unroll
            for (int j = 0; j < 4; ++j) bfr[j] = *(const bf16x8*)&Bs[q][j * 2 + kk][lane * 8];
#pragma unroll
            for (int i = 0; i < 4; ++i)
#pragma unroll
                for (int j = 0; j < 4; ++j)
                    acc[i][j] = __builtin_amdgcn_mfma_f32_16x16x32_bf16(af[i], bfr[j], acc[i][j], 0, 0, 0);
        }
    }

    const int wm = p * 64, wn = q * 64;
#pragma unroll
    for (int i = 0; i < 4; ++i)
#pragma unroll
        for (int j = 0; j < 4; ++j) {
            const int col = n0 + wn + j * 16 + lr;
            const float bval = bias[(size_t)e * Nout + col];
#pragma unroll
            for (int r = 0; r < 4; ++r) {
                const int rloc = wm + i * 16 + lgp * 4 + r;
                float v = acc[i][j][r] + bval;
                if (MODE == 0) {
                    v = 0.5f * v * (1.f + erff(v * 0.70710678118654752f));
                    Hout[((size_t)le * CAPE + m0 + rloc) * Nout + col] = __float2bfloat16(v);
                } else {
                    const float g = s_gate[rloc];
                    if (g != 0.f) atomicAdd(&Fout[(size_t)s_tok[rloc] * DM + col], v * g);
                }
            }
        }
}

// ---------------- attention pass 1: S_c = K_c^T V_c (in place over K), Z_c into V row0 ----------------
__global__ __launch_bounds__(256) void k_scan_kv(float* KS, float* Vz,
                                                 const float* __restrict__ ct,
                                                 const float* __restrict__ st)
{
    const int c = blockIdx.x, bh = blockIdx.y;
    const int h = bh & 15, b = bh >> 4;
    const int tid = threadIdx.x;
    __shared__ float ks[64][68];
    __shared__ float vs[64][68];
    const size_t rowbase = ((size_t)b * TSEQ + c * 64) * DM + h * 64;
#pragma unroll
    for (int p = 0; p < 8; ++p) {
        int idx = p * 256 + tid;
        int t = idx >> 5, j = idx & 31;
        const size_t base = rowbase + (size_t)t * DM + j;
        float cn = ct[(c * 64 + t) * 32 + j];
        float sn = st[(c * 64 + t) * 32 + j];
        float k1 = KS[base], k2 = KS[base + 32];
        ks[t][j]      = phi_f(k1 * cn - k2 * sn);
        ks[t][j + 32] = phi_f(k1 * sn + k2 * cn);
    }
#pragma unroll
    for (int p = 0; p < 4; ++p) {
        int idx = p * 256 + tid;
        int t = idx >> 4, e4 = (idx & 15) * 4;
        *(float4*)&vs[t][e4] = *(const float4*)&Vz[rowbase + (size_t)t * DM + e4];
    }
    __syncthreads();
    const int e = tid & 63, dg = tid >> 6;
    float acc[16] = {};
    for (int t = 0; t < 64; ++t) {
        float vv = vs[t][e];
#pragma unroll
        for (int qq = 0; qq < 4; ++qq) {
            float4 kq = *(const float4*)&ks[t][dg * 16 + qq * 4];
            acc[qq * 4 + 0] = fmaf(kq.x, vv, acc[qq * 4 + 0]);
            acc[qq * 4 + 1] = fmaf(kq.y, vv, acc[qq * 4 + 1]);
            acc[qq * 4 + 2] = fmaf(kq.z, vv, acc[qq * 4 + 2]);
            acc[qq * 4 + 3] = fmaf(kq.w, vv, acc[qq * 4 + 3]);
        }
    }
#pragma unroll
    for (int i = 0; i < 16; ++i) {
        int d = dg * 16 + i;
        KS[rowbase + (size_t)d * DM + e] = acc[i];
    }
    if (tid < 64) {
        float z = 0.f;
        for (int t = 0; t < 64; ++t) z += ks[t][tid];
        Vz[rowbase + tid] = z;
    }
}

// ---------------- attention pass 2: inclusive prefix over chunks ----------------
__global__ __launch_bounds__(256) void k_scan_prefix(float* S)
{
    const int sg = blockIdx.x, bh = blockIdx.y;
    const int h = bh & 15, b = bh >> 4;
    const int idx = sg * 256 + threadIdx.x;
    const int d = idx >> 6, e = idx & 63;
    const size_t base = (size_t)b * TSEQ * DM + h * 64 + (size_t)d * DM + e;
    float acc = 0.f;
    for (int c = 0; c < 64; ++c) {
        size_t p = base + (size_t)c * 64 * DM;
        acc += S[p];
        S[p] = acc;
    }
}

__global__ void k_zprefix(float* Vz)
{
    const int bh = blockIdx.x;
    const int h = bh & 15, b = bh >> 4;
    const int d = threadIdx.x;
    const size_t base = (size_t)b * TSEQ * DM + h * 64 + d;
    float acc = 0.f;
    for (int c = 0; c < 64; ++c) {
        size_t p = base + (size_t)c * 64 * DM;
        acc += Vz[p];
        Vz[p] = acc;
    }
}

// ---------------- attention pass 3: O = g*(q@S)/(q.Z+eps), split to 3 bf16 planes in Xs ----------------
__global__ __launch_bounds__(256) void k_scan_out(const float* __restrict__ Q,
                                                  const float* __restrict__ S,
                                                  const float* __restrict__ Zv,
                                                  const float* __restrict__ G,
                                                  __hip_bfloat16* __restrict__ Xs,
                                                  const float* __restrict__ ct,
                                                  const float* __restrict__ st)
{
    const int c = blockIdx.x, bh = blockIdx.y;
    const int h = bh & 15, b = bh >> 4;
    const int tid = threadIdx.x;
    __shared__ float qs[64][69];
    __shared__ float Ss[64][68];
    __shared__ float den[64], Zl[64];
    const size_t rowbase = ((size_t)b * TSEQ + c * 64) * DM + h * 64;
#pragma unroll
    for (int p = 0; p < 8; ++p) {
        int idx = p * 256 + tid;
        int t = idx >> 5, j = idx & 31;
        const size_t base = rowbase + (size_t)t * DM + j;
        float cn = ct[(c * 64 + t) * 32 + j];
        float sn = st[(c * 64 + t) * 32 + j];
        float q1 = Q[base], q2 = Q[base + 32];
        qs[t][j]      = phi_f(q1 * cn - q2 * sn);
        qs[t][j + 32] = phi_f(q1 * sn + q2 * cn);
    }
#pragma unroll
    for (int p = 0; p < 4; ++p) {
        int idx = p * 256 + tid;
        int d = idx >> 4, e4 = (idx & 15) * 4;
        *(float4*)&Ss[d][e4] = *(const float4*)&S[rowbase + (size_t)d * DM + e4];
    }
    const int e = tid & 63, tg = tid >> 6;
    float greg[16];
#pragma unroll
    for (int i = 0; i < 16; ++i)
        greg[i] = G[rowbase + (size_t)(tg * 16 + i) * DM + e];
    if (tid < 64) Zl[tid] = Zv[rowbase + tid];
    __syncthreads();
    if (tid < 64) {
        float dd = 0.f;
        for (int d = 0; d < 64; ++d) dd += qs[tid][d] * Zl[d];
        den[tid] = dd + 1e-6f;
    }
    __syncthreads();
    float acc[16] = {};
    for (int d = 0; d < 64; ++d) {
        float sv = Ss[d][e];
#pragma unroll
        for (int i = 0; i < 16; ++i)
            acc[i] = fmaf(qs[tg * 16 + i][d], sv, acc[i]);
    }
    unsigned short* Xu = (unsigned short*)Xs;
#pragma unroll
    for (int i = 0; i < 16; ++i) {
        int t = tg * 16 + i;
        float g = 1.f / (1.f + expf(-greg[i]));
        float o = g * acc[i] / den[t];
        unsigned short b0 = f2bf_bits(o);
        float r1 = o - bf_to_f(b0);
        unsigned short b1 = f2bf_bits(r1);
        float r2 = r1 - bf_to_f(b1);
        unsigned short b2 = f2bf_bits(r2);
        const size_t xb = (size_t)(b * TSEQ + c * 64 + t) * 3072 + h * 64 + e;
        Xu[xb] = b0;
        Xu[xb + 1024] = b1;
        Xu[xb + 2048] = b2;
    }
}

// ---------------- router ----------------
__global__ __launch_bounds__(256) void k_router(const float* __restrict__ X2,
                                                const float* __restrict__ rn2,
                                                const float* __restrict__ ns2,
                                                const float* __restrict__ rW,
                                                const float* __restrict__ rb,
                                                int* __restrict__ route_e,
                                                float* __restrict__ route_g,
                                                float* __restrict__ probs)
{
    const int tok = blockIdx.x * 4 + (threadIdx.x >> 6);
    const int lane = threadIdx.x & 63;
    const float* xr = X2 + (size_t)tok * DM;
    const float rn = rn2[tok];
    float lg[8] = {};
    for (int d = lane; d < DM; d += 64) {
        float xv = xr[d] * rn * ns2[d];
        const float4* w4 = (const float4*)(rW + (size_t)d * 8);
        float4 w0 = w4[0], w1 = w4[1];
        lg[0] += xv * w0.x; lg[1] += xv * w0.y; lg[2] += xv * w0.z; lg[3] += xv * w0.w;
        lg[4] += xv * w1.x; lg[5] += xv * w1.y; lg[6] += xv * w1.z; lg[7] += xv * w1.w;
    }
#pragma unroll
    for (int e = 0; e < 8; ++e)
        for (int off = 32; off; off >>= 1) lg[e] += __shfl_xor(lg[e], off);
    if (lane == 0) {
        float pe[8]; float mx = -1e30f, s = 0.f;
#pragma unroll
        for (int e = 0; e < 8; ++e) { lg[e] += rb[e]; mx = fmaxf(mx, lg[e]); }
#pragma unroll
        for (int e = 0; e < 8; ++e) { pe[e] = expf(lg[e] - mx); s += pe[e]; }
#pragma unroll
        for (int e = 0; e < 8; ++e) { pe[e] /= s; probs[(size_t)tok * 8 + e] = pe[e]; }
        int i1 = 0; float p1 = pe[0];
#pragma unroll
        for (int e = 1; e < 8; ++e) if (pe[e] > p1) { p1 = pe[e]; i1 = e; }
        int i2 = -1; float p2 = -1.f;
#pragma unroll
        for (int e = 0; e < 8; ++e) if (e != i1 && pe[e] > p2) { p2 = pe[e]; i2 = e; }
        const float gsum = p1 + p2;
        route_e[tok * 2] = i1; route_e[tok * 2 + 1] = i2;
        route_g[tok * 2] = p1 / gsum; route_g[tok * 2 + 1] = p2 / gsum;
    }
}

// ---------------- capacity routing ----------------
__global__ __launch_bounds__(256) void k_count(const int* __restrict__ route_e, int* __restrict__ bcnt)
{
    __shared__ int c[8];
    const int tid = threadIdx.x;
    if (tid < 8) c[tid] = 0;
    __syncthreads();
    atomicAdd(&c[route_e[blockIdx.x * 256 + tid]], 1);
    __syncthreads();
    if (tid < 8) bcnt[blockIdx.x * 8 + tid] = c[tid];
}

__global__ void k_scan_blocks(const int* __restrict__ bcnt, int* __restrict__ bbase, int* __restrict__ ctot)
{
    const int e = threadIdx.x;
    if (e < 8) {
        int run = 0;
        for (int b = 0; b < 256; ++b) { bbase[b * 8 + e] = run; run += bcnt[b * 8 + e]; }
        ctot[e] = run;
    }
}

__global__ __launch_bounds__(256) void k_place(const int* __restrict__ route_e,
                                               const float* __restrict__ route_g,
                                               const int* __restrict__ bbase,
                                               int* __restrict__ tokslot,
                                               float* __restrict__ gateslot)
{
    const int tid = threadIdx.x;
    const int a = blockIdx.x * 256 + tid;
    const int e = route_e[a];
    __shared__ int se[256];
    se[tid] = e;
    __syncthreads();
    int rank = 0;
    for (int j = 0; j < tid; ++j) rank += (se[j] == e) ? 1 : 0;
    const int slot = bbase[blockIdx.x * 8 + e] + rank;
    if (slot < CAPE) {
        tokslot[e * CAPE + slot] = a >> 1;
        gateslot[e * CAPE + slot] = route_g[a];
    }
}

// ---------------- aux loss ----------------
__global__ __launch_bounds__(256) void k_aux(const float* __restrict__ probs,
                                             const int* __restrict__ ctot,
                                             float* __restrict__ out_aux)
{
    const int tid = threadIdx.x;
    float part[8] = {};
    for (int i = tid; i < NTOK; i += 256) {
        const float* p = probs + (size_t)i * 8;
#pragma unroll
        for (int e = 0; e < 8; ++e) part[e] += p[e];
    }
    __shared__ float red[256];
    __shared__ float accs[8];
    for (int e = 0; e < 8; ++e) {
        red[tid] = part[e];
        __syncthreads();
        for (int s = 128; s; s >>= 1) { if (tid < s) red[tid] += red[tid + s]; __syncthreads(); }
        if (tid == 0) accs[e] = red[0];
        __syncthreads();
    }
    if (tid == 0) {
        float isum = 0.f, lsum = 0.f, l[8];
        for (int e = 0; e < 8; ++e) isum += accs[e];
        for (int e = 0; e < 8; ++e) { l[e] = fminf((float)ctot[e], (float)CAPE); lsum += l[e]; }
        float aux = 0.f;
        for (int e = 0; e < 8; ++e) aux += (accs[e] / isum) * (l[e] / lsum);
        out_aux[0] = aux * 64.f;
    }
}

// ---------------- f32 -> bf16 transpose (per expert z) ----------------
__global__ void k_transpose_bf16(const float* __restrict__ src, __hip_bfloat16* __restrict__ dst,
                                 int K_, int N_)
{
    __shared__ float t_[32][33];
    const int z = blockIdx.z;
    const float* s = src + (size_t)z * K_ * N_;
    __hip_bfloat16* d = dst + (size_t)z * K_ * N_;
    const int n0 = blockIdx.x * 32, k0 = blockIdx.y * 32;
    const int c = threadIdx.x, r0 = threadIdx.y;
#pragma unroll
    for (int i = 0; i < 4; ++i) { int r = r0 + i * 8; t_[r][c] = s[(size_t)(k0 + r) * N_ + n0 + c]; }
    __syncthreads();
#pragma unroll
    for (int i = 0; i < 4; ++i) { int r = r0 + i * 8; d[(size_t)(n0 + r) * K_ + k0 + c] = __float2bfloat16(t_[c][r]); }
}

extern "C" void kernel_launch(void* const* d_in, const int* in_sizes, int n_in,
                              void* d_out, int out_size, void* d_ws, size_t ws_size,
                              hipStream_t stream)
{
    (void)in_sizes; (void)n_in; (void)out_size;
    const float* x   = (const float*)d_in[0];
    const float* ns1 = (const float*)d_in[1];
    const float* ns2 = (const float*)d_in[2];
    const float* Wq  = (const float*)d_in[3];
    const float* bq  = (const float*)d_in[4];
    const float* Wk  = (const float*)d_in[5];
    const float* bk  = (const float*)d_in[6];
    const float* Wv  = (const float*)d_in[7];
    const float* bv  = (const float*)d_in[8];
    const float* Wg  = (const float*)d_in[9];
    const float* bg  = (const float*)d_in[10];
    const float* Wo  = (const float*)d_in[11];
    const float* bo  = (const float*)d_in[12];
    const float* rW  = (const float*)d_in[13];
    const float* rb  = (const float*)d_in[14];
    const float* W1  = (const float*)d_in[15];
    const float* b1  = (const float*)d_in[16];
    const float* W2  = (const float*)d_in[17];
    const float* b2  = (const float*)d_in[18];
    float* out = (float*)d_out;
    char* wsb = (char*)d_ws;

    constexpr size_t MiB = 1024ull * 1024ull;
    constexpr size_t R = (size_t)NTOK * DM * 4;        // 128 MiB
    constexpr size_t TAIL = 3 * R;
    constexpr size_t OFF_RN1  = TAIL;
    constexpr size_t OFF_RN2  = OFF_RN1 + (size_t)NTOK * 4;
    constexpr size_t OFF_PROB = OFF_RN2 + (size_t)NTOK * 4;
    constexpr size_t OFF_RE   = OFF_PROB + (size_t)NTOK * 8 * 4;
    constexpr size_t OFF_RG   = OFF_RE + (size_t)NTOK * 2 * 4;
    constexpr size_t OFF_BCNT = OFF_RG + (size_t)NTOK * 2 * 4;
    constexpr size_t OFF_BBASE= OFF_BCNT + 256 * 8 * 4;
    constexpr size_t OFF_CTOT = OFF_BBASE + 256 * 8 * 4;
    constexpr size_t OFF_TOK  = OFF_CTOT + 4096;
    constexpr size_t OFF_GATE = OFF_TOK + (size_t)NEXP * CAPE * 4;
    constexpr size_t REQUIRED = OFF_GATE + (size_t)NEXP * CAPE * 4;

    if (ws_size < REQUIRED) {
        k_ws_flag<<<1, 64, 0, stream>>>(out, (float)(ws_size >> 20));
        return;
    }

    // main region layout (within [0, 3R))
    __hip_bfloat16* xn2bf = (__hip_bfloat16*)(wsb);                 // 64 MiB persistent
    __hip_bfloat16* WST   = (__hip_bfloat16*)(wsb + 64 * MiB);      // 5 x 10 MiB = 50 MiB
    __hip_bfloat16* Xs    = (__hip_bfloat16*)(wsb + 114 * MiB);     // 48 MiB per-group
    float* qg = (float*)(wsb + 162 * MiB);                          // 32 MiB
    float* kg = (float*)(wsb + 194 * MiB);                          // 32 MiB
    float* gg = (float*)(wsb + 226 * MiB);                          // 32 MiB (ends 258)
    __hip_bfloat16* W1T  = (__hip_bfloat16*)(wsb + 64 * MiB);       // 64 MiB (after WST dead)
    __hip_bfloat16* W2T  = (__hip_bfloat16*)(wsb + 128 * MiB);      // 64 MiB
    __hip_bfloat16* Hbuf = (__hip_bfloat16*)(wsb + 192 * MiB);      // 120 MiB (ends 312)

    float* rn2 = (float*)(wsb + OFF_RN2);
    float* probs = (float*)(wsb + OFF_PROB);
    float* rope_ct = (float*)(wsb + OFF_PROB);
    float* rope_st = (float*)(wsb + OFF_PROB + (size_t)TSEQ * 32 * 4);
    int*   route_e = (int*)(wsb + OFF_RE);
    float* route_g = (float*)(wsb + OFF_RG);
    int*   bcnt  = (int*)(wsb + OFF_BCNT);
    int*   bbase = (int*)(wsb + OFF_BBASE);
    int*   ctot  = (int*)(wsb + OFF_CTOT);
    int*   tokslot  = (int*)(wsb + OFF_TOK);
    float* gateslot = (float*)(wsb + OFF_GATE);

    // 0. rope table + weight stacks (w0/w1 split, BT layout)
    k_rope_table<<<512, 256, 0, stream>>>(rope_ct, rope_st);
    {
        WPack WP; WP.W[0] = Wq; WP.W[1] = Wk; WP.W[2] = Wg; WP.W[3] = Wv; WP.W[4] = Wo;
        k_build_wstack<<<dim3(32, 32, 5), 256, 0, stream>>>(WP, WST);
    }

    // 1. per-group: rms-split -> QKVG -> attn (O split fused) -> Wo+resid -> rmsnorm2
    for (int gi = 0; gi < 4; ++gi) {
        const size_t tok0 = (size_t)gi * GTOK;
        const float* xg = x + tok0 * DM;
        float* vg = out + tok0 * DM;

        k_rms_split<true><<<GTOK, 256, 0, stream>>>(xg, ns1, Xs);

        ProjPack P;
        P.BT[0] = WST;                     P.bias[0] = bq; P.C[0] = qg;
        P.BT[1] = WST + (size_t)DM * KSPL; P.bias[1] = bk; P.C[1] = kg;
        P.BT[2] = WST + 2ull * DM * KSPL;  P.bias[2] = bg; P.C[2] = gg;
        P.BT[3] = WST + 3ull * DM * KSPL;  P.bias[3] = bv; P.C[3] = vg;
        k_gemm_proj<4, false><<<dim3(8, GTOK / 128, 4), 256, 0, stream>>>(Xs, P, nullptr);

        k_scan_kv<<<dim3(64, 32), 256, 0, stream>>>(kg, vg, rope_ct, rope_st);
        k_scan_prefix<<<dim3(16, 32), 256, 0, stream>>>(kg);
        k_zprefix<<<32, 64, 0, stream>>>(vg);
        k_scan_out<<<dim3(64, 32), 256, 0, stream>>>(qg, kg, vg, gg, Xs, rope_ct, rope_st);

        ProjPack P2;
        P2.BT[0] = WST + 4ull * DM * KSPL; P2.bias[0] = bo; P2.C[0] = vg;  // x2 -> d_out slice
        P2.BT[1] = P2.BT[2] = P2.BT[3] = P2.BT[0];
        P2.bias[1] = P2.bias[2] = P2.bias[3] = bo;
        P2.C[1] = P2.C[2] = P2.C[3] = vg;
        k_gemm_proj<1, true><<<dim3(8, GTOK / 128, 1), 256, 0, stream>>>(Xs, P2, xg);

        k_rmsnorm_stats<<<GTOK, 256, 0, stream>>>(vg, rn2 + tok0, ns2, xn2bf + tok0 * DM);
    }

    // 2. router (fp32) — overwrites rope table region with probs
    k_router<<<NTOK / 4, 256, 0, stream>>>(out, rn2, ns2, rW, rb, route_e, route_g, probs);

    // 3. capacity routing
    k_count<<<256, 256, 0, stream>>>(route_e, bcnt);
    k_scan_blocks<<<1, 64, 0, stream>>>(bcnt, bbase, ctot);
    k_zero<<<(NEXP * CAPE * 2 + 255) / 256, 256, 0, stream>>>(tokslot, NEXP * CAPE * 2);
    k_place<<<256, 256, 0, stream>>>(route_e, route_g, bbase, tokslot, gateslot);

    // 4. aux loss scalar
    k_aux<<<1, 256, 0, stream>>>(probs, ctot, out + (size_t)NTOK * DM);

    // 5. MoE expert weights (bf16, transposed) + expert MLP in groups of {3,3,2}
    k_transpose_bf16<<<dim3(HIDN / 32, DM / 32, NEXP), dim3(32, 8), 0, stream>>>(W1, W1T, DM, HIDN);
    k_transpose_bf16<<<dim3(DM / 32, HIDN / 32, NEXP), dim3(32, 8), 0, stream>>>(W2, W2T, HIDN, DM);

    for (int g = 0; g < 3; ++g) {
        const int e0 = g * 3;
        const int ecnt = (g == 2) ? 2 : 3;
        k_gemm_bf16<0><<<dim3(HIDN / 128, CAPE / 128, ecnt), 256, 0, stream>>>(
            xn2bf, W1T, b1, Hbuf, nullptr, tokslot, gateslot, DM, HIDN, e0);
        k_gemm_bf16<1><<<dim3(DM / 128, CAPE / 128, ecnt), 256, 0, stream>>>(
            Hbuf, W2T, b2, nullptr, out, tokslot, gateslot, HIDN, DM, e0);
    }
}

// Round 7
// 4609.968 us; speedup vs baseline: 1.2494x; 1.2494x over previous
//
#include <hip/hip_runtime.h>
#include <hip/hip_bf16.h>

#define NTOK 32768
#define TSEQ 4096
#define DM   1024
#define NHEAD 16
#define NEXP 8
#define CAPE 5120
#define HIDN 4096
#define GTOK 8192         // tokens per batch-group (2 sequences)
#define KSPL 5120         // split-GEMM K (3*1024 + 2*1024)

#ifndef __has_builtin
#define __has_builtin(x) 0
#endif
#if __has_builtin(__builtin_amdgcn_global_load_lds)
#define HAVE_GLOAD 1
#else
#define HAVE_GLOAD 0
#endif

typedef __attribute__((ext_vector_type(8))) short bf16x8;
typedef __attribute__((ext_vector_type(4))) float f32x4;

__device__ __forceinline__ float phi_f(float v) { return v > 0.f ? v + 1.f : expf(v); }

__device__ __forceinline__ unsigned short f2bf_bits(float f) {
    __hip_bfloat16 h = __float2bfloat16(f);
    union { __hip_bfloat16 h; unsigned short s; } u;
    u.h = h;
    return u.s;
}
__device__ __forceinline__ float bf_to_f(unsigned short s) {
    unsigned int u = ((unsigned int)s) << 16;
    union { unsigned int u; float f; } w; w.u = u;
    return w.f;
}

__global__ void k_ws_flag(float* out, float v) { if (threadIdx.x == 0) out[0] = v; }

__global__ void k_zero(int* p, int n) {
    int i = blockIdx.x * 256 + threadIdx.x;
    if (i < n) p[i] = 0;
}

// ---------------- rope table ----------------
__global__ __launch_bounds__(256) void k_rope_table(float* __restrict__ ct, float* __restrict__ st)
{
    const int idx = blockIdx.x * 256 + threadIdx.x;
    const int t = idx >> 5, j = idx & 31;
    const float inv = (float)(1.0 / pow(10000.0, (double)j / 32.0));
    float sn, cn;
    sincosf((float)t * inv, &sn, &cn);
    ct[idx] = cn; st[idx] = sn;
}

// ---------------- build W stacks: BT[n, k] bf16, k-> (seg, d); seg<3: w0, else w1 ----------------
struct WPack { const float* W[5]; };
__global__ __launch_bounds__(256) void k_build_wstack(WPack P, __hip_bfloat16* __restrict__ BTbase)
{
    __shared__ float t_[32][33];
    const int z = blockIdx.z;
    const float* Wm = P.W[z];
    __hip_bfloat16* BT = BTbase + (size_t)z * DM * KSPL;
    const int n0 = blockIdx.x * 32, k0 = blockIdx.y * 32;
    const int c = threadIdx.x & 31, r0 = (threadIdx.x >> 5);   // 32 x 8
#pragma unroll
    for (int i = 0; i < 4; ++i) { int r = r0 + i * 8; t_[r][c] = Wm[(size_t)(k0 + r) * DM + n0 + c]; }
    __syncthreads();
#pragma unroll
    for (int i = 0; i < 4; ++i) {
        int r = r0 + i * 8;                       // local n
        float val = t_[c][r];                     // W[k0+c][n0+r]
        unsigned short b0 = f2bf_bits(val);
        float res = val - bf_to_f(b0);
        unsigned short b1 = f2bf_bits(res);
        __hip_bfloat16 h0, h1;
        union { __hip_bfloat16 h; unsigned short s; } u0, u1;
        u0.s = b0; u1.s = b1; h0 = u0.h; h1 = u1.h;
        const size_t nrow = (size_t)(n0 + r) * KSPL + (k0 + c);
        BT[nrow]            = h0;
        BT[nrow + 1024]     = h0;
        BT[nrow + 2048]     = h0;
        BT[nrow + 3072]     = h1;
        BT[nrow + 4096]     = h1;
    }
}

// ---------------- split rows into 3 bf16 planes (rmsnorm-scaled) ----------------
template<bool NORM>
__global__ __launch_bounds__(256) void k_rms_split(const float* __restrict__ X,
                                                   const float* __restrict__ nscale,
                                                   __hip_bfloat16* __restrict__ Xs)
{
    const int row = blockIdx.x;
    const int tid = threadIdx.x;
    const float* xr = X + (size_t)row * DM;
    float4 v = ((const float4*)xr)[tid];
    float r = 1.f;
    if (NORM) {
        float s = v.x * v.x + v.y * v.y + v.z * v.z + v.w * v.w;
        for (int off = 32; off; off >>= 1) s += __shfl_xor(s, off);
        __shared__ float redw[4];
        __shared__ float rbc;
        if ((tid & 63) == 0) redw[tid >> 6] = s;
        __syncthreads();
        if (tid == 0) {
            float tot = redw[0] + redw[1] + redw[2] + redw[3];
            rbc = (float)(1.0 / sqrt((double)tot * (1.0 / 1024.0)));
        }
        __syncthreads();
        r = rbc;
    }
    float c[4] = {v.x, v.y, v.z, v.w};
    if (NORM) {
        float4 ns = ((const float4*)nscale)[tid];
        c[0] *= r * ns.x; c[1] *= r * ns.y; c[2] *= r * ns.z; c[3] *= r * ns.w;
    }
    ushort4 p0, p1, p2;
    unsigned short* q0 = (unsigned short*)&p0;
    unsigned short* q1 = (unsigned short*)&p1;
    unsigned short* q2 = (unsigned short*)&p2;
#pragma unroll
    for (int i = 0; i < 4; ++i) {
        float x = c[i];
        unsigned short b0 = f2bf_bits(x);
        float r1 = x - bf_to_f(b0);
        unsigned short b1 = f2bf_bits(r1);
        float r2 = r1 - bf_to_f(b1);
        unsigned short b2 = f2bf_bits(r2);
        q0[i] = b0; q1[i] = b1; q2[i] = b2;
    }
    __hip_bfloat16* base = Xs + (size_t)row * 3072;
    ((ushort4*)(base))[tid] = p0;
    ((ushort4*)(base + 1024))[tid] = p1;
    ((ushort4*)(base + 2048))[tid] = p2;
}

// ---------------- rmsnorm stats + bf16 normalized rows ----------------
__global__ __launch_bounds__(256) void k_rmsnorm_stats(const float* __restrict__ X,
                                                       float* __restrict__ rn,
                                                       const float* __restrict__ nscale,
                                                       __hip_bfloat16* __restrict__ xbf)
{
    const int row = blockIdx.x;
    const int tid = threadIdx.x;
    const float* xr = X + (size_t)row * DM;
    float4 v = ((const float4*)xr)[tid];
    float s = v.x * v.x + v.y * v.y + v.z * v.z + v.w * v.w;
    for (int off = 32; off; off >>= 1) s += __shfl_xor(s, off);
    __shared__ float redw[4];
    __shared__ float rbc;
    if ((tid & 63) == 0) redw[tid >> 6] = s;
    __syncthreads();
    if (tid == 0) {
        float tot = redw[0] + redw[1] + redw[2] + redw[3];
        float r = (float)(1.0 / sqrt((double)tot * (1.0 / 1024.0)));
        rn[row] = r; rbc = r;
    }
    __syncthreads();
    float r = rbc;
    float4 ns = ((const float4*)nscale)[tid];
    ushort4 o;
    o.x = f2bf_bits(v.x * r * ns.x);
    o.y = f2bf_bits(v.y * r * ns.y);
    o.z = f2bf_bits(v.z * r * ns.z);
    o.w = f2bf_bits(v.w * r * ns.w);
    ((ushort4*)(xbf + (size_t)row * DM))[tid] = o;
}

#if HAVE_GLOAD
__device__ __forceinline__ void gload16(const __hip_bfloat16* g, __hip_bfloat16* l)
{
    __builtin_amdgcn_global_load_lds((const __attribute__((address_space(1))) unsigned int*)g,
                                     (__attribute__((address_space(3))) unsigned int*)l, 16, 0, 0);
}
#endif

// ============ R5 GEMM cores + T3-min 2-phase double-buffer pipeline ============
// Per K-step: STAGE(buf^1, k+32) issued first (async), then ds_read+MFMA on buf,
// then ONE __syncthreads() (carries vmcnt(0)+lgkmcnt(0) drain). Loads fly under MFMA.

// ---------------- split-precision projection GEMM ----------------
struct ProjPack {
    const __hip_bfloat16* BT[4];
    const float* bias[4];
    float* C[4];
};

template<int NMAT, bool RESID>
__global__ __launch_bounds__(256) void k_gemm_proj(const __hip_bfloat16* __restrict__ A,
                                                   ProjPack P,
                                                   const float* __restrict__ resid)
{
    const int z = (NMAT == 4) ? blockIdx.z : 0;
    const __hip_bfloat16* BT = P.BT[z];
    const float* bias = P.bias[z];
    float* C = P.C[z];
    const int m0 = blockIdx.y * 128;
    const int n0 = blockIdx.x * 128;
    const int tid = threadIdx.x;
    __shared__ alignas(16) __hip_bfloat16 As[2][128 * 32];
    __shared__ alignas(16) __hip_bfloat16 Bs[2][128 * 32];

    const int lane = tid & 63, wv = tid >> 6;
    const int lr = lane & 15, lgp = lane >> 4;
    const int wm = (wv >> 1) * 64, wn = (wv & 1) * 64;

#if HAVE_GLOAD
    const int rA0 = wv * 32 + (lane >> 2), rA1 = rA0 + 16;
    const int ch = lane & 3;
    const __hip_bfloat16* srcA0 = A + (size_t)(m0 + rA0) * 3072 + ((ch ^ (rA0 & 3)) * 8);
    const __hip_bfloat16* srcA1 = A + (size_t)(m0 + rA1) * 3072 + ((ch ^ (rA1 & 3)) * 8);
    const __hip_bfloat16* srcB0 = BT + (size_t)(n0 + rA0) * KSPL + ((ch ^ (rA0 & 3)) * 8);
    const __hip_bfloat16* srcB1 = BT + (size_t)(n0 + rA1) * KSPL + ((ch ^ (rA1 & 3)) * 8);
    const int ldsO0 = (wv * 32) * 32;
    const int ldsO1 = (wv * 32 + 16) * 32;
#else
    const int ar = tid >> 1, ac0 = (tid & 1) * 2;
    const __hip_bfloat16* Arow = A + (size_t)(m0 + ar) * 3072;
    const __hip_bfloat16* Brow = BT + (size_t)(n0 + ar) * KSPL;
#endif

    f32x4 acc[4][4];
#pragma unroll
    for (int i = 0; i < 4; ++i)
#pragma unroll
        for (int j = 0; j < 4; ++j) acc[i][j] = (f32x4){0.f, 0.f, 0.f, 0.f};

    int a_off[4], b_off[4];
#pragma unroll
    for (int i = 0; i < 4; ++i) {
        int mrow = wm + i * 16 + lr;
        a_off[i] = mrow * 32 + ((lgp ^ (mrow & 3)) * 8);
        int nrow = wn + i * 16 + lr;
        b_off[i] = nrow * 32 + ((lgp ^ (nrow & 3)) * 8);
    }

    // prologue: stage k=0 into buf 0
#if HAVE_GLOAD
    gload16(srcA0, &As[0][ldsO0]);
    gload16(srcA1, &As[0][ldsO1]);
    gload16(srcB0, &Bs[0][ldsO0]);
    gload16(srcB1, &Bs[0][ldsO1]);
#else
    {
        uint4 av0 = *(const uint4*)(Arow + ac0 * 8);
        uint4 av1 = *(const uint4*)(Arow + ac0 * 8 + 8);
        uint4 bv0 = *(const uint4*)(Brow + ac0 * 8);
        uint4 bv1 = *(const uint4*)(Brow + ac0 * 8 + 8);
        *(uint4*)(&As[0][0] + ar * 32 + ((ac0    ) ^ (ar & 3)) * 8) = av0;
        *(uint4*)(&As[0][0] + ar * 32 + ((ac0 + 1) ^ (ar & 3)) * 8) = av1;
        *(uint4*)(&Bs[0][0] + ar * 32 + ((ac0    ) ^ (ar & 3)) * 8) = bv0;
        *(uint4*)(&Bs[0][0] + ar * 32 + ((ac0 + 1) ^ (ar & 3)) * 8) = bv1;
    }
#endif
    __syncthreads();

    int cur = 0;
    for (int k0 = 0; k0 < KSPL; k0 += 32) {
        if (k0 + 32 < KSPL) {
            const int kn = k0 + 32;
            const int acoln = (kn < 3072) ? kn : (kn - 3072);
#if HAVE_GLOAD
            gload16(srcA0 + acoln, &As[cur ^ 1][ldsO0]);
            gload16(srcA1 + acoln, &As[cur ^ 1][ldsO1]);
            gload16(srcB0 + kn, &Bs[cur ^ 1][ldsO0]);
            gload16(srcB1 + kn, &Bs[cur ^ 1][ldsO1]);
#else
            uint4 av0 = *(const uint4*)(Arow + acoln + ac0 * 8);
            uint4 av1 = *(const uint4*)(Arow + acoln + ac0 * 8 + 8);
            uint4 bv0 = *(const uint4*)(Brow + kn + ac0 * 8);
            uint4 bv1 = *(const uint4*)(Brow + kn + ac0 * 8 + 8);
            *(uint4*)(&As[cur ^ 1][0] + ar * 32 + ((ac0    ) ^ (ar & 3)) * 8) = av0;
            *(uint4*)(&As[cur ^ 1][0] + ar * 32 + ((ac0 + 1) ^ (ar & 3)) * 8) = av1;
            *(uint4*)(&Bs[cur ^ 1][0] + ar * 32 + ((ac0    ) ^ (ar & 3)) * 8) = bv0;
            *(uint4*)(&Bs[cur ^ 1][0] + ar * 32 + ((ac0 + 1) ^ (ar & 3)) * 8) = bv1;
#endif
        }
        bf16x8 af[4], bfr[4];
#pragma unroll
        for (int i = 0; i < 4; ++i) af[i] = *(const bf16x8*)(&As[cur][0] + a_off[i]);
#pragma unroll
        for (int j = 0; j < 4; ++j) bfr[j] = *(const bf16x8*)(&Bs[cur][0] + b_off[j]);
#pragma unroll
        for (int i = 0; i < 4; ++i)
#pragma unroll
            for (int j = 0; j < 4; ++j)
                acc[i][j] = __builtin_amdgcn_mfma_f32_16x16x32_bf16(af[i], bfr[j], acc[i][j], 0, 0, 0);
        __syncthreads();
        cur ^= 1;
    }

#pragma unroll
    for (int i = 0; i < 4; ++i)
#pragma unroll
        for (int j = 0; j < 4; ++j) {
            const int col = n0 + wn + j * 16 + lr;
            const float bval = bias[col];
#pragma unroll
            for (int r = 0; r < 4; ++r) {
                const int rloc = wm + i * 16 + lgp * 4 + r;
                float v = acc[i][j][r] + bval;
                if (RESID) v += resid[(size_t)(m0 + rloc) * DM + col];
                C[(size_t)(m0 + rloc) * DM + col] = v;
            }
        }
}

// ---------------- bf16 MFMA GEMM for experts ----------------
// MODE 0: Hbuf[le][slot] = gelu(xn2bf[tok] @ W1T[e]^T + b1[e])   (K=1024, Nout=4096)
// MODE 1: out[tok] += gate * (Hbuf[le][slot] @ W2T[e]^T + b2[e]) (K=4096, Nout=1024)
template<int MODE>
__global__ __launch_bounds__(256) void k_gemm_bf16(const __hip_bfloat16* __restrict__ A,
                                                   const __hip_bfloat16* __restrict__ BT,
                                                   const float* __restrict__ bias,
                                                   __hip_bfloat16* __restrict__ Hout,
                                                   float* __restrict__ Fout,
                                                   const int* __restrict__ tokslot,
                                                   const float* __restrict__ gateslot,
                                                   int K, int Nout, int e0)
{
    const int le = blockIdx.z;
    const int e = e0 + le;
    const int m0 = blockIdx.y * 128;
    const int n0 = blockIdx.x * 128;
    const int tid = threadIdx.x;
    __shared__ alignas(16) __hip_bfloat16 As[2][128 * 32];
    __shared__ alignas(16) __hip_bfloat16 Bs[2][128 * 32];
    __shared__ int s_tok[128];
    __shared__ float s_gate[128];
    if (tid < 128) {
        s_tok[tid] = tokslot[e * CAPE + m0 + tid];
        s_gate[tid] = gateslot[e * CAPE + m0 + tid];
    }
    __syncthreads();

    const int lane = tid & 63, wv = tid >> 6;
    const int lr = lane & 15, lgp = lane >> 4;
    const int wm = (wv >> 1) * 64, wn = (wv & 1) * 64;

#if HAVE_GLOAD
    const int rA0 = wv * 32 + (lane >> 2), rA1 = rA0 + 16;
    const int ch = lane & 3;
    const __hip_bfloat16 *srcA0, *srcA1;
    if (MODE == 0) {
        srcA0 = A + (size_t)s_tok[rA0] * K + ((ch ^ (rA0 & 3)) * 8);
        srcA1 = A + (size_t)s_tok[rA1] * K + ((ch ^ (rA1 & 3)) * 8);
    } else {
        srcA0 = A + ((size_t)le * CAPE + m0 + rA0) * K + ((ch ^ (rA0 & 3)) * 8);
        srcA1 = A + ((size_t)le * CAPE + m0 + rA1) * K + ((ch ^ (rA1 & 3)) * 8);
    }
    const __hip_bfloat16* srcB0 = BT + ((size_t)e * Nout + n0 + rA0) * K + ((ch ^ (rA0 & 3)) * 8);
    const __hip_bfloat16* srcB1 = BT + ((size_t)e * Nout + n0 + rA1) * K + ((ch ^ (rA1 & 3)) * 8);
    const int ldsO0 = (wv * 32) * 32;
    const int ldsO1 = (wv * 32 + 16) * 32;
#else
    const int ar = tid >> 1, ac0 = (tid & 1) * 2;
    const __hip_bfloat16* Arow;
    if (MODE == 0) Arow = A + (size_t)s_tok[ar] * K;
    else           Arow = A + ((size_t)le * CAPE + m0 + ar) * K;
    const __hip_bfloat16* Brow = BT + ((size_t)e * Nout + n0 + ar) * K;
#endif

    f32x4 acc[4][4];
#pragma unroll
    for (int i = 0; i < 4; ++i)
#pragma unroll
        for (int j = 0; j < 4; ++j) acc[i][j] = (f32x4){0.f, 0.f, 0.f, 0.f};

    int a_off[4], b_off[4];
#pragma unroll
    for (int i = 0; i < 4; ++i) {
        int mrow = wm + i * 16 + lr;
        a_off[i] = mrow * 32 + ((lgp ^ (mrow & 3)) * 8);
        int nrow = wn + i * 16 + lr;
        b_off[i] = nrow * 32 + ((lgp ^ (nrow & 3)) * 8);
    }

    // prologue: stage k=0 into buf 0
#if HAVE_GLOAD
    gload16(srcA0, &As[0][ldsO0]);
    gload16(srcA1, &As[0][ldsO1]);
    gload16(srcB0, &Bs[0][ldsO0]);
    gload16(srcB1, &Bs[0][ldsO1]);
#else
    {
        uint4 av0 = *(const uint4*)(Arow + ac0 * 8);
        uint4 av1 = *(const uint4*)(Arow + ac0 * 8 + 8);
        uint4 bv0 = *(const uint4*)(Brow + ac0 * 8);
        uint4 bv1 = *(const uint4*)(Brow + ac0 * 8 + 8);
        *(uint4*)(&As[0][0] + ar * 32 + ((ac0    ) ^ (ar & 3)) * 8) = av0;
        *(uint4*)(&As[0][0] + ar * 32 + ((ac0 + 1) ^ (ar & 3)) * 8) = av1;
        *(uint4*)(&Bs[0][0] + ar * 32 + ((ac0    ) ^ (ar & 3)) * 8) = bv0;
        *(uint4*)(&Bs[0][0] + ar * 32 + ((ac0 + 1) ^ (ar & 3)) * 8) = bv1;
    }
#endif
    __syncthreads();

    int cur = 0;
    for (int k0 = 0; k0 < K; k0 += 32) {
        if (k0 + 32 < K) {
            const int kn = k0 + 32;
#if HAVE_GLOAD
            gload16(srcA0 + kn, &As[cur ^ 1][ldsO0]);
            gload16(srcA1 + kn, &As[cur ^ 1][ldsO1]);
            gload16(srcB0 + kn, &Bs[cur ^ 1][ldsO0]);
            gload16(srcB1 + kn, &Bs[cur ^ 1][ldsO1]);
#else
            uint4 av0 = *(const uint4*)(Arow + kn + ac0 * 8);
            uint4 av1 = *(const uint4*)(Arow + kn + ac0 * 8 + 8);
            uint4 bv0 = *(const uint4*)(Brow + kn + ac0 * 8);
            uint4 bv1 = *(const uint4*)(Brow + kn + ac0 * 8 + 8);
            *(uint4*)(&As[cur ^ 1][0] + ar * 32 + ((ac0    ) ^ (ar & 3)) * 8) = av0;
            *(uint4*)(&As[cur ^ 1][0] + ar * 32 + ((ac0 + 1) ^ (ar & 3)) * 8) = av1;
            *(uint4*)(&Bs[cur ^ 1][0] + ar * 32 + ((ac0    ) ^ (ar & 3)) * 8) = bv0;
            *(uint4*)(&Bs[cur ^ 1][0] + ar * 32 + ((ac0 + 1) ^ (ar & 3)) * 8) = bv1;
#endif
        }
        bf16x8 af[4], bfr[4];
#pragma unroll
        for (int i = 0; i < 4; ++i) af[i] = *(const bf16x8*)(&As[cur][0] + a_off[i]);
#pragma unroll
        for (int j = 0; j < 4; ++j) bfr[j] = *(const bf16x8*)(&Bs[cur][0] + b_off[j]);
#pragma unroll
        for (int i = 0; i < 4; ++i)
#pragma unroll
            for (int j = 0; j < 4; ++j)
                acc[i][j] = __builtin_amdgcn_mfma_f32_16x16x32_bf16(af[i], bfr[j], acc[i][j], 0, 0, 0);
        __syncthreads();
        cur ^= 1;
    }

#pragma unroll
    for (int i = 0; i < 4; ++i)
#pragma unroll
        for (int j = 0; j < 4; ++j) {
            const int col = n0 + wn + j * 16 + lr;
            const float bval = bias[(size_t)e * Nout + col];
#pragma unroll
            for (int r = 0; r < 4; ++r) {
                const int rloc = wm + i * 16 + lgp * 4 + r;
                float v = acc[i][j][r] + bval;
                if (MODE == 0) {
                    v = 0.5f * v * (1.f + erff(v * 0.70710678118654752f));
                    Hout[((size_t)le * CAPE + m0 + rloc) * Nout + col] = __float2bfloat16(v);
                } else {
                    const float g = s_gate[rloc];
                    if (g != 0.f) atomicAdd(&Fout[(size_t)s_tok[rloc] * DM + col], v * g);
                }
            }
        }
}

// ---------------- attention pass 1: S_c = K_c^T V_c (in place over K), Z_c into V row0 ----------------
__global__ __launch_bounds__(256) void k_scan_kv(float* KS, float* Vz,
                                                 const float* __restrict__ ct,
                                                 const float* __restrict__ st)
{
    const int c = blockIdx.x, bh = blockIdx.y;
    const int h = bh & 15, b = bh >> 4;
    const int tid = threadIdx.x;
    __shared__ float ks[64][68];
    __shared__ float vs[64][68];
    const size_t rowbase = ((size_t)b * TSEQ + c * 64) * DM + h * 64;
#pragma unroll
    for (int p = 0; p < 8; ++p) {
        int idx = p * 256 + tid;
        int t = idx >> 5, j = idx & 31;
        const size_t base = rowbase + (size_t)t * DM + j;
        float cn = ct[(c * 64 + t) * 32 + j];
        float sn = st[(c * 64 + t) * 32 + j];
        float k1 = KS[base], k2 = KS[base + 32];
        ks[t][j]      = phi_f(k1 * cn - k2 * sn);
        ks[t][j + 32] = phi_f(k1 * sn + k2 * cn);
    }
#pragma unroll
    for (int p = 0; p < 4; ++p) {
        int idx = p * 256 + tid;
        int t = idx >> 4, e4 = (idx & 15) * 4;
        *(float4*)&vs[t][e4] = *(const float4*)&Vz[rowbase + (size_t)t * DM + e4];
    }
    __syncthreads();
    const int e = tid & 63, dg = tid >> 6;
    float acc[16] = {};
    for (int t = 0; t < 64; ++t) {
        float vv = vs[t][e];
#pragma unroll
        for (int qq = 0; qq < 4; ++qq) {
            float4 kq = *(const float4*)&ks[t][dg * 16 + qq * 4];
            acc[qq * 4 + 0] = fmaf(kq.x, vv, acc[qq * 4 + 0]);
            acc[qq * 4 + 1] = fmaf(kq.y, vv, acc[qq * 4 + 1]);
            acc[qq * 4 + 2] = fmaf(kq.z, vv, acc[qq * 4 + 2]);
            acc[qq * 4 + 3] = fmaf(kq.w, vv, acc[qq * 4 + 3]);
        }
    }
#pragma unroll
    for (int i = 0; i < 16; ++i) {
        int d = dg * 16 + i;
        KS[rowbase + (size_t)d * DM + e] = acc[i];
    }
    if (tid < 64) {
        float z = 0.f;
        for (int t = 0; t < 64; ++t) z += ks[t][tid];
        Vz[rowbase + tid] = z;
    }
}

// ---------------- attention pass 2: inclusive prefix over chunks ----------------
__global__ __launch_bounds__(256) void k_scan_prefix(float* S)
{
    const int sg = blockIdx.x, bh = blockIdx.y;
    const int h = bh & 15, b = bh >> 4;
    const int idx = sg * 256 + threadIdx.x;
    const int d = idx >> 6, e = idx & 63;
    const size_t base = (size_t)b * TSEQ * DM + h * 64 + (size_t)d * DM + e;
    float acc = 0.f;
    for (int c = 0; c < 64; ++c) {
        size_t p = base + (size_t)c * 64 * DM;
        acc += S[p];
        S[p] = acc;
    }
}

__global__ void k_zprefix(float* Vz)
{
    const int bh = blockIdx.x;
    const int h = bh & 15, b = bh >> 4;
    const int d = threadIdx.x;
    const size_t base = (size_t)b * TSEQ * DM + h * 64 + d;
    float acc = 0.f;
    for (int c = 0; c < 64; ++c) {
        size_t p = base + (size_t)c * 64 * DM;
        acc += Vz[p];
        Vz[p] = acc;
    }
}

// ---------------- attention pass 3: O = g*(q@S)/(q.Z+eps), split to 3 bf16 planes in Xs ----------------
__global__ __launch_bounds__(256) void k_scan_out(const float* __restrict__ Q,
                                                  const float* __restrict__ S,
                                                  const float* __restrict__ Zv,
                                                  const float* __restrict__ G,
                                                  __hip_bfloat16* __restrict__ Xs,
                                                  const float* __restrict__ ct,
                                                  const float* __restrict__ st)
{
    const int c = blockIdx.x, bh = blockIdx.y;
    const int h = bh & 15, b = bh >> 4;
    const int tid = threadIdx.x;
    __shared__ float qs[64][69];
    __shared__ float Ss[64][68];
    __shared__ float den[64], Zl[64];
    const size_t rowbase = ((size_t)b * TSEQ + c * 64) * DM + h * 64;
#pragma unroll
    for (int p = 0; p < 8; ++p) {
        int idx = p * 256 + tid;
        int t = idx >> 5, j = idx & 31;
        const size_t base = rowbase + (size_t)t * DM + j;
        float cn = ct[(c * 64 + t) * 32 + j];
        float sn = st[(c * 64 + t) * 32 + j];
        float q1 = Q[base], q2 = Q[base + 32];
        qs[t][j]      = phi_f(q1 * cn - q2 * sn);
        qs[t][j + 32] = phi_f(q1 * sn + q2 * cn);
    }
#pragma unroll
    for (int p = 0; p < 4; ++p) {
        int idx = p * 256 + tid;
        int d = idx >> 4, e4 = (idx & 15) * 4;
        *(float4*)&Ss[d][e4] = *(const float4*)&S[rowbase + (size_t)d * DM + e4];
    }
    const int e = tid & 63, tg = tid >> 6;
    float greg[16];
#pragma unroll
    for (int i = 0; i < 16; ++i)
        greg[i] = G[rowbase + (size_t)(tg * 16 + i) * DM + e];
    if (tid < 64) Zl[tid] = Zv[rowbase + tid];
    __syncthreads();
    if (tid < 64) {
        float dd = 0.f;
        for (int d = 0; d < 64; ++d) dd += qs[tid][d] * Zl[d];
        den[tid] = dd + 1e-6f;
    }
    __syncthreads();
    float acc[16] = {};
    for (int d = 0; d < 64; ++d) {
        float sv = Ss[d][e];
#pragma unroll
        for (int i = 0; i < 16; ++i)
            acc[i] = fmaf(qs[tg * 16 + i][d], sv, acc[i]);
    }
    unsigned short* Xu = (unsigned short*)Xs;
#pragma unroll
    for (int i = 0; i < 16; ++i) {
        int t = tg * 16 + i;
        float g = 1.f / (1.f + expf(-greg[i]));
        float o = g * acc[i] / den[t];
        unsigned short b0 = f2bf_bits(o);
        float r1 = o - bf_to_f(b0);
        unsigned short b1 = f2bf_bits(r1);
        float r2 = r1 - bf_to_f(b1);
        unsigned short b2 = f2bf_bits(r2);
        const size_t xb = (size_t)(b * TSEQ + c * 64 + t) * 3072 + h * 64 + e;
        Xu[xb] = b0;
        Xu[xb + 1024] = b1;
        Xu[xb + 2048] = b2;
    }
}

// ---------------- router ----------------
__global__ __launch_bounds__(256) void k_router(const float* __restrict__ X2,
                                                const float* __restrict__ rn2,
                                                const float* __restrict__ ns2,
                                                const float* __restrict__ rW,
                                                const float* __restrict__ rb,
                                                int* __restrict__ route_e,
                                                float* __restrict__ route_g,
                                                float* __restrict__ probs)
{
    const int tok = blockIdx.x * 4 + (threadIdx.x >> 6);
    const int lane = threadIdx.x & 63;
    const float* xr = X2 + (size_t)tok * DM;
    const float rn = rn2[tok];
    float lg[8] = {};
    for (int d = lane; d < DM; d += 64) {
        float xv = xr[d] * rn * ns2[d];
        const float4* w4 = (const float4*)(rW + (size_t)d * 8);
        float4 w0 = w4[0], w1 = w4[1];
        lg[0] += xv * w0.x; lg[1] += xv * w0.y; lg[2] += xv * w0.z; lg[3] += xv * w0.w;
        lg[4] += xv * w1.x; lg[5] += xv * w1.y; lg[6] += xv * w1.z; lg[7] += xv * w1.w;
    }
#pragma unroll
    for (int e = 0; e < 8; ++e)
        for (int off = 32; off; off >>= 1) lg[e] += __shfl_xor(lg[e], off);
    if (lane == 0) {
        float pe[8]; float mx = -1e30f, s = 0.f;
#pragma unroll
        for (int e = 0; e < 8; ++e) { lg[e] += rb[e]; mx = fmaxf(mx, lg[e]); }
#pragma unroll
        for (int e = 0; e < 8; ++e) { pe[e] = expf(lg[e] - mx); s += pe[e]; }
#pragma unroll
        for (int e = 0; e < 8; ++e) { pe[e] /= s; probs[(size_t)tok * 8 + e] = pe[e]; }
        int i1 = 0; float p1 = pe[0];
#pragma unroll
        for (int e = 1; e < 8; ++e) if (pe[e] > p1) { p1 = pe[e]; i1 = e; }
        int i2 = -1; float p2 = -1.f;
#pragma unroll
        for (int e = 0; e < 8; ++e) if (e != i1 && pe[e] > p2) { p2 = pe[e]; i2 = e; }
        const float gsum = p1 + p2;
        route_e[tok * 2] = i1; route_e[tok * 2 + 1] = i2;
        route_g[tok * 2] = p1 / gsum; route_g[tok * 2 + 1] = p2 / gsum;
    }
}

// ---------------- capacity routing ----------------
__global__ __launch_bounds__(256) void k_count(const int* __restrict__ route_e, int* __restrict__ bcnt)
{
    __shared__ int c[8];
    const int tid = threadIdx.x;
    if (tid < 8) c[tid] = 0;
    __syncthreads();
    atomicAdd(&c[route_e[blockIdx.x * 256 + tid]], 1);
    __syncthreads();
    if (tid < 8) bcnt[blockIdx.x * 8 + tid] = c[tid];
}

__global__ void k_scan_blocks(const int* __restrict__ bcnt, int* __restrict__ bbase, int* __restrict__ ctot)
{
    const int e = threadIdx.x;
    if (e < 8) {
        int run = 0;
        for (int b = 0; b < 256; ++b) { bbase[b * 8 + e] = run; run += bcnt[b * 8 + e]; }
        ctot[e] = run;
    }
}

__global__ __launch_bounds__(256) void k_place(const int* __restrict__ route_e,
                                               const float* __restrict__ route_g,
                                               const int* __restrict__ bbase,
                                               int* __restrict__ tokslot,
                                               float* __restrict__ gateslot)
{
    const int tid = threadIdx.x;
    const int a = blockIdx.x * 256 + tid;
    const int e = route_e[a];
    __shared__ int se[256];
    se[tid] = e;
    __syncthreads();
    int rank = 0;
    for (int j = 0; j < tid; ++j) rank += (se[j] == e) ? 1 : 0;
    const int slot = bbase[blockIdx.x * 8 + e] + rank;
    if (slot < CAPE) {
        tokslot[e * CAPE + slot] = a >> 1;
        gateslot[e * CAPE + slot] = route_g[a];
    }
}

// ---------------- aux loss ----------------
__global__ __launch_bounds__(256) void k_aux(const float* __restrict__ probs,
                                             const int* __restrict__ ctot,
                                             float* __restrict__ out_aux)
{
    const int tid = threadIdx.x;
    float part[8] = {};
    for (int i = tid; i < NTOK; i += 256) {
        const float* p = probs + (size_t)i * 8;
#pragma unroll
        for (int e = 0; e < 8; ++e) part[e] += p[e];
    }
    __shared__ float red[256];
    __shared__ float accs[8];
    for (int e = 0; e < 8; ++e) {
        red[tid] = part[e];
        __syncthreads();
        for (int s = 128; s; s >>= 1) { if (tid < s) red[tid] += red[tid + s]; __syncthreads(); }
        if (tid == 0) accs[e] = red[0];
        __syncthreads();
    }
    if (tid == 0) {
        float isum = 0.f, lsum = 0.f, l[8];
        for (int e = 0; e < 8; ++e) isum += accs[e];
        for (int e = 0; e < 8; ++e) { l[e] = fminf((float)ctot[e], (float)CAPE); lsum += l[e]; }
        float aux = 0.f;
        for (int e = 0; e < 8; ++e) aux += (accs[e] / isum) * (l[e] / lsum);
        out_aux[0] = aux * 64.f;
    }
}

// ---------------- f32 -> bf16 transpose (per expert z) ----------------
__global__ void k_transpose_bf16(const float* __restrict__ src, __hip_bfloat16* __restrict__ dst,
                                 int K_, int N_)
{
    __shared__ float t_[32][33];
    const int z = blockIdx.z;
    const float* s = src + (size_t)z * K_ * N_;
    __hip_bfloat16* d = dst + (size_t)z * K_ * N_;
    const int n0 = blockIdx.x * 32, k0 = blockIdx.y * 32;
    const int c = threadIdx.x, r0 = threadIdx.y;
#pragma unroll
    for (int i = 0; i < 4; ++i) { int r = r0 + i * 8; t_[r][c] = s[(size_t)(k0 + r) * N_ + n0 + c]; }
    __syncthreads();
#pragma unroll
    for (int i = 0; i < 4; ++i) { int r = r0 + i * 8; d[(size_t)(n0 + r) * K_ + k0 + c] = __float2bfloat16(t_[c][r]); }
}

extern "C" void kernel_launch(void* const* d_in, const int* in_sizes, int n_in,
                              void* d_out, int out_size, void* d_ws, size_t ws_size,
                              hipStream_t stream)
{
    (void)in_sizes; (void)n_in; (void)out_size;
    const float* x   = (const float*)d_in[0];
    const float* ns1 = (const float*)d_in[1];
    const float* ns2 = (const float*)d_in[2];
    const float* Wq  = (const float*)d_in[3];
    const float* bq  = (const float*)d_in[4];
    const float* Wk  = (const float*)d_in[5];
    const float* bk  = (const float*)d_in[6];
    const float* Wv  = (const float*)d_in[7];
    const float* bv  = (const float*)d_in[8];
    const float* Wg  = (const float*)d_in[9];
    const float* bg  = (const float*)d_in[10];
    const float* Wo  = (const float*)d_in[11];
    const float* bo  = (const float*)d_in[12];
    const float* rW  = (const float*)d_in[13];
    const float* rb  = (const float*)d_in[14];
    const float* W1  = (const float*)d_in[15];
    const float* b1  = (const float*)d_in[16];
    const float* W2  = (const float*)d_in[17];
    const float* b2  = (const float*)d_in[18];
    float* out = (float*)d_out;
    char* wsb = (char*)d_ws;

    constexpr size_t MiB = 1024ull * 1024ull;
    constexpr size_t R = (size_t)NTOK * DM * 4;        // 128 MiB
    constexpr size_t TAIL = 3 * R;
    constexpr size_t OFF_RN1  = TAIL;
    constexpr size_t OFF_RN2  = OFF_RN1 + (size_t)NTOK * 4;
    constexpr size_t OFF_PROB = OFF_RN2 + (size_t)NTOK * 4;
    constexpr size_t OFF_RE   = OFF_PROB + (size_t)NTOK * 8 * 4;
    constexpr size_t OFF_RG   = OFF_RE + (size_t)NTOK * 2 * 4;
    constexpr size_t OFF_BCNT = OFF_RG + (size_t)NTOK * 2 * 4;
    constexpr size_t OFF_BBASE= OFF_BCNT + 256 * 8 * 4;
    constexpr size_t OFF_CTOT = OFF_BBASE + 256 * 8 * 4;
    constexpr size_t OFF_TOK  = OFF_CTOT + 4096;
    constexpr size_t OFF_GATE = OFF_TOK + (size_t)NEXP * CAPE * 4;
    constexpr size_t REQUIRED = OFF_GATE + (size_t)NEXP * CAPE * 4;

    if (ws_size < REQUIRED) {
        k_ws_flag<<<1, 64, 0, stream>>>(out, (float)(ws_size >> 20));
        return;
    }

    // main region layout (within [0, 3R))
    __hip_bfloat16* xn2bf = (__hip_bfloat16*)(wsb);                 // 64 MiB persistent
    __hip_bfloat16* WST   = (__hip_bfloat16*)(wsb + 64 * MiB);      // 5 x 10 MiB = 50 MiB
    __hip_bfloat16* Xs    = (__hip_bfloat16*)(wsb + 114 * MiB);     // 48 MiB per-group
    float* qg = (float*)(wsb + 162 * MiB);                          // 32 MiB
    float* kg = (float*)(wsb + 194 * MiB);                          // 32 MiB
    float* gg = (float*)(wsb + 226 * MiB);                          // 32 MiB (ends 258)
    __hip_bfloat16* W1T  = (__hip_bfloat16*)(wsb + 64 * MiB);       // 64 MiB (after WST dead)
    __hip_bfloat16* W2T  = (__hip_bfloat16*)(wsb + 128 * MiB);      // 64 MiB
    __hip_bfloat16* Hbuf = (__hip_bfloat16*)(wsb + 192 * MiB);      // 120 MiB (ends 312)

    float* rn2 = (float*)(wsb + OFF_RN2);
    float* probs = (float*)(wsb + OFF_PROB);
    float* rope_ct = (float*)(wsb + OFF_PROB);
    float* rope_st = (float*)(wsb + OFF_PROB + (size_t)TSEQ * 32 * 4);
    int*   route_e = (int*)(wsb + OFF_RE);
    float* route_g = (float*)(wsb + OFF_RG);
    int*   bcnt  = (int*)(wsb + OFF_BCNT);
    int*   bbase = (int*)(wsb + OFF_BBASE);
    int*   ctot  = (int*)(wsb + OFF_CTOT);
    int*   tokslot  = (int*)(wsb + OFF_TOK);
    float* gateslot = (float*)(wsb + OFF_GATE);

    // 0. rope table + weight stacks (w0/w1 split, BT layout)
    k_rope_table<<<512, 256, 0, stream>>>(rope_ct, rope_st);
    {
        WPack WP; WP.W[0] = Wq; WP.W[1] = Wk; WP.W[2] = Wg; WP.W[3] = Wv; WP.W[4] = Wo;
        k_build_wstack<<<dim3(32, 32, 5), 256, 0, stream>>>(WP, WST);
    }

    // 1. per-group: rms-split -> QKVG -> attn (O split fused) -> Wo+resid -> rmsnorm2
    for (int gi = 0; gi < 4; ++gi) {
        const size_t tok0 = (size_t)gi * GTOK;
        const float* xg = x + tok0 * DM;
        float* vg = out + tok0 * DM;

        k_rms_split<true><<<GTOK, 256, 0, stream>>>(xg, ns1, Xs);

        ProjPack P;
        P.BT[0] = WST;                     P.bias[0] = bq; P.C[0] = qg;
        P.BT[1] = WST + (size_t)DM * KSPL; P.bias[1] = bk; P.C[1] = kg;
        P.BT[2] = WST + 2ull * DM * KSPL;  P.bias[2] = bg; P.C[2] = gg;
        P.BT[3] = WST + 3ull * DM * KSPL;  P.bias[3] = bv; P.C[3] = vg;
        k_gemm_proj<4, false><<<dim3(8, GTOK / 128, 4), 256, 0, stream>>>(Xs, P, nullptr);

        k_scan_kv<<<dim3(64, 32), 256, 0, stream>>>(kg, vg, rope_ct, rope_st);
        k_scan_prefix<<<dim3(16, 32), 256, 0, stream>>>(kg);
        k_zprefix<<<32, 64, 0, stream>>>(vg);
        k_scan_out<<<dim3(64, 32), 256, 0, stream>>>(qg, kg, vg, gg, Xs, rope_ct, rope_st);

        ProjPack P2;
        P2.BT[0] = WST + 4ull * DM * KSPL; P2.bias[0] = bo; P2.C[0] = vg;  // x2 -> d_out slice
        P2.BT[1] = P2.BT[2] = P2.BT[3] = P2.BT[0];
        P2.bias[1] = P2.bias[2] = P2.bias[3] = bo;
        P2.C[1] = P2.C[2] = P2.C[3] = vg;
        k_gemm_proj<1, true><<<dim3(8, GTOK / 128, 1), 256, 0, stream>>>(Xs, P2, xg);

        k_rmsnorm_stats<<<GTOK, 256, 0, stream>>>(vg, rn2 + tok0, ns2, xn2bf + tok0 * DM);
    }

    // 2. router (fp32) — overwrites rope table region with probs
    k_router<<<NTOK / 4, 256, 0, stream>>>(out, rn2, ns2, rW, rb, route_e, route_g, probs);

    // 3. capacity routing
    k_count<<<256, 256, 0, stream>>>(route_e, bcnt);
    k_scan_blocks<<<1, 64, 0, stream>>>(bcnt, bbase, ctot);
    k_zero<<<(NEXP * CAPE * 2 + 255) / 256, 256, 0, stream>>>(tokslot, NEXP * CAPE * 2);
    k_place<<<256, 256, 0, stream>>>(route_e, route_g, bbase, tokslot, gateslot);

    // 4. aux loss scalar
    k_aux<<<1, 256, 0, stream>>>(probs, ctot, out + (size_t)NTOK * DM);

    // 5. MoE expert weights (bf16, transposed) + expert MLP in groups of {3,3,2}
    k_transpose_bf16<<<dim3(HIDN / 32, DM / 32, NEXP), dim3(32, 8), 0, stream>>>(W1, W1T, DM, HIDN);
    k_transpose_bf16<<<dim3(DM / 32, HIDN / 32, NEXP), dim3(32, 8), 0, stream>>>(W2, W2T, HIDN, DM);

    for (int g = 0; g < 3; ++g) {
        const int e0 = g * 3;
        const int ecnt = (g == 2) ? 2 : 3;
        k_gemm_bf16<0><<<dim3(HIDN / 128, CAPE / 128, ecnt), 256, 0, stream>>>(
            xn2bf, W1T, b1, Hbuf, nullptr, tokslot, gateslot, DM, HIDN, e0);
        k_gemm_bf16<1><<<dim3(DM / 128, CAPE / 128, ecnt), 256, 0, stream>>>(
            Hbuf, W2T, b2, nullptr, out, tokslot, gateslot, HIDN, DM, e0);
    }
}

// Round 8
// 4508.340 us; speedup vs baseline: 1.2776x; 1.0225x over previous
//
#include <hip/hip_runtime.h>
#include <hip/hip_bf16.h>

#define NTOK 32768
#define TSEQ 4096
#define DM   1024
#define NHEAD 16
#define NEXP 8
#define CAPE 5120
#define HIDN 4096
#define GTOK 8192         // tokens per batch-group (2 sequences)
#define KSPL 5120         // split-GEMM K (3*1024 + 2*1024)

#ifndef __has_builtin
#define __has_builtin(x) 0
#endif
#if __has_builtin(__builtin_amdgcn_global_load_lds)
#define HAVE_GLOAD 1
#else
#define HAVE_GLOAD 0
#endif

typedef __attribute__((ext_vector_type(8))) short bf16x8;
typedef __attribute__((ext_vector_type(4))) float f32x4;

#define WAITCNT8() asm volatile("s_waitcnt vmcnt(8)" ::: "memory")
#define WAITCNT4() asm volatile("s_waitcnt vmcnt(4)" ::: "memory")
#define WAITCNT0() asm volatile("s_waitcnt vmcnt(0)" ::: "memory")
#define RAWBAR()   do { asm volatile("" ::: "memory"); __builtin_amdgcn_s_barrier(); asm volatile("" ::: "memory"); } while (0)

__device__ __forceinline__ float phi_f(float v) { return v > 0.f ? v + 1.f : expf(v); }

__device__ __forceinline__ unsigned short f2bf_bits(float f) {
    __hip_bfloat16 h = __float2bfloat16(f);
    union { __hip_bfloat16 h; unsigned short s; } u;
    u.h = h;
    return u.s;
}
__device__ __forceinline__ float bf_to_f(unsigned short s) {
    unsigned int u = ((unsigned int)s) << 16;
    union { unsigned int u; float f; } w; w.u = u;
    return w.f;
}

__global__ void k_ws_flag(float* out, float v) { if (threadIdx.x == 0) out[0] = v; }

__global__ void k_zero(int* p, int n) {
    int i = blockIdx.x * 256 + threadIdx.x;
    if (i < n) p[i] = 0;
}

// ---------------- rope table ----------------
__global__ __launch_bounds__(256) void k_rope_table(float* __restrict__ ct, float* __restrict__ st)
{
    const int idx = blockIdx.x * 256 + threadIdx.x;
    const int t = idx >> 5, j = idx & 31;
    const float inv = (float)(1.0 / pow(10000.0, (double)j / 32.0));
    float sn, cn;
    sincosf((float)t * inv, &sn, &cn);
    ct[idx] = cn; st[idx] = sn;
}

// ---------------- build W stacks: BT[n, k] bf16, k-> (seg, d); seg<3: w0, else w1 ----------------
struct WPack { const float* W[5]; };
__global__ __launch_bounds__(256) void k_build_wstack(WPack P, __hip_bfloat16* __restrict__ BTbase)
{
    __shared__ float t_[32][33];
    const int z = blockIdx.z;
    const float* Wm = P.W[z];
    __hip_bfloat16* BT = BTbase + (size_t)z * DM * KSPL;
    const int n0 = blockIdx.x * 32, k0 = blockIdx.y * 32;
    const int c = threadIdx.x & 31, r0 = (threadIdx.x >> 5);   // 32 x 8
#pragma unroll
    for (int i = 0; i < 4; ++i) { int r = r0 + i * 8; t_[r][c] = Wm[(size_t)(k0 + r) * DM + n0 + c]; }
    __syncthreads();
#pragma unroll
    for (int i = 0; i < 4; ++i) {
        int r = r0 + i * 8;                       // local n
        float val = t_[c][r];                     // W[k0+c][n0+r]
        unsigned short b0 = f2bf_bits(val);
        float res = val - bf_to_f(b0);
        unsigned short b1 = f2bf_bits(res);
        __hip_bfloat16 h0, h1;
        union { __hip_bfloat16 h; unsigned short s; } u0, u1;
        u0.s = b0; u1.s = b1; h0 = u0.h; h1 = u1.h;
        const size_t nrow = (size_t)(n0 + r) * KSPL + (k0 + c);
        BT[nrow]            = h0;
        BT[nrow + 1024]     = h0;
        BT[nrow + 2048]     = h0;
        BT[nrow + 3072]     = h1;
        BT[nrow + 4096]     = h1;
    }
}

// ---------------- split rows into 3 bf16 planes (rmsnorm-scaled) ----------------
template<bool NORM>
__global__ __launch_bounds__(256) void k_rms_split(const float* __restrict__ X,
                                                   const float* __restrict__ nscale,
                                                   __hip_bfloat16* __restrict__ Xs)
{
    const int row = blockIdx.x;
    const int tid = threadIdx.x;
    const float* xr = X + (size_t)row * DM;
    float4 v = ((const float4*)xr)[tid];
    float r = 1.f;
    if (NORM) {
        float s = v.x * v.x + v.y * v.y + v.z * v.z + v.w * v.w;
        for (int off = 32; off; off >>= 1) s += __shfl_xor(s, off);
        __shared__ float redw[4];
        __shared__ float rbc;
        if ((tid & 63) == 0) redw[tid >> 6] = s;
        __syncthreads();
        if (tid == 0) {
            float tot = redw[0] + redw[1] + redw[2] + redw[3];
            rbc = (float)(1.0 / sqrt((double)tot * (1.0 / 1024.0)));
        }
        __syncthreads();
        r = rbc;
    }
    float c[4] = {v.x, v.y, v.z, v.w};
    if (NORM) {
        float4 ns = ((const float4*)nscale)[tid];
        c[0] *= r * ns.x; c[1] *= r * ns.y; c[2] *= r * ns.z; c[3] *= r * ns.w;
    }
    ushort4 p0, p1, p2;
    unsigned short* q0 = (unsigned short*)&p0;
    unsigned short* q1 = (unsigned short*)&p1;
    unsigned short* q2 = (unsigned short*)&p2;
#pragma unroll
    for (int i = 0; i < 4; ++i) {
        float x = c[i];
        unsigned short b0 = f2bf_bits(x);
        float r1 = x - bf_to_f(b0);
        unsigned short b1 = f2bf_bits(r1);
        float r2 = r1 - bf_to_f(b1);
        unsigned short b2 = f2bf_bits(r2);
        q0[i] = b0; q1[i] = b1; q2[i] = b2;
    }
    __hip_bfloat16* base = Xs + (size_t)row * 3072;
    ((ushort4*)(base))[tid] = p0;
    ((ushort4*)(base + 1024))[tid] = p1;
    ((ushort4*)(base + 2048))[tid] = p2;
}

// ---------------- rmsnorm stats + bf16 normalized rows ----------------
__global__ __launch_bounds__(256) void k_rmsnorm_stats(const float* __restrict__ X,
                                                       float* __restrict__ rn,
                                                       const float* __restrict__ nscale,
                                                       __hip_bfloat16* __restrict__ xbf)
{
    const int row = blockIdx.x;
    const int tid = threadIdx.x;
    const float* xr = X + (size_t)row * DM;
    float4 v = ((const float4*)xr)[tid];
    float s = v.x * v.x + v.y * v.y + v.z * v.z + v.w * v.w;
    for (int off = 32; off; off >>= 1) s += __shfl_xor(s, off);
    __shared__ float redw[4];
    __shared__ float rbc;
    if ((tid & 63) == 0) redw[tid >> 6] = s;
    __syncthreads();
    if (tid == 0) {
        float tot = redw[0] + redw[1] + redw[2] + redw[3];
        float r = (float)(1.0 / sqrt((double)tot * (1.0 / 1024.0)));
        rn[row] = r; rbc = r;
    }
    __syncthreads();
    float r = rbc;
    float4 ns = ((const float4*)nscale)[tid];
    ushort4 o;
    o.x = f2bf_bits(v.x * r * ns.x);
    o.y = f2bf_bits(v.y * r * ns.y);
    o.z = f2bf_bits(v.z * r * ns.z);
    o.w = f2bf_bits(v.w * r * ns.w);
    ((ushort4*)(xbf + (size_t)row * DM))[tid] = o;
}

#if HAVE_GLOAD
__device__ __forceinline__ void gload16(const __hip_bfloat16* g, __hip_bfloat16* l)
{
    __builtin_amdgcn_global_load_lds((const __attribute__((address_space(1))) unsigned int*)g,
                                     (__attribute__((address_space(3))) unsigned int*)l, 16, 0, 0);
}
#endif

// ====== R5 GEMM cores + 3-deep counted-vmcnt pipeline (T4: never drain to 0) ======
// Per iter: WAITCNT(8) [tile t's loads done, t+1/t+2 in flight] -> RAWBAR ->
// ds_read+MFMA on buf[t%3] -> RAWBAR -> stage(t+3) into buf[t%3]. Tail: 8->4->0.

// ---------------- split-precision projection GEMM ----------------
struct ProjPack {
    const __hip_bfloat16* BT[4];
    const float* bias[4];
    float* C[4];
};

template<int NMAT, bool RESID>
__global__ __launch_bounds__(256) void k_gemm_proj(const __hip_bfloat16* __restrict__ A,
                                                   ProjPack P,
                                                   const float* __restrict__ resid)
{
    const int z = (NMAT == 4) ? blockIdx.z : 0;
    const __hip_bfloat16* BT = P.BT[z];
    const float* bias = P.bias[z];
    float* C = P.C[z];
    const int m0 = blockIdx.y * 128;
    const int n0 = blockIdx.x * 128;
    const int tid = threadIdx.x;
    __shared__ alignas(16) __hip_bfloat16 As[3][128 * 32];
    __shared__ alignas(16) __hip_bfloat16 Bs[3][128 * 32];

    const int lane = tid & 63, wv = tid >> 6;
    const int lr = lane & 15, lgp = lane >> 4;
    const int wm = (wv >> 1) * 64, wn = (wv & 1) * 64;

    f32x4 acc[4][4];
#pragma unroll
    for (int i = 0; i < 4; ++i)
#pragma unroll
        for (int j = 0; j < 4; ++j) acc[i][j] = (f32x4){0.f, 0.f, 0.f, 0.f};

    int a_off[4], b_off[4];
#pragma unroll
    for (int i = 0; i < 4; ++i) {
        int mrow = wm + i * 16 + lr;
        a_off[i] = mrow * 32 + ((lgp ^ (mrow & 3)) * 8);
        int nrow = wn + i * 16 + lr;
        b_off[i] = nrow * 32 + ((lgp ^ (nrow & 3)) * 8);
    }

    constexpr int T = KSPL / 32;   // 160

#if HAVE_GLOAD
    const int rA0 = wv * 32 + (lane >> 2), rA1 = rA0 + 16;
    const int ch = lane & 3;
    const __hip_bfloat16* srcA0 = A + (size_t)(m0 + rA0) * 3072 + ((ch ^ (rA0 & 3)) * 8);
    const __hip_bfloat16* srcA1 = A + (size_t)(m0 + rA1) * 3072 + ((ch ^ (rA1 & 3)) * 8);
    const __hip_bfloat16* srcB0 = BT + (size_t)(n0 + rA0) * KSPL + ((ch ^ (rA0 & 3)) * 8);
    const __hip_bfloat16* srcB1 = BT + (size_t)(n0 + rA1) * KSPL + ((ch ^ (rA1 & 3)) * 8);
    const int ldsO0 = (wv * 32) * 32;
    const int ldsO1 = (wv * 32 + 16) * 32;

    auto STAGE = [&](int tile, int buf) {
        const int kb = tile * 32;
        const int acol = (kb < 3072) ? kb : (kb - 3072);
        gload16(srcA0 + acol, &As[buf][ldsO0]);
        gload16(srcA1 + acol, &As[buf][ldsO1]);
        gload16(srcB0 + kb,  &Bs[buf][ldsO0]);
        gload16(srcB1 + kb,  &Bs[buf][ldsO1]);
    };

    STAGE(0, 0); STAGE(1, 1); STAGE(2, 2);
    int buf = 0;
    for (int t = 0; t < T; ++t) {
        if (t <= T - 3)      { WAITCNT8(); }
        else if (t == T - 2) { WAITCNT4(); }
        else                 { WAITCNT0(); }
        RAWBAR();
        bf16x8 af[4], bfr[4];
#pragma unroll
        for (int i = 0; i < 4; ++i) af[i] = *(const bf16x8*)(&As[buf][0] + a_off[i]);
#pragma unroll
        for (int j = 0; j < 4; ++j) bfr[j] = *(const bf16x8*)(&Bs[buf][0] + b_off[j]);
#pragma unroll
        for (int i = 0; i < 4; ++i)
#pragma unroll
            for (int j = 0; j < 4; ++j)
                acc[i][j] = __builtin_amdgcn_mfma_f32_16x16x32_bf16(af[i], bfr[j], acc[i][j], 0, 0, 0);
        if (t + 3 < T) {
            RAWBAR();
            STAGE(t + 3, buf);
        }
        buf = (buf == 2) ? 0 : buf + 1;
    }
#else
    const int ar = tid >> 1, ac0 = (tid & 1) * 2;
    const __hip_bfloat16* Arow = A + (size_t)(m0 + ar) * 3072;
    const __hip_bfloat16* Brow = BT + (size_t)(n0 + ar) * KSPL;
    for (int t = 0; t < T; ++t) {
        const int kb = t * 32;
        const int acol = (kb < 3072) ? kb : (kb - 3072);
        __syncthreads();
        uint4 av0 = *(const uint4*)(Arow + acol + ac0 * 8);
        uint4 av1 = *(const uint4*)(Arow + acol + ac0 * 8 + 8);
        uint4 bv0 = *(const uint4*)(Brow + kb + ac0 * 8);
        uint4 bv1 = *(const uint4*)(Brow + kb + ac0 * 8 + 8);
        *(uint4*)(&As[0][0] + ar * 32 + ((ac0    ) ^ (ar & 3)) * 8) = av0;
        *(uint4*)(&As[0][0] + ar * 32 + ((ac0 + 1) ^ (ar & 3)) * 8) = av1;
        *(uint4*)(&Bs[0][0] + ar * 32 + ((ac0    ) ^ (ar & 3)) * 8) = bv0;
        *(uint4*)(&Bs[0][0] + ar * 32 + ((ac0 + 1) ^ (ar & 3)) * 8) = bv1;
        __syncthreads();
        bf16x8 af[4], bfr[4];
#pragma unroll
        for (int i = 0; i < 4; ++i) af[i] = *(const bf16x8*)(&As[0][0] + a_off[i]);
#pragma unroll
        for (int j = 0; j < 4; ++j) bfr[j] = *(const bf16x8*)(&Bs[0][0] + b_off[j]);
#pragma unroll
        for (int i = 0; i < 4; ++i)
#pragma unroll
            for (int j = 0; j < 4; ++j)
                acc[i][j] = __builtin_amdgcn_mfma_f32_16x16x32_bf16(af[i], bfr[j], acc[i][j], 0, 0, 0);
    }
#endif

#pragma unroll
    for (int i = 0; i < 4; ++i)
#pragma unroll
        for (int j = 0; j < 4; ++j) {
            const int col = n0 + wn + j * 16 + lr;
            const float bval = bias[col];
#pragma unroll
            for (int r = 0; r < 4; ++r) {
                const int rloc = wm + i * 16 + lgp * 4 + r;
                float v = acc[i][j][r] + bval;
                if (RESID) v += resid[(size_t)(m0 + rloc) * DM + col];
                C[(size_t)(m0 + rloc) * DM + col] = v;
            }
        }
}

// ---------------- bf16 MFMA GEMM for experts ----------------
// MODE 0: Hbuf[le][slot] = gelu(xn2bf[tok] @ W1T[e]^T + b1[e])   (K=1024, Nout=4096)
// MODE 1: out[tok] += gate * (Hbuf[le][slot] @ W2T[e]^T + b2[e]) (K=4096, Nout=1024)
template<int MODE>
__global__ __launch_bounds__(256) void k_gemm_bf16(const __hip_bfloat16* __restrict__ A,
                                                   const __hip_bfloat16* __restrict__ BT,
                                                   const float* __restrict__ bias,
                                                   __hip_bfloat16* __restrict__ Hout,
                                                   float* __restrict__ Fout,
                                                   const int* __restrict__ tokslot,
                                                   const float* __restrict__ gateslot,
                                                   int K, int Nout, int e0)
{
    const int le = blockIdx.z;
    const int e = e0 + le;
    const int m0 = blockIdx.y * 128;
    const int n0 = blockIdx.x * 128;
    const int tid = threadIdx.x;
    __shared__ alignas(16) __hip_bfloat16 As[3][128 * 32];
    __shared__ alignas(16) __hip_bfloat16 Bs[3][128 * 32];
    __shared__ int s_tok[128];
    __shared__ float s_gate[128];
    if (tid < 128) {
        s_tok[tid] = tokslot[e * CAPE + m0 + tid];
        s_gate[tid] = gateslot[e * CAPE + m0 + tid];
    }
    __syncthreads();

    const int lane = tid & 63, wv = tid >> 6;
    const int lr = lane & 15, lgp = lane >> 4;
    const int wm = (wv >> 1) * 64, wn = (wv & 1) * 64;

    f32x4 acc[4][4];
#pragma unroll
    for (int i = 0; i < 4; ++i)
#pragma unroll
        for (int j = 0; j < 4; ++j) acc[i][j] = (f32x4){0.f, 0.f, 0.f, 0.f};

    int a_off[4], b_off[4];
#pragma unroll
    for (int i = 0; i < 4; ++i) {
        int mrow = wm + i * 16 + lr;
        a_off[i] = mrow * 32 + ((lgp ^ (mrow & 3)) * 8);
        int nrow = wn + i * 16 + lr;
        b_off[i] = nrow * 32 + ((lgp ^ (nrow & 3)) * 8);
    }

#if HAVE_GLOAD
    const int rA0 = wv * 32 + (lane >> 2), rA1 = rA0 + 16;
    const int ch = lane & 3;
    const __hip_bfloat16 *srcA0, *srcA1;
    if (MODE == 0) {
        srcA0 = A + (size_t)s_tok[rA0] * K + ((ch ^ (rA0 & 3)) * 8);
        srcA1 = A + (size_t)s_tok[rA1] * K + ((ch ^ (rA1 & 3)) * 8);
    } else {
        srcA0 = A + ((size_t)le * CAPE + m0 + rA0) * K + ((ch ^ (rA0 & 3)) * 8);
        srcA1 = A + ((size_t)le * CAPE + m0 + rA1) * K + ((ch ^ (rA1 & 3)) * 8);
    }
    const __hip_bfloat16* srcB0 = BT + ((size_t)e * Nout + n0 + rA0) * K + ((ch ^ (rA0 & 3)) * 8);
    const __hip_bfloat16* srcB1 = BT + ((size_t)e * Nout + n0 + rA1) * K + ((ch ^ (rA1 & 3)) * 8);
    const int ldsO0 = (wv * 32) * 32;
    const int ldsO1 = (wv * 32 + 16) * 32;

    auto STAGE = [&](int tile, int buf) {
        const int kb = tile * 32;
        gload16(srcA0 + kb, &As[buf][ldsO0]);
        gload16(srcA1 + kb, &As[buf][ldsO1]);
        gload16(srcB0 + kb, &Bs[buf][ldsO0]);
        gload16(srcB1 + kb, &Bs[buf][ldsO1]);
    };

    const int T = K / 32;
    STAGE(0, 0); STAGE(1, 1); STAGE(2, 2);
    int buf = 0;
    for (int t = 0; t < T; ++t) {
        if (t <= T - 3)      { WAITCNT8(); }
        else if (t == T - 2) { WAITCNT4(); }
        else                 { WAITCNT0(); }
        RAWBAR();
        bf16x8 af[4], bfr[4];
#pragma unroll
        for (int i = 0; i < 4; ++i) af[i] = *(const bf16x8*)(&As[buf][0] + a_off[i]);
#pragma unroll
        for (int j = 0; j < 4; ++j) bfr[j] = *(const bf16x8*)(&Bs[buf][0] + b_off[j]);
#pragma unroll
        for (int i = 0; i < 4; ++i)
#pragma unroll
            for (int j = 0; j < 4; ++j)
                acc[i][j] = __builtin_amdgcn_mfma_f32_16x16x32_bf16(af[i], bfr[j], acc[i][j], 0, 0, 0);
        if (t + 3 < T) {
            RAWBAR();
            STAGE(t + 3, buf);
        }
        buf = (buf == 2) ? 0 : buf + 1;
    }
#else
    const int ar = tid >> 1, ac0 = (tid & 1) * 2;
    const __hip_bfloat16* Arow;
    if (MODE == 0) Arow = A + (size_t)s_tok[ar] * K;
    else           Arow = A + ((size_t)le * CAPE + m0 + ar) * K;
    const __hip_bfloat16* Brow = BT + ((size_t)e * Nout + n0 + ar) * K;
    for (int k0 = 0; k0 < K; k0 += 32) {
        __syncthreads();
        uint4 av0 = *(const uint4*)(Arow + k0 + ac0 * 8);
        uint4 av1 = *(const uint4*)(Arow + k0 + ac0 * 8 + 8);
        uint4 bv0 = *(const uint4*)(Brow + k0 + ac0 * 8);
        uint4 bv1 = *(const uint4*)(Brow + k0 + ac0 * 8 + 8);
        *(uint4*)(&As[0][0] + ar * 32 + ((ac0    ) ^ (ar & 3)) * 8) = av0;
        *(uint4*)(&As[0][0] + ar * 32 + ((ac0 + 1) ^ (ar & 3)) * 8) = av1;
        *(uint4*)(&Bs[0][0] + ar * 32 + ((ac0    ) ^ (ar & 3)) * 8) = bv0;
        *(uint4*)(&Bs[0][0] + ar * 32 + ((ac0 + 1) ^ (ar & 3)) * 8) = bv1;
        __syncthreads();
        bf16x8 af[4], bfr[4];
#pragma unroll
        for (int i = 0; i < 4; ++i) af[i] = *(const bf16x8*)(&As[0][0] + a_off[i]);
#pragma unroll
        for (int j = 0; j < 4; ++j) bfr[j] = *(const bf16x8*)(&Bs[0][0] + b_off[j]);
#pragma unroll
        for (int i = 0; i < 4; ++i)
#pragma unroll
            for (int j = 0; j < 4; ++j)
                acc[i][j] = __builtin_amdgcn_mfma_f32_16x16x32_bf16(af[i], bfr[j], acc[i][j], 0, 0, 0);
    }
#endif

#pragma unroll
    for (int i = 0; i < 4; ++i)
#pragma unroll
        for (int j = 0; j < 4; ++j) {
            const int col = n0 + wn + j * 16 + lr;
            const float bval = bias[(size_t)e * Nout + col];
#pragma unroll
            for (int r = 0; r < 4; ++r) {
                const int rloc = wm + i * 16 + lgp * 4 + r;
                float v = acc[i][j][r] + bval;
                if (MODE == 0) {
                    v = 0.5f * v * (1.f + erff(v * 0.70710678118654752f));
                    Hout[((size_t)le * CAPE + m0 + rloc) * Nout + col] = __float2bfloat16(v);
                } else {
                    const float g = s_gate[rloc];
                    if (g != 0.f) atomicAdd(&Fout[(size_t)s_tok[rloc] * DM + col], v * g);
                }
            }
        }
}

// ---------------- attention pass 1: S_c = K_c^T V_c (in place over K), Z_c into V row0 ----------------
__global__ __launch_bounds__(256) void k_scan_kv(float* KS, float* Vz,
                                                 const float* __restrict__ ct,
                                                 const float* __restrict__ st)
{
    const int c = blockIdx.x, bh = blockIdx.y;
    const int h = bh & 15, b = bh >> 4;
    const int tid = threadIdx.x;
    __shared__ float ks[64][68];
    __shared__ float vs[64][68];
    const size_t rowbase = ((size_t)b * TSEQ + c * 64) * DM + h * 64;
#pragma unroll
    for (int p = 0; p < 8; ++p) {
        int idx = p * 256 + tid;
        int t = idx >> 5, j = idx & 31;
        const size_t base = rowbase + (size_t)t * DM + j;
        float cn = ct[(c * 64 + t) * 32 + j];
        float sn = st[(c * 64 + t) * 32 + j];
        float k1 = KS[base], k2 = KS[base + 32];
        ks[t][j]      = phi_f(k1 * cn - k2 * sn);
        ks[t][j + 32] = phi_f(k1 * sn + k2 * cn);
    }
#pragma unroll
    for (int p = 0; p < 4; ++p) {
        int idx = p * 256 + tid;
        int t = idx >> 4, e4 = (idx & 15) * 4;
        *(float4*)&vs[t][e4] = *(const float4*)&Vz[rowbase + (size_t)t * DM + e4];
    }
    __syncthreads();
    const int e = tid & 63, dg = tid >> 6;
    float acc[16] = {};
    for (int t = 0; t < 64; ++t) {
        float vv = vs[t][e];
#pragma unroll
        for (int qq = 0; qq < 4; ++qq) {
            float4 kq = *(const float4*)&ks[t][dg * 16 + qq * 4];
            acc[qq * 4 + 0] = fmaf(kq.x, vv, acc[qq * 4 + 0]);
            acc[qq * 4 + 1] = fmaf(kq.y, vv, acc[qq * 4 + 1]);
            acc[qq * 4 + 2] = fmaf(kq.z, vv, acc[qq * 4 + 2]);
            acc[qq * 4 + 3] = fmaf(kq.w, vv, acc[qq * 4 + 3]);
        }
    }
#pragma unroll
    for (int i = 0; i < 16; ++i) {
        int d = dg * 16 + i;
        KS[rowbase + (size_t)d * DM + e] = acc[i];
    }
    if (tid < 64) {
        float z = 0.f;
        for (int t = 0; t < 64; ++t) z += ks[t][tid];
        Vz[rowbase + tid] = z;
    }
}

// ---------------- attention pass 2: inclusive prefix over chunks ----------------
__global__ __launch_bounds__(256) void k_scan_prefix(float* S)
{
    const int sg = blockIdx.x, bh = blockIdx.y;
    const int h = bh & 15, b = bh >> 4;
    const int idx = sg * 256 + threadIdx.x;
    const int d = idx >> 6, e = idx & 63;
    const size_t base = (size_t)b * TSEQ * DM + h * 64 + (size_t)d * DM + e;
    float acc = 0.f;
    for (int c = 0; c < 64; ++c) {
        size_t p = base + (size_t)c * 64 * DM;
        acc += S[p];
        S[p] = acc;
    }
}

__global__ void k_zprefix(float* Vz)
{
    const int bh = blockIdx.x;
    const int h = bh & 15, b = bh >> 4;
    const int d = threadIdx.x;
    const size_t base = (size_t)b * TSEQ * DM + h * 64 + d;
    float acc = 0.f;
    for (int c = 0; c < 64; ++c) {
        size_t p = base + (size_t)c * 64 * DM;
        acc += Vz[p];
        Vz[p] = acc;
    }
}

// ---------------- attention pass 3: O = g*(q@S)/(q.Z+eps), split to 3 bf16 planes in Xs ----------------
__global__ __launch_bounds__(256) void k_scan_out(const float* __restrict__ Q,
                                                  const float* __restrict__ S,
                                                  const float* __restrict__ Zv,
                                                  const float* __restrict__ G,
                                                  __hip_bfloat16* __restrict__ Xs,
                                                  const float* __restrict__ ct,
                                                  const float* __restrict__ st)
{
    const int c = blockIdx.x, bh = blockIdx.y;
    const int h = bh & 15, b = bh >> 4;
    const int tid = threadIdx.x;
    __shared__ float qs[64][69];
    __shared__ float Ss[64][68];
    __shared__ float den[64], Zl[64];
    const size_t rowbase = ((size_t)b * TSEQ + c * 64) * DM + h * 64;
#pragma unroll
    for (int p = 0; p < 8; ++p) {
        int idx = p * 256 + tid;
        int t = idx >> 5, j = idx & 31;
        const size_t base = rowbase + (size_t)t * DM + j;
        float cn = ct[(c * 64 + t) * 32 + j];
        float sn = st[(c * 64 + t) * 32 + j];
        float q1 = Q[base], q2 = Q[base + 32];
        qs[t][j]      = phi_f(q1 * cn - q2 * sn);
        qs[t][j + 32] = phi_f(q1 * sn + q2 * cn);
    }
#pragma unroll
    for (int p = 0; p < 4; ++p) {
        int idx = p * 256 + tid;
        int d = idx >> 4, e4 = (idx & 15) * 4;
        *(float4*)&Ss[d][e4] = *(const float4*)&S[rowbase + (size_t)d * DM + e4];
    }
    const int e = tid & 63, tg = tid >> 6;
    float greg[16];
#pragma unroll
    for (int i = 0; i < 16; ++i)
        greg[i] = G[rowbase + (size_t)(tg * 16 + i) * DM + e];
    if (tid < 64) Zl[tid] = Zv[rowbase + tid];
    __syncthreads();
    if (tid < 64) {
        float dd = 0.f;
        for (int d = 0; d < 64; ++d) dd += qs[tid][d] * Zl[d];
        den[tid] = dd + 1e-6f;
    }
    __syncthreads();
    float acc[16] = {};
    for (int d = 0; d < 64; ++d) {
        float sv = Ss[d][e];
#pragma unroll
        for (int i = 0; i < 16; ++i)
            acc[i] = fmaf(qs[tg * 16 + i][d], sv, acc[i]);
    }
    unsigned short* Xu = (unsigned short*)Xs;
#pragma unroll
    for (int i = 0; i < 16; ++i) {
        int t = tg * 16 + i;
        float g = 1.f / (1.f + expf(-greg[i]));
        float o = g * acc[i] / den[t];
        unsigned short b0 = f2bf_bits(o);
        float r1 = o - bf_to_f(b0);
        unsigned short b1 = f2bf_bits(r1);
        float r2 = r1 - bf_to_f(b1);
        unsigned short b2 = f2bf_bits(r2);
        const size_t xb = (size_t)(b * TSEQ + c * 64 + t) * 3072 + h * 64 + e;
        Xu[xb] = b0;
        Xu[xb + 1024] = b1;
        Xu[xb + 2048] = b2;
    }
}

// ---------------- router ----------------
__global__ __launch_bounds__(256) void k_router(const float* __restrict__ X2,
                                                const float* __restrict__ rn2,
                                                const float* __restrict__ ns2,
                                                const float* __restrict__ rW,
                                                const float* __restrict__ rb,
                                                int* __restrict__ route_e,
                                                float* __restrict__ route_g,
                                                float* __restrict__ probs)
{
    const int tok = blockIdx.x * 4 + (threadIdx.x >> 6);
    const int lane = threadIdx.x & 63;
    const float* xr = X2 + (size_t)tok * DM;
    const float rn = rn2[tok];
    float lg[8] = {};
    for (int d = lane; d < DM; d += 64) {
        float xv = xr[d] * rn * ns2[d];
        const float4* w4 = (const float4*)(rW + (size_t)d * 8);
        float4 w0 = w4[0], w1 = w4[1];
        lg[0] += xv * w0.x; lg[1] += xv * w0.y; lg[2] += xv * w0.z; lg[3] += xv * w0.w;
        lg[4] += xv * w1.x; lg[5] += xv * w1.y; lg[6] += xv * w1.z; lg[7] += xv * w1.w;
    }
#pragma unroll
    for (int e = 0; e < 8; ++e)
        for (int off = 32; off; off >>= 1) lg[e] += __shfl_xor(lg[e], off);
    if (lane == 0) {
        float pe[8]; float mx = -1e30f, s = 0.f;
#pragma unroll
        for (int e = 0; e < 8; ++e) { lg[e] += rb[e]; mx = fmaxf(mx, lg[e]); }
#pragma unroll
        for (int e = 0; e < 8; ++e) { pe[e] = expf(lg[e] - mx); s += pe[e]; }
#pragma unroll
        for (int e = 0; e < 8; ++e) { pe[e] /= s; probs[(size_t)tok * 8 + e] = pe[e]; }
        int i1 = 0; float p1 = pe[0];
#pragma unroll
        for (int e = 1; e < 8; ++e) if (pe[e] > p1) { p1 = pe[e]; i1 = e; }
        int i2 = -1; float p2 = -1.f;
#pragma unroll
        for (int e = 0; e < 8; ++e) if (e != i1 && pe[e] > p2) { p2 = pe[e]; i2 = e; }
        const float gsum = p1 + p2;
        route_e[tok * 2] = i1; route_e[tok * 2 + 1] = i2;
        route_g[tok * 2] = p1 / gsum; route_g[tok * 2 + 1] = p2 / gsum;
    }
}

// ---------------- capacity routing ----------------
__global__ __launch_bounds__(256) void k_count(const int* __restrict__ route_e, int* __restrict__ bcnt)
{
    __shared__ int c[8];
    const int tid = threadIdx.x;
    if (tid < 8) c[tid] = 0;
    __syncthreads();
    atomicAdd(&c[route_e[blockIdx.x * 256 + tid]], 1);
    __syncthreads();
    if (tid < 8) bcnt[blockIdx.x * 8 + tid] = c[tid];
}

__global__ void k_scan_blocks(const int* __restrict__ bcnt, int* __restrict__ bbase, int* __restrict__ ctot)
{
    const int e = threadIdx.x;
    if (e < 8) {
        int run = 0;
        for (int b = 0; b < 256; ++b) { bbase[b * 8 + e] = run; run += bcnt[b * 8 + e]; }
        ctot[e] = run;
    }
}

__global__ __launch_bounds__(256) void k_place(const int* __restrict__ route_e,
                                               const float* __restrict__ route_g,
                                               const int* __restrict__ bbase,
                                               int* __restrict__ tokslot,
                                               float* __restrict__ gateslot)
{
    const int tid = threadIdx.x;
    const int a = blockIdx.x * 256 + tid;
    const int e = route_e[a];
    __shared__ int se[256];
    se[tid] = e;
    __syncthreads();
    int rank = 0;
    for (int j = 0; j < tid; ++j) rank += (se[j] == e) ? 1 : 0;
    const int slot = bbase[blockIdx.x * 8 + e] + rank;
    if (slot < CAPE) {
        tokslot[e * CAPE + slot] = a >> 1;
        gateslot[e * CAPE + slot] = route_g[a];
    }
}

// ---------------- aux loss ----------------
__global__ __launch_bounds__(256) void k_aux(const float* __restrict__ probs,
                                             const int* __restrict__ ctot,
                                             float* __restrict__ out_aux)
{
    const int tid = threadIdx.x;
    float part[8] = {};
    for (int i = tid; i < NTOK; i += 256) {
        const float* p = probs + (size_t)i * 8;
#pragma unroll
        for (int e = 0; e < 8; ++e) part[e] += p[e];
    }
    __shared__ float red[256];
    __shared__ float accs[8];
    for (int e = 0; e < 8; ++e) {
        red[tid] = part[e];
        __syncthreads();
        for (int s = 128; s; s >>= 1) { if (tid < s) red[tid] += red[tid + s]; __syncthreads(); }
        if (tid == 0) accs[e] = red[0];
        __syncthreads();
    }
    if (tid == 0) {
        float isum = 0.f, lsum = 0.f, l[8];
        for (int e = 0; e < 8; ++e) isum += accs[e];
        for (int e = 0; e < 8; ++e) { l[e] = fminf((float)ctot[e], (float)CAPE); lsum += l[e]; }
        float aux = 0.f;
        for (int e = 0; e < 8; ++e) aux += (accs[e] / isum) * (l[e] / lsum);
        out_aux[0] = aux * 64.f;
    }
}

// ---------------- f32 -> bf16 transpose (per expert z) ----------------
__global__ void k_transpose_bf16(const float* __restrict__ src, __hip_bfloat16* __restrict__ dst,
                                 int K_, int N_)
{
    __shared__ float t_[32][33];
    const int z = blockIdx.z;
    const float* s = src + (size_t)z * K_ * N_;
    __hip_bfloat16* d = dst + (size_t)z * K_ * N_;
    const int n0 = blockIdx.x * 32, k0 = blockIdx.y * 32;
    const int c = threadIdx.x, r0 = threadIdx.y;
#pragma unroll
    for (int i = 0; i < 4; ++i) { int r = r0 + i * 8; t_[r][c] = s[(size_t)(k0 + r) * N_ + n0 + c]; }
    __syncthreads();
#pragma unroll
    for (int i = 0; i < 4; ++i) { int r = r0 + i * 8; d[(size_t)(n0 + r) * K_ + k0 + c] = __float2bfloat16(t_[c][r]); }
}

extern "C" void kernel_launch(void* const* d_in, const int* in_sizes, int n_in,
                              void* d_out, int out_size, void* d_ws, size_t ws_size,
                              hipStream_t stream)
{
    (void)in_sizes; (void)n_in; (void)out_size;
    const float* x   = (const float*)d_in[0];
    const float* ns1 = (const float*)d_in[1];
    const float* ns2 = (const float*)d_in[2];
    const float* Wq  = (const float*)d_in[3];
    const float* bq  = (const float*)d_in[4];
    const float* Wk  = (const float*)d_in[5];
    const float* bk  = (const float*)d_in[6];
    const float* Wv  = (const float*)d_in[7];
    const float* bv  = (const float*)d_in[8];
    const float* Wg  = (const float*)d_in[9];
    const float* bg  = (const float*)d_in[10];
    const float* Wo  = (const float*)d_in[11];
    const float* bo  = (const float*)d_in[12];
    const float* rW  = (const float*)d_in[13];
    const float* rb  = (const float*)d_in[14];
    const float* W1  = (const float*)d_in[15];
    const float* b1  = (const float*)d_in[16];
    const float* W2  = (const float*)d_in[17];
    const float* b2  = (const float*)d_in[18];
    float* out = (float*)d_out;
    char* wsb = (char*)d_ws;

    constexpr size_t MiB = 1024ull * 1024ull;
    constexpr size_t R = (size_t)NTOK * DM * 4;        // 128 MiB
    constexpr size_t TAIL = 3 * R;
    constexpr size_t OFF_RN1  = TAIL;
    constexpr size_t OFF_RN2  = OFF_RN1 + (size_t)NTOK * 4;
    constexpr size_t OFF_PROB = OFF_RN2 + (size_t)NTOK * 4;
    constexpr size_t OFF_RE   = OFF_PROB + (size_t)NTOK * 8 * 4;
    constexpr size_t OFF_RG   = OFF_RE + (size_t)NTOK * 2 * 4;
    constexpr size_t OFF_BCNT = OFF_RG + (size_t)NTOK * 2 * 4;
    constexpr size_t OFF_BBASE= OFF_BCNT + 256 * 8 * 4;
    constexpr size_t OFF_CTOT = OFF_BBASE + 256 * 8 * 4;
    constexpr size_t OFF_TOK  = OFF_CTOT + 4096;
    constexpr size_t OFF_GATE = OFF_TOK + (size_t)NEXP * CAPE * 4;
    constexpr size_t REQUIRED = OFF_GATE + (size_t)NEXP * CAPE * 4;

    if (ws_size < REQUIRED) {
        k_ws_flag<<<1, 64, 0, stream>>>(out, (float)(ws_size >> 20));
        return;
    }

    // main region layout (within [0, 3R))
    __hip_bfloat16* xn2bf = (__hip_bfloat16*)(wsb);                 // 64 MiB persistent
    __hip_bfloat16* WST   = (__hip_bfloat16*)(wsb + 64 * MiB);      // 5 x 10 MiB = 50 MiB
    __hip_bfloat16* Xs    = (__hip_bfloat16*)(wsb + 114 * MiB);     // 48 MiB per-group
    float* qg = (float*)(wsb + 162 * MiB);                          // 32 MiB
    float* kg = (float*)(wsb + 194 * MiB);                          // 32 MiB
    float* gg = (float*)(wsb + 226 * MiB);                          // 32 MiB (ends 258)
    __hip_bfloat16* W1T  = (__hip_bfloat16*)(wsb + 64 * MiB);       // 64 MiB (after WST dead)
    __hip_bfloat16* W2T  = (__hip_bfloat16*)(wsb + 128 * MiB);      // 64 MiB
    __hip_bfloat16* Hbuf = (__hip_bfloat16*)(wsb + 192 * MiB);      // 120 MiB (ends 312)

    float* rn2 = (float*)(wsb + OFF_RN2);
    float* probs = (float*)(wsb + OFF_PROB);
    float* rope_ct = (float*)(wsb + OFF_PROB);
    float* rope_st = (float*)(wsb + OFF_PROB + (size_t)TSEQ * 32 * 4);
    int*   route_e = (int*)(wsb + OFF_RE);
    float* route_g = (float*)(wsb + OFF_RG);
    int*   bcnt  = (int*)(wsb + OFF_BCNT);
    int*   bbase = (int*)(wsb + OFF_BBASE);
    int*   ctot  = (int*)(wsb + OFF_CTOT);
    int*   tokslot  = (int*)(wsb + OFF_TOK);
    float* gateslot = (float*)(wsb + OFF_GATE);

    // 0. rope table + weight stacks (w0/w1 split, BT layout)
    k_rope_table<<<512, 256, 0, stream>>>(rope_ct, rope_st);
    {
        WPack WP; WP.W[0] = Wq; WP.W[1] = Wk; WP.W[2] = Wg; WP.W[3] = Wv; WP.W[4] = Wo;
        k_build_wstack<<<dim3(32, 32, 5), 256, 0, stream>>>(WP, WST);
    }

    // 1. per-group: rms-split -> QKVG -> attn (O split fused) -> Wo+resid -> rmsnorm2
    for (int gi = 0; gi < 4; ++gi) {
        const size_t tok0 = (size_t)gi * GTOK;
        const float* xg = x + tok0 * DM;
        float* vg = out + tok0 * DM;

        k_rms_split<true><<<GTOK, 256, 0, stream>>>(xg, ns1, Xs);

        ProjPack P;
        P.BT[0] = WST;                     P.bias[0] = bq; P.C[0] = qg;
        P.BT[1] = WST + (size_t)DM * KSPL; P.bias[1] = bk; P.C[1] = kg;
        P.BT[2] = WST + 2ull * DM * KSPL;  P.bias[2] = bg; P.C[2] = gg;
        P.BT[3] = WST + 3ull * DM * KSPL;  P.bias[3] = bv; P.C[3] = vg;
        k_gemm_proj<4, false><<<dim3(8, GTOK / 128, 4), 256, 0, stream>>>(Xs, P, nullptr);

        k_scan_kv<<<dim3(64, 32), 256, 0, stream>>>(kg, vg, rope_ct, rope_st);
        k_scan_prefix<<<dim3(16, 32), 256, 0, stream>>>(kg);
        k_zprefix<<<32, 64, 0, stream>>>(vg);
        k_scan_out<<<dim3(64, 32), 256, 0, stream>>>(qg, kg, vg, gg, Xs, rope_ct, rope_st);

        ProjPack P2;
        P2.BT[0] = WST + 4ull * DM * KSPL; P2.bias[0] = bo; P2.C[0] = vg;  // x2 -> d_out slice
        P2.BT[1] = P2.BT[2] = P2.BT[3] = P2.BT[0];
        P2.bias[1] = P2.bias[2] = P2.bias[3] = bo;
        P2.C[1] = P2.C[2] = P2.C[3] = vg;
        k_gemm_proj<1, true><<<dim3(8, GTOK / 128, 1), 256, 0, stream>>>(Xs, P2, xg);

        k_rmsnorm_stats<<<GTOK, 256, 0, stream>>>(vg, rn2 + tok0, ns2, xn2bf + tok0 * DM);
    }

    // 2. router (fp32) — overwrites rope table region with probs
    k_router<<<NTOK / 4, 256, 0, stream>>>(out, rn2, ns2, rW, rb, route_e, route_g, probs);

    // 3. capacity routing
    k_count<<<256, 256, 0, stream>>>(route_e, bcnt);
    k_scan_blocks<<<1, 64, 0, stream>>>(bcnt, bbase, ctot);
    k_zero<<<(NEXP * CAPE * 2 + 255) / 256, 256, 0, stream>>>(tokslot, NEXP * CAPE * 2);
    k_place<<<256, 256, 0, stream>>>(route_e, route_g, bbase, tokslot, gateslot);

    // 4. aux loss scalar
    k_aux<<<1, 256, 0, stream>>>(probs, ctot, out + (size_t)NTOK * DM);

    // 5. MoE expert weights (bf16, transposed) + expert MLP in groups of {3,3,2}
    k_transpose_bf16<<<dim3(HIDN / 32, DM / 32, NEXP), dim3(32, 8), 0, stream>>>(W1, W1T, DM, HIDN);
    k_transpose_bf16<<<dim3(DM / 32, HIDN / 32, NEXP), dim3(32, 8), 0, stream>>>(W2, W2T, HIDN, DM);

    for (int g = 0; g < 3; ++g) {
        const int e0 = g * 3;
        const int ecnt = (g == 2) ? 2 : 3;
        k_gemm_bf16<0><<<dim3(HIDN / 128, CAPE / 128, ecnt), 256, 0, stream>>>(
            xn2bf, W1T, b1, Hbuf, nullptr, tokslot, gateslot, DM, HIDN, e0);
        k_gemm_bf16<1><<<dim3(DM / 128, CAPE / 128, ecnt), 256, 0, stream>>>(
            Hbuf, W2T, b2, nullptr, out, tokslot, gateslot, HIDN, DM, e0);
    }
}

// Round 9
// 4322.089 us; speedup vs baseline: 1.3326x; 1.0431x over previous
//
#include <hip/hip_runtime.h>
#include <hip/hip_bf16.h>

#define NTOK 32768
#define TSEQ 4096
#define DM   1024
#define NHEAD 16
#define NEXP 8
#define CAPE 5120
#define HIDN 4096
#define GTOK 8192         // tokens per batch-group (2 sequences)
#define KSPL 5120         // split-GEMM logical K (3*1024 + 2*1024)
#define KW   2048         // dedup W-stack row stride (w0 | w1)

#ifndef __has_builtin
#define __has_builtin(x) 0
#endif
#if __has_builtin(__builtin_amdgcn_global_load_lds)
#define HAVE_GLOAD 1
#else
#define HAVE_GLOAD 0
#endif

typedef __attribute__((ext_vector_type(8))) short bf16x8;
typedef __attribute__((ext_vector_type(4))) float f32x4;

#define WAITCNT8() asm volatile("s_waitcnt vmcnt(8)" ::: "memory")
#define WAITCNT4() asm volatile("s_waitcnt vmcnt(4)" ::: "memory")
#define WAITCNT0() asm volatile("s_waitcnt vmcnt(0)" ::: "memory")
#define RAWBAR()   do { asm volatile("" ::: "memory"); __builtin_amdgcn_s_barrier(); asm volatile("" ::: "memory"); } while (0)

__device__ __forceinline__ float phi_f(float v) { return v > 0.f ? v + 1.f : expf(v); }

__device__ __forceinline__ unsigned short f2bf_bits(float f) {
    __hip_bfloat16 h = __float2bfloat16(f);
    union { __hip_bfloat16 h; unsigned short s; } u;
    u.h = h;
    return u.s;
}
__device__ __forceinline__ float bf_to_f(unsigned short s) {
    unsigned int u = ((unsigned int)s) << 16;
    union { unsigned int u; float f; } w; w.u = u;
    return w.f;
}

__global__ void k_ws_flag(float* out, float v) { if (threadIdx.x == 0) out[0] = v; }

__global__ void k_zero(int* p, int n) {
    int i = blockIdx.x * 256 + threadIdx.x;
    if (i < n) p[i] = 0;
}

// ---------------- rope table ----------------
__global__ __launch_bounds__(256) void k_rope_table(float* __restrict__ ct, float* __restrict__ st)
{
    const int idx = blockIdx.x * 256 + threadIdx.x;
    const int t = idx >> 5, j = idx & 31;
    const float inv = (float)(1.0 / pow(10000.0, (double)j / 32.0));
    float sn, cn;
    sincosf((float)t * inv, &sn, &cn);
    ct[idx] = cn; st[idx] = sn;
}

// ---------------- build dedup W stacks: BT[n][0..1024)=w0, [1024..2048)=w1 ----------------
struct WPack { const float* W[5]; };
__global__ __launch_bounds__(256) void k_build_wstack(WPack P, __hip_bfloat16* __restrict__ BTbase)
{
    __shared__ float t_[32][33];
    const int z = blockIdx.z;
    const float* Wm = P.W[z];
    __hip_bfloat16* BT = BTbase + (size_t)z * DM * KW;
    const int n0 = blockIdx.x * 32, k0 = blockIdx.y * 32;
    const int c = threadIdx.x & 31, r0 = (threadIdx.x >> 5);   // 32 x 8
#pragma unroll
    for (int i = 0; i < 4; ++i) { int r = r0 + i * 8; t_[r][c] = Wm[(size_t)(k0 + r) * DM + n0 + c]; }
    __syncthreads();
#pragma unroll
    for (int i = 0; i < 4; ++i) {
        int r = r0 + i * 8;                       // local n
        float val = t_[c][r];                     // W[k0+c][n0+r]
        unsigned short b0 = f2bf_bits(val);
        float res = val - bf_to_f(b0);
        unsigned short b1 = f2bf_bits(res);
        __hip_bfloat16 h0, h1;
        union { __hip_bfloat16 h; unsigned short s; } u0, u1;
        u0.s = b0; u1.s = b1; h0 = u0.h; h1 = u1.h;
        const size_t nrow = (size_t)(n0 + r) * KW + (k0 + c);
        BT[nrow]        = h0;
        BT[nrow + 1024] = h1;
    }
}

// ---------------- split rows into 3 bf16 planes (rmsnorm-scaled) ----------------
template<bool NORM>
__global__ __launch_bounds__(256) void k_rms_split(const float* __restrict__ X,
                                                   const float* __restrict__ nscale,
                                                   __hip_bfloat16* __restrict__ Xs)
{
    const int row = blockIdx.x;
    const int tid = threadIdx.x;
    const float* xr = X + (size_t)row * DM;
    float4 v = ((const float4*)xr)[tid];
    float r = 1.f;
    if (NORM) {
        float s = v.x * v.x + v.y * v.y + v.z * v.z + v.w * v.w;
        for (int off = 32; off; off >>= 1) s += __shfl_xor(s, off);
        __shared__ float redw[4];
        __shared__ float rbc;
        if ((tid & 63) == 0) redw[tid >> 6] = s;
        __syncthreads();
        if (tid == 0) {
            float tot = redw[0] + redw[1] + redw[2] + redw[3];
            rbc = (float)(1.0 / sqrt((double)tot * (1.0 / 1024.0)));
        }
        __syncthreads();
        r = rbc;
    }
    float c[4] = {v.x, v.y, v.z, v.w};
    if (NORM) {
        float4 ns = ((const float4*)nscale)[tid];
        c[0] *= r * ns.x; c[1] *= r * ns.y; c[2] *= r * ns.z; c[3] *= r * ns.w;
    }
    ushort4 p0, p1, p2;
    unsigned short* q0 = (unsigned short*)&p0;
    unsigned short* q1 = (unsigned short*)&p1;
    unsigned short* q2 = (unsigned short*)&p2;
#pragma unroll
    for (int i = 0; i < 4; ++i) {
        float x = c[i];
        unsigned short b0 = f2bf_bits(x);
        float r1 = x - bf_to_f(b0);
        unsigned short b1 = f2bf_bits(r1);
        float r2 = r1 - bf_to_f(b1);
        unsigned short b2 = f2bf_bits(r2);
        q0[i] = b0; q1[i] = b1; q2[i] = b2;
    }
    __hip_bfloat16* base = Xs + (size_t)row * 3072;
    ((ushort4*)(base))[tid] = p0;
    ((ushort4*)(base + 1024))[tid] = p1;
    ((ushort4*)(base + 2048))[tid] = p2;
}

// ---------------- rmsnorm stats + bf16 normalized rows ----------------
__global__ __launch_bounds__(256) void k_rmsnorm_stats(const float* __restrict__ X,
                                                       float* __restrict__ rn,
                                                       const float* __restrict__ nscale,
                                                       __hip_bfloat16* __restrict__ xbf)
{
    const int row = blockIdx.x;
    const int tid = threadIdx.x;
    const float* xr = X + (size_t)row * DM;
    float4 v = ((const float4*)xr)[tid];
    float s = v.x * v.x + v.y * v.y + v.z * v.z + v.w * v.w;
    for (int off = 32; off; off >>= 1) s += __shfl_xor(s, off);
    __shared__ float redw[4];
    __shared__ float rbc;
    if ((tid & 63) == 0) redw[tid >> 6] = s;
    __syncthreads();
    if (tid == 0) {
        float tot = redw[0] + redw[1] + redw[2] + redw[3];
        float r = (float)(1.0 / sqrt((double)tot * (1.0 / 1024.0)));
        rn[row] = r; rbc = r;
    }
    __syncthreads();
    float r = rbc;
    float4 ns = ((const float4*)nscale)[tid];
    ushort4 o;
    o.x = f2bf_bits(v.x * r * ns.x);
    o.y = f2bf_bits(v.y * r * ns.y);
    o.z = f2bf_bits(v.z * r * ns.z);
    o.w = f2bf_bits(v.w * r * ns.w);
    ((ushort4*)(xbf + (size_t)row * DM))[tid] = o;
}

#if HAVE_GLOAD
__device__ __forceinline__ void gload16(const __hip_bfloat16* g, __hip_bfloat16* l)
{
    __builtin_amdgcn_global_load_lds((const __attribute__((address_space(1))) unsigned int*)g,
                                     (__attribute__((address_space(3))) unsigned int*)l, 16, 0, 0);
}
#endif

// ====== GEMM cores: 3-deep counted-vmcnt pipeline + dedup B addressing ======

// ---------------- split-precision projection GEMM ----------------
struct ProjPack {
    const __hip_bfloat16* BT[4];
    const float* bias[4];
    float* C[4];
};

template<int NMAT, bool RESID>
__global__ __launch_bounds__(256) void k_gemm_proj(const __hip_bfloat16* __restrict__ A,
                                                   ProjPack P,
                                                   const float* __restrict__ resid)
{
    const int z = (NMAT == 4) ? blockIdx.z : 0;
    const __hip_bfloat16* BT = P.BT[z];
    const float* bias = P.bias[z];
    float* C = P.C[z];
    const int m0 = blockIdx.y * 128;
    const int n0 = blockIdx.x * 128;
    const int tid = threadIdx.x;
    __shared__ alignas(16) __hip_bfloat16 As[3][128 * 32];
    __shared__ alignas(16) __hip_bfloat16 Bs[3][128 * 32];

    const int lane = tid & 63, wv = tid >> 6;
    const int lr = lane & 15, lgp = lane >> 4;
    const int wm = (wv >> 1) * 64, wn = (wv & 1) * 64;

    f32x4 acc[4][4];
#pragma unroll
    for (int i = 0; i < 4; ++i)
#pragma unroll
        for (int j = 0; j < 4; ++j) acc[i][j] = (f32x4){0.f, 0.f, 0.f, 0.f};

    int a_off[4], b_off[4];
#pragma unroll
    for (int i = 0; i < 4; ++i) {
        int mrow = wm + i * 16 + lr;
        a_off[i] = mrow * 32 + ((lgp ^ (mrow & 3)) * 8);
        int nrow = wn + i * 16 + lr;
        b_off[i] = nrow * 32 + ((lgp ^ (nrow & 3)) * 8);
    }

    constexpr int T = KSPL / 32;   // 160

#if HAVE_GLOAD
    const int rA0 = wv * 32 + (lane >> 2), rA1 = rA0 + 16;
    const int ch = lane & 3;
    const __hip_bfloat16* srcA0 = A + (size_t)(m0 + rA0) * 3072 + ((ch ^ (rA0 & 3)) * 8);
    const __hip_bfloat16* srcA1 = A + (size_t)(m0 + rA1) * 3072 + ((ch ^ (rA1 & 3)) * 8);
    const __hip_bfloat16* srcB0 = BT + (size_t)(n0 + rA0) * KW + ((ch ^ (rA0 & 3)) * 8);
    const __hip_bfloat16* srcB1 = BT + (size_t)(n0 + rA1) * KW + ((ch ^ (rA1 & 3)) * 8);
    const int ldsO0 = (wv * 32) * 32;
    const int ldsO1 = (wv * 32 + 16) * 32;

    auto STAGE = [&](int tile, int buf) {
        const int kb = tile * 32;
        const int acol = (kb < 3072) ? kb : (kb - 3072);
        const int bcol = ((kb < 3072) ? 0 : 1024) + (kb & 1023);
        gload16(srcA0 + acol, &As[buf][ldsO0]);
        gload16(srcA1 + acol, &As[buf][ldsO1]);
        gload16(srcB0 + bcol, &Bs[buf][ldsO0]);
        gload16(srcB1 + bcol, &Bs[buf][ldsO1]);
    };

    STAGE(0, 0); STAGE(1, 1); STAGE(2, 2);
    int buf = 0;
    for (int t = 0; t < T; ++t) {
        if (t <= T - 3)      { WAITCNT8(); }
        else if (t == T - 2) { WAITCNT4(); }
        else                 { WAITCNT0(); }
        RAWBAR();
        bf16x8 af[4], bfr[4];
#pragma unroll
        for (int i = 0; i < 4; ++i) af[i] = *(const bf16x8*)(&As[buf][0] + a_off[i]);
#pragma unroll
        for (int j = 0; j < 4; ++j) bfr[j] = *(const bf16x8*)(&Bs[buf][0] + b_off[j]);
#pragma unroll
        for (int i = 0; i < 4; ++i)
#pragma unroll
            for (int j = 0; j < 4; ++j)
                acc[i][j] = __builtin_amdgcn_mfma_f32_16x16x32_bf16(af[i], bfr[j], acc[i][j], 0, 0, 0);
        if (t + 3 < T) {
            RAWBAR();
            STAGE(t + 3, buf);
        }
        buf = (buf == 2) ? 0 : buf + 1;
    }
#else
    const int ar = tid >> 1, ac0 = (tid & 1) * 2;
    const __hip_bfloat16* Arow = A + (size_t)(m0 + ar) * 3072;
    const __hip_bfloat16* Brow = BT + (size_t)(n0 + ar) * KW;
    for (int t = 0; t < T; ++t) {
        const int kb = t * 32;
        const int acol = (kb < 3072) ? kb : (kb - 3072);
        const int bcol = ((kb < 3072) ? 0 : 1024) + (kb & 1023);
        __syncthreads();
        uint4 av0 = *(const uint4*)(Arow + acol + ac0 * 8);
        uint4 av1 = *(const uint4*)(Arow + acol + ac0 * 8 + 8);
        uint4 bv0 = *(const uint4*)(Brow + bcol + ac0 * 8);
        uint4 bv1 = *(const uint4*)(Brow + bcol + ac0 * 8 + 8);
        *(uint4*)(&As[0][0] + ar * 32 + ((ac0    ) ^ (ar & 3)) * 8) = av0;
        *(uint4*)(&As[0][0] + ar * 32 + ((ac0 + 1) ^ (ar & 3)) * 8) = av1;
        *(uint4*)(&Bs[0][0] + ar * 32 + ((ac0    ) ^ (ar & 3)) * 8) = bv0;
        *(uint4*)(&Bs[0][0] + ar * 32 + ((ac0 + 1) ^ (ar & 3)) * 8) = bv1;
        __syncthreads();
        bf16x8 af[4], bfr[4];
#pragma unroll
        for (int i = 0; i < 4; ++i) af[i] = *(const bf16x8*)(&As[0][0] + a_off[i]);
#pragma unroll
        for (int j = 0; j < 4; ++j) bfr[j] = *(const bf16x8*)(&Bs[0][0] + b_off[j]);
#pragma unroll
        for (int i = 0; i < 4; ++i)
#pragma unroll
            for (int j = 0; j < 4; ++j)
                acc[i][j] = __builtin_amdgcn_mfma_f32_16x16x32_bf16(af[i], bfr[j], acc[i][j], 0, 0, 0);
    }
#endif

#pragma unroll
    for (int i = 0; i < 4; ++i)
#pragma unroll
        for (int j = 0; j < 4; ++j) {
            const int col = n0 + wn + j * 16 + lr;
            const float bval = bias[col];
#pragma unroll
            for (int r = 0; r < 4; ++r) {
                const int rloc = wm + i * 16 + lgp * 4 + r;
                float v = acc[i][j][r] + bval;
                if (RESID) v += resid[(size_t)(m0 + rloc) * DM + col];
                C[(size_t)(m0 + rloc) * DM + col] = v;
            }
        }
}

// ---------------- bf16 MFMA GEMM for experts ----------------
// MODE 0: grid (n, m, e): Hbuf[le][slot] = gelu(xn2bf[tok] @ W1T[e]^T + b1[e])
// MODE 1: grid (m, n, e) [swapped for XCD A-locality]: out[tok] += gate*(Hbuf@W2T^T + b2)
template<int MODE>
__global__ __launch_bounds__(256) void k_gemm_bf16(const __hip_bfloat16* __restrict__ A,
                                                   const __hip_bfloat16* __restrict__ BT,
                                                   const float* __restrict__ bias,
                                                   __hip_bfloat16* __restrict__ Hout,
                                                   float* __restrict__ Fout,
                                                   const int* __restrict__ tokslot,
                                                   const float* __restrict__ gateslot,
                                                   int K, int Nout, int e0)
{
    const int le = blockIdx.z;
    const int e = e0 + le;
    const int m0 = (MODE == 1 ? blockIdx.x : blockIdx.y) * 128;
    const int n0 = (MODE == 1 ? blockIdx.y : blockIdx.x) * 128;
    const int tid = threadIdx.x;
    __shared__ alignas(16) __hip_bfloat16 As[3][128 * 32];
    __shared__ alignas(16) __hip_bfloat16 Bs[3][128 * 32];
    __shared__ int s_tok[128];
    __shared__ float s_gate[128];
    if (tid < 128) {
        s_tok[tid] = tokslot[e * CAPE + m0 + tid];
        s_gate[tid] = gateslot[e * CAPE + m0 + tid];
    }
    __syncthreads();

    const int lane = tid & 63, wv = tid >> 6;
    const int lr = lane & 15, lgp = lane >> 4;
    const int wm = (wv >> 1) * 64, wn = (wv & 1) * 64;

    f32x4 acc[4][4];
#pragma unroll
    for (int i = 0; i < 4; ++i)
#pragma unroll
        for (int j = 0; j < 4; ++j) acc[i][j] = (f32x4){0.f, 0.f, 0.f, 0.f};

    int a_off[4], b_off[4];
#pragma unroll
    for (int i = 0; i < 4; ++i) {
        int mrow = wm + i * 16 + lr;
        a_off[i] = mrow * 32 + ((lgp ^ (mrow & 3)) * 8);
        int nrow = wn + i * 16 + lr;
        b_off[i] = nrow * 32 + ((lgp ^ (nrow & 3)) * 8);
    }

#if HAVE_GLOAD
    const int rA0 = wv * 32 + (lane >> 2), rA1 = rA0 + 16;
    const int ch = lane & 3;
    const __hip_bfloat16 *srcA0, *srcA1;
    if (MODE == 0) {
        srcA0 = A + (size_t)s_tok[rA0] * K + ((ch ^ (rA0 & 3)) * 8);
        srcA1 = A + (size_t)s_tok[rA1] * K + ((ch ^ (rA1 & 3)) * 8);
    } else {
        srcA0 = A + ((size_t)le * CAPE + m0 + rA0) * K + ((ch ^ (rA0 & 3)) * 8);
        srcA1 = A + ((size_t)le * CAPE + m0 + rA1) * K + ((ch ^ (rA1 & 3)) * 8);
    }
    const __hip_bfloat16* srcB0 = BT + ((size_t)e * Nout + n0 + rA0) * K + ((ch ^ (rA0 & 3)) * 8);
    const __hip_bfloat16* srcB1 = BT + ((size_t)e * Nout + n0 + rA1) * K + ((ch ^ (rA1 & 3)) * 8);
    const int ldsO0 = (wv * 32) * 32;
    const int ldsO1 = (wv * 32 + 16) * 32;

    auto STAGE = [&](int tile, int buf) {
        const int kb = tile * 32;
        gload16(srcA0 + kb, &As[buf][ldsO0]);
        gload16(srcA1 + kb, &As[buf][ldsO1]);
        gload16(srcB0 + kb, &Bs[buf][ldsO0]);
        gload16(srcB1 + kb, &Bs[buf][ldsO1]);
    };

    const int T = K / 32;
    STAGE(0, 0); STAGE(1, 1); STAGE(2, 2);
    int buf = 0;
    for (int t = 0; t < T; ++t) {
        if (t <= T - 3)      { WAITCNT8(); }
        else if (t == T - 2) { WAITCNT4(); }
        else                 { WAITCNT0(); }
        RAWBAR();
        bf16x8 af[4], bfr[4];
#pragma unroll
        for (int i = 0; i < 4; ++i) af[i] = *(const bf16x8*)(&As[buf][0] + a_off[i]);
#pragma unroll
        for (int j = 0; j < 4; ++j) bfr[j] = *(const bf16x8*)(&Bs[buf][0] + b_off[j]);
#pragma unroll
        for (int i = 0; i < 4; ++i)
#pragma unroll
            for (int j = 0; j < 4; ++j)
                acc[i][j] = __builtin_amdgcn_mfma_f32_16x16x32_bf16(af[i], bfr[j], acc[i][j], 0, 0, 0);
        if (t + 3 < T) {
            RAWBAR();
            STAGE(t + 3, buf);
        }
        buf = (buf == 2) ? 0 : buf + 1;
    }
#else
    const int ar = tid >> 1, ac0 = (tid & 1) * 2;
    const __hip_bfloat16* Arow;
    if (MODE == 0) Arow = A + (size_t)s_tok[ar] * K;
    else           Arow = A + ((size_t)le * CAPE + m0 + ar) * K;
    const __hip_bfloat16* Brow = BT + ((size_t)e * Nout + n0 + ar) * K;
    for (int k0 = 0; k0 < K; k0 += 32) {
        __syncthreads();
        uint4 av0 = *(const uint4*)(Arow + k0 + ac0 * 8);
        uint4 av1 = *(const uint4*)(Arow + k0 + ac0 * 8 + 8);
        uint4 bv0 = *(const uint4*)(Brow + k0 + ac0 * 8);
        uint4 bv1 = *(const uint4*)(Brow + k0 + ac0 * 8 + 8);
        *(uint4*)(&As[0][0] + ar * 32 + ((ac0    ) ^ (ar & 3)) * 8) = av0;
        *(uint4*)(&As[0][0] + ar * 32 + ((ac0 + 1) ^ (ar & 3)) * 8) = av1;
        *(uint4*)(&Bs[0][0] + ar * 32 + ((ac0    ) ^ (ar & 3)) * 8) = bv0;
        *(uint4*)(&Bs[0][0] + ar * 32 + ((ac0 + 1) ^ (ar & 3)) * 8) = bv1;
        __syncthreads();
        bf16x8 af[4], bfr[4];
#pragma unroll
        for (int i = 0; i < 4; ++i) af[i] = *(const bf16x8*)(&As[0][0] + a_off[i]);
#pragma unroll
        for (int j = 0; j < 4; ++j) bfr[j] = *(const bf16x8*)(&Bs[0][0] + b_off[j]);
#pragma unroll
        for (int i = 0; i < 4; ++i)
#pragma unroll
            for (int j = 0; j < 4; ++j)
                acc[i][j] = __builtin_amdgcn_mfma_f32_16x16x32_bf16(af[i], bfr[j], acc[i][j], 0, 0, 0);
    }
#endif

#pragma unroll
    for (int i = 0; i < 4; ++i)
#pragma unroll
        for (int j = 0; j < 4; ++j) {
            const int col = n0 + wn + j * 16 + lr;
            const float bval = bias[(size_t)e * Nout + col];
#pragma unroll
            for (int r = 0; r < 4; ++r) {
                const int rloc = wm + i * 16 + lgp * 4 + r;
                float v = acc[i][j][r] + bval;
                if (MODE == 0) {
                    v = 0.5f * v * (1.f + erff(v * 0.70710678118654752f));
                    Hout[((size_t)le * CAPE + m0 + rloc) * Nout + col] = __float2bfloat16(v);
                } else {
                    const float g = s_gate[rloc];
                    if (g != 0.f) atomicAdd(&Fout[(size_t)s_tok[rloc] * DM + col], v * g);
                }
            }
        }
}

// ---------------- attention pass 1: S_c = K_c^T V_c (in place over K), Z_c into V row0 ----------------
__global__ __launch_bounds__(256) void k_scan_kv(float* KS, float* Vz,
                                                 const float* __restrict__ ct,
                                                 const float* __restrict__ st)
{
    const int c = blockIdx.x, bh = blockIdx.y;
    const int h = bh & 15, b = bh >> 4;
    const int tid = threadIdx.x;
    __shared__ float ks[64][68];
    __shared__ float vs[64][68];
    const size_t rowbase = ((size_t)b * TSEQ + c * 64) * DM + h * 64;
#pragma unroll
    for (int p = 0; p < 8; ++p) {
        int idx = p * 256 + tid;
        int t = idx >> 5, j = idx & 31;
        const size_t base = rowbase + (size_t)t * DM + j;
        float cn = ct[(c * 64 + t) * 32 + j];
        float sn = st[(c * 64 + t) * 32 + j];
        float k1 = KS[base], k2 = KS[base + 32];
        ks[t][j]      = phi_f(k1 * cn - k2 * sn);
        ks[t][j + 32] = phi_f(k1 * sn + k2 * cn);
    }
#pragma unroll
    for (int p = 0; p < 4; ++p) {
        int idx = p * 256 + tid;
        int t = idx >> 4, e4 = (idx & 15) * 4;
        *(float4*)&vs[t][e4] = *(const float4*)&Vz[rowbase + (size_t)t * DM + e4];
    }
    __syncthreads();
    const int e = tid & 63, dg = tid >> 6;
    float acc[16] = {};
    for (int t = 0; t < 64; ++t) {
        float vv = vs[t][e];
#pragma unroll
        for (int qq = 0; qq < 4; ++qq) {
            float4 kq = *(const float4*)&ks[t][dg * 16 + qq * 4];
            acc[qq * 4 + 0] = fmaf(kq.x, vv, acc[qq * 4 + 0]);
            acc[qq * 4 + 1] = fmaf(kq.y, vv, acc[qq * 4 + 1]);
            acc[qq * 4 + 2] = fmaf(kq.z, vv, acc[qq * 4 + 2]);
            acc[qq * 4 + 3] = fmaf(kq.w, vv, acc[qq * 4 + 3]);
        }
    }
#pragma unroll
    for (int i = 0; i < 16; ++i) {
        int d = dg * 16 + i;
        KS[rowbase + (size_t)d * DM + e] = acc[i];
    }
    if (tid < 64) {
        float z = 0.f;
        for (int t = 0; t < 64; ++t) z += ks[t][tid];
        Vz[rowbase + tid] = z;
    }
}

// ---------------- attention pass 2: inclusive prefix over chunks ----------------
__global__ __launch_bounds__(256) void k_scan_prefix(float* S)
{
    const int sg = blockIdx.x, bh = blockIdx.y;
    const int h = bh & 15, b = bh >> 4;
    const int idx = sg * 256 + threadIdx.x;
    const int d = idx >> 6, e = idx & 63;
    const size_t base = (size_t)b * TSEQ * DM + h * 64 + (size_t)d * DM + e;
    float acc = 0.f;
    for (int c = 0; c < 64; ++c) {
        size_t p = base + (size_t)c * 64 * DM;
        acc += S[p];
        S[p] = acc;
    }
}

__global__ void k_zprefix(float* Vz)
{
    const int bh = blockIdx.x;
    const int h = bh & 15, b = bh >> 4;
    const int d = threadIdx.x;
    const size_t base = (size_t)b * TSEQ * DM + h * 64 + d;
    float acc = 0.f;
    for (int c = 0; c < 64; ++c) {
        size_t p = base + (size_t)c * 64 * DM;
        acc += Vz[p];
        Vz[p] = acc;
    }
}

// ---------------- attention pass 3: O = g*(q@S)/(q.Z+eps), split to 3 bf16 planes in Xs ----------------
__global__ __launch_bounds__(256) void k_scan_out(const float* __restrict__ Q,
                                                  const float* __restrict__ S,
                                                  const float* __restrict__ Zv,
                                                  const float* __restrict__ G,
                                                  __hip_bfloat16* __restrict__ Xs,
                                                  const float* __restrict__ ct,
                                                  const float* __restrict__ st)
{
    const int c = blockIdx.x, bh = blockIdx.y;
    const int h = bh & 15, b = bh >> 4;
    const int tid = threadIdx.x;
    __shared__ float qs[64][69];
    __shared__ float Ss[64][68];
    __shared__ float den[64], Zl[64];
    const size_t rowbase = ((size_t)b * TSEQ + c * 64) * DM + h * 64;
#pragma unroll
    for (int p = 0; p < 8; ++p) {
        int idx = p * 256 + tid;
        int t = idx >> 5, j = idx & 31;
        const size_t base = rowbase + (size_t)t * DM + j;
        float cn = ct[(c * 64 + t) * 32 + j];
        float sn = st[(c * 64 + t) * 32 + j];
        float q1 = Q[base], q2 = Q[base + 32];
        qs[t][j]      = phi_f(q1 * cn - q2 * sn);
        qs[t][j + 32] = phi_f(q1 * sn + q2 * cn);
    }
#pragma unroll
    for (int p = 0; p < 4; ++p) {
        int idx = p * 256 + tid;
        int d = idx >> 4, e4 = (idx & 15) * 4;
        *(float4*)&Ss[d][e4] = *(const float4*)&S[rowbase + (size_t)d * DM + e4];
    }
    const int e = tid & 63, tg = tid >> 6;
    float greg[16];
#pragma unroll
    for (int i = 0; i < 16; ++i)
        greg[i] = G[rowbase + (size_t)(tg * 16 + i) * DM + e];
    if (tid < 64) Zl[tid] = Zv[rowbase + tid];
    __syncthreads();
    if (tid < 64) {
        float dd = 0.f;
        for (int d = 0; d < 64; ++d) dd += qs[tid][d] * Zl[d];
        den[tid] = dd + 1e-6f;
    }
    __syncthreads();
    float acc[16] = {};
    for (int d = 0; d < 64; ++d) {
        float sv = Ss[d][e];
#pragma unroll
        for (int i = 0; i < 16; ++i)
            acc[i] = fmaf(qs[tg * 16 + i][d], sv, acc[i]);
    }
    unsigned short* Xu = (unsigned short*)Xs;
#pragma unroll
    for (int i = 0; i < 16; ++i) {
        int t = tg * 16 + i;
        float g = 1.f / (1.f + expf(-greg[i]));
        float o = g * acc[i] / den[t];
        unsigned short b0 = f2bf_bits(o);
        float r1 = o - bf_to_f(b0);
        unsigned short b1 = f2bf_bits(r1);
        float r2 = r1 - bf_to_f(b1);
        unsigned short b2 = f2bf_bits(r2);
        const size_t xb = (size_t)(b * TSEQ + c * 64 + t) * 3072 + h * 64 + e;
        Xu[xb] = b0;
        Xu[xb + 1024] = b1;
        Xu[xb + 2048] = b2;
    }
}

// ---------------- router ----------------
__global__ __launch_bounds__(256) void k_router(const float* __restrict__ X2,
                                                const float* __restrict__ rn2,
                                                const float* __restrict__ ns2,
                                                const float* __restrict__ rW,
                                                const float* __restrict__ rb,
                                                int* __restrict__ route_e,
                                                float* __restrict__ route_g,
                                                float* __restrict__ probs)
{
    const int tok = blockIdx.x * 4 + (threadIdx.x >> 6);
    const int lane = threadIdx.x & 63;
    const float* xr = X2 + (size_t)tok * DM;
    const float rn = rn2[tok];
    float lg[8] = {};
    for (int d = lane; d < DM; d += 64) {
        float xv = xr[d] * rn * ns2[d];
        const float4* w4 = (const float4*)(rW + (size_t)d * 8);
        float4 w0 = w4[0], w1 = w4[1];
        lg[0] += xv * w0.x; lg[1] += xv * w0.y; lg[2] += xv * w0.z; lg[3] += xv * w0.w;
        lg[4] += xv * w1.x; lg[5] += xv * w1.y; lg[6] += xv * w1.z; lg[7] += xv * w1.w;
    }
#pragma unroll
    for (int e = 0; e < 8; ++e)
        for (int off = 32; off; off >>= 1) lg[e] += __shfl_xor(lg[e], off);
    if (lane == 0) {
        float pe[8]; float mx = -1e30f, s = 0.f;
#pragma unroll
        for (int e = 0; e < 8; ++e) { lg[e] += rb[e]; mx = fmaxf(mx, lg[e]); }
#pragma unroll
        for (int e = 0; e < 8; ++e) { pe[e] = expf(lg[e] - mx); s += pe[e]; }
#pragma unroll
        for (int e = 0; e < 8; ++e) { pe[e] /= s; probs[(size_t)tok * 8 + e] = pe[e]; }
        int i1 = 0; float p1 = pe[0];
#pragma unroll
        for (int e = 1; e < 8; ++e) if (pe[e] > p1) { p1 = pe[e]; i1 = e; }
        int i2 = -1; float p2 = -1.f;
#pragma unroll
        for (int e = 0; e < 8; ++e) if (e != i1 && pe[e] > p2) { p2 = pe[e]; i2 = e; }
        const float gsum = p1 + p2;
        route_e[tok * 2] = i1; route_e[tok * 2 + 1] = i2;
        route_g[tok * 2] = p1 / gsum; route_g[tok * 2 + 1] = p2 / gsum;
    }
}

// ---------------- capacity routing ----------------
__global__ __launch_bounds__(256) void k_count(const int* __restrict__ route_e, int* __restrict__ bcnt)
{
    __shared__ int c[8];
    const int tid = threadIdx.x;
    if (tid < 8) c[tid] = 0;
    __syncthreads();
    atomicAdd(&c[route_e[blockIdx.x * 256 + tid]], 1);
    __syncthreads();
    if (tid < 8) bcnt[blockIdx.x * 8 + tid] = c[tid];
}

__global__ void k_scan_blocks(const int* __restrict__ bcnt, int* __restrict__ bbase, int* __restrict__ ctot)
{
    const int e = threadIdx.x;
    if (e < 8) {
        int run = 0;
        for (int b = 0; b < 256; ++b) { bbase[b * 8 + e] = run; run += bcnt[b * 8 + e]; }
        ctot[e] = run;
    }
}

__global__ __launch_bounds__(256) void k_place(const int* __restrict__ route_e,
                                               const float* __restrict__ route_g,
                                               const int* __restrict__ bbase,
                                               int* __restrict__ tokslot,
                                               float* __restrict__ gateslot)
{
    const int tid = threadIdx.x;
    const int a = blockIdx.x * 256 + tid;
    const int e = route_e[a];
    __shared__ int se[256];
    se[tid] = e;
    __syncthreads();
    int rank = 0;
    for (int j = 0; j < tid; ++j) rank += (se[j] == e) ? 1 : 0;
    const int slot = bbase[blockIdx.x * 8 + e] + rank;
    if (slot < CAPE) {
        tokslot[e * CAPE + slot] = a >> 1;
        gateslot[e * CAPE + slot] = route_g[a];
    }
}

// ---------------- aux loss ----------------
__global__ __launch_bounds__(256) void k_aux(const float* __restrict__ probs,
                                             const int* __restrict__ ctot,
                                             float* __restrict__ out_aux)
{
    const int tid = threadIdx.x;
    float part[8] = {};
    for (int i = tid; i < NTOK; i += 256) {
        const float* p = probs + (size_t)i * 8;
#pragma unroll
        for (int e = 0; e < 8; ++e) part[e] += p[e];
    }
    __shared__ float red[256];
    __shared__ float accs[8];
    for (int e = 0; e < 8; ++e) {
        red[tid] = part[e];
        __syncthreads();
        for (int s = 128; s; s >>= 1) { if (tid < s) red[tid] += red[tid + s]; __syncthreads(); }
        if (tid == 0) accs[e] = red[0];
        __syncthreads();
    }
    if (tid == 0) {
        float isum = 0.f, lsum = 0.f, l[8];
        for (int e = 0; e < 8; ++e) isum += accs[e];
        for (int e = 0; e < 8; ++e) { l[e] = fminf((float)ctot[e], (float)CAPE); lsum += l[e]; }
        float aux = 0.f;
        for (int e = 0; e < 8; ++e) aux += (accs[e] / isum) * (l[e] / lsum);
        out_aux[0] = aux * 64.f;
    }
}

// ---------------- f32 -> bf16 transpose (per expert z) ----------------
__global__ void k_transpose_bf16(const float* __restrict__ src, __hip_bfloat16* __restrict__ dst,
                                 int K_, int N_)
{
    __shared__ float t_[32][33];
    const int z = blockIdx.z;
    const float* s = src + (size_t)z * K_ * N_;
    __hip_bfloat16* d = dst + (size_t)z * K_ * N_;
    const int n0 = blockIdx.x * 32, k0 = blockIdx.y * 32;
    const int c = threadIdx.x, r0 = threadIdx.y;
#pragma unroll
    for (int i = 0; i < 4; ++i) { int r = r0 + i * 8; t_[r][c] = s[(size_t)(k0 + r) * N_ + n0 + c]; }
    __syncthreads();
#pragma unroll
    for (int i = 0; i < 4; ++i) { int r = r0 + i * 8; d[(size_t)(n0 + r) * K_ + k0 + c] = __float2bfloat16(t_[c][r]); }
}

extern "C" void kernel_launch(void* const* d_in, const int* in_sizes, int n_in,
                              void* d_out, int out_size, void* d_ws, size_t ws_size,
                              hipStream_t stream)
{
    (void)in_sizes; (void)n_in; (void)out_size;
    const float* x   = (const float*)d_in[0];
    const float* ns1 = (const float*)d_in[1];
    const float* ns2 = (const float*)d_in[2];
    const float* Wq  = (const float*)d_in[3];
    const float* bq  = (const float*)d_in[4];
    const float* Wk  = (const float*)d_in[5];
    const float* bk  = (const float*)d_in[6];
    const float* Wv  = (const float*)d_in[7];
    const float* bv  = (const float*)d_in[8];
    const float* Wg  = (const float*)d_in[9];
    const float* bg  = (const float*)d_in[10];
    const float* Wo  = (const float*)d_in[11];
    const float* bo  = (const float*)d_in[12];
    const float* rW  = (const float*)d_in[13];
    const float* rb  = (const float*)d_in[14];
    const float* W1  = (const float*)d_in[15];
    const float* b1  = (const float*)d_in[16];
    const float* W2  = (const float*)d_in[17];
    const float* b2  = (const float*)d_in[18];
    float* out = (float*)d_out;
    char* wsb = (char*)d_ws;

    constexpr size_t MiB = 1024ull * 1024ull;
    constexpr size_t R = (size_t)NTOK * DM * 4;        // 128 MiB
    constexpr size_t TAIL = 3 * R;
    constexpr size_t OFF_RN1  = TAIL;
    constexpr size_t OFF_RN2  = OFF_RN1 + (size_t)NTOK * 4;
    constexpr size_t OFF_PROB = OFF_RN2 + (size_t)NTOK * 4;
    constexpr size_t OFF_RE   = OFF_PROB + (size_t)NTOK * 8 * 4;
    constexpr size_t OFF_RG   = OFF_RE + (size_t)NTOK * 2 * 4;
    constexpr size_t OFF_BCNT = OFF_RG + (size_t)NTOK * 2 * 4;
    constexpr size_t OFF_BBASE= OFF_BCNT + 256 * 8 * 4;
    constexpr size_t OFF_CTOT = OFF_BBASE + 256 * 8 * 4;
    constexpr size_t OFF_TOK  = OFF_CTOT + 4096;
    constexpr size_t OFF_GATE = OFF_TOK + (size_t)NEXP * CAPE * 4;
    constexpr size_t REQUIRED = OFF_GATE + (size_t)NEXP * CAPE * 4;

    if (ws_size < REQUIRED) {
        k_ws_flag<<<1, 64, 0, stream>>>(out, (float)(ws_size >> 20));
        return;
    }

    // main region layout (within [0, 3R))
    __hip_bfloat16* xn2bf = (__hip_bfloat16*)(wsb);                 // 64 MiB persistent
    __hip_bfloat16* WST   = (__hip_bfloat16*)(wsb + 64 * MiB);      // 5 x 4 MiB = 20 MiB (dedup)
    __hip_bfloat16* Xs    = (__hip_bfloat16*)(wsb + 114 * MiB);     // 48 MiB per-group
    float* qg = (float*)(wsb + 162 * MiB);                          // 32 MiB
    float* kg = (float*)(wsb + 194 * MiB);                          // 32 MiB
    float* gg = (float*)(wsb + 226 * MiB);                          // 32 MiB (ends 258)
    __hip_bfloat16* W1T  = (__hip_bfloat16*)(wsb + 64 * MiB);       // 64 MiB (after WST dead)
    __hip_bfloat16* W2T  = (__hip_bfloat16*)(wsb + 128 * MiB);      // 64 MiB
    __hip_bfloat16* Hbuf = (__hip_bfloat16*)(wsb + 192 * MiB);      // 120 MiB (ends 312)

    float* rn2 = (float*)(wsb + OFF_RN2);
    float* probs = (float*)(wsb + OFF_PROB);
    float* rope_ct = (float*)(wsb + OFF_PROB);
    float* rope_st = (float*)(wsb + OFF_PROB + (size_t)TSEQ * 32 * 4);
    int*   route_e = (int*)(wsb + OFF_RE);
    float* route_g = (float*)(wsb + OFF_RG);
    int*   bcnt  = (int*)(wsb + OFF_BCNT);
    int*   bbase = (int*)(wsb + OFF_BBASE);
    int*   ctot  = (int*)(wsb + OFF_CTOT);
    int*   tokslot  = (int*)(wsb + OFF_TOK);
    float* gateslot = (float*)(wsb + OFF_GATE);

    // 0. rope table + dedup weight stacks (w0|w1)
    k_rope_table<<<512, 256, 0, stream>>>(rope_ct, rope_st);
    {
        WPack WP; WP.W[0] = Wq; WP.W[1] = Wk; WP.W[2] = Wg; WP.W[3] = Wv; WP.W[4] = Wo;
        k_build_wstack<<<dim3(32, 32, 5), 256, 0, stream>>>(WP, WST);
    }

    // 1. per-group: rms-split -> QKVG -> attn (O split fused) -> Wo+resid -> rmsnorm2
    for (int gi = 0; gi < 4; ++gi) {
        const size_t tok0 = (size_t)gi * GTOK;
        const float* xg = x + tok0 * DM;
        float* vg = out + tok0 * DM;

        k_rms_split<true><<<GTOK, 256, 0, stream>>>(xg, ns1, Xs);

        ProjPack P;
        P.BT[0] = WST;                   P.bias[0] = bq; P.C[0] = qg;
        P.BT[1] = WST + (size_t)DM * KW; P.bias[1] = bk; P.C[1] = kg;
        P.BT[2] = WST + 2ull * DM * KW;  P.bias[2] = bg; P.C[2] = gg;
        P.BT[3] = WST + 3ull * DM * KW;  P.bias[3] = bv; P.C[3] = vg;
        k_gemm_proj<4, false><<<dim3(8, GTOK / 128, 4), 256, 0, stream>>>(Xs, P, nullptr);

        k_scan_kv<<<dim3(64, 32), 256, 0, stream>>>(kg, vg, rope_ct, rope_st);
        k_scan_prefix<<<dim3(16, 32), 256, 0, stream>>>(kg);
        k_zprefix<<<32, 64, 0, stream>>>(vg);
        k_scan_out<<<dim3(64, 32), 256, 0, stream>>>(qg, kg, vg, gg, Xs, rope_ct, rope_st);

        ProjPack P2;
        P2.BT[0] = WST + 4ull * DM * KW; P2.bias[0] = bo; P2.C[0] = vg;  // x2 -> d_out slice
        P2.BT[1] = P2.BT[2] = P2.BT[3] = P2.BT[0];
        P2.bias[1] = P2.bias[2] = P2.bias[3] = bo;
        P2.C[1] = P2.C[2] = P2.C[3] = vg;
        k_gemm_proj<1, true><<<dim3(8, GTOK / 128, 1), 256, 0, stream>>>(Xs, P2, xg);

        k_rmsnorm_stats<<<GTOK, 256, 0, stream>>>(vg, rn2 + tok0, ns2, xn2bf + tok0 * DM);
    }

    // 2. router (fp32) — overwrites rope table region with probs
    k_router<<<NTOK / 4, 256, 0, stream>>>(out, rn2, ns2, rW, rb, route_e, route_g, probs);

    // 3. capacity routing
    k_count<<<256, 256, 0, stream>>>(route_e, bcnt);
    k_scan_blocks<<<1, 64, 0, stream>>>(bcnt, bbase, ctot);
    k_zero<<<(NEXP * CAPE * 2 + 255) / 256, 256, 0, stream>>>(tokslot, NEXP * CAPE * 2);
    k_place<<<256, 256, 0, stream>>>(route_e, route_g, bbase, tokslot, gateslot);

    // 4. aux loss scalar
    k_aux<<<1, 256, 0, stream>>>(probs, ctot, out + (size_t)NTOK * DM);

    // 5. MoE expert weights (bf16, transposed) + expert MLP in groups of {3,3,2}
    k_transpose_bf16<<<dim3(HIDN / 32, DM / 32, NEXP), dim3(32, 8), 0, stream>>>(W1, W1T, DM, HIDN);
    k_transpose_bf16<<<dim3(DM / 32, HIDN / 32, NEXP), dim3(32, 8), 0, stream>>>(W2, W2T, HIDN, DM);

    for (int g = 0; g < 3; ++g) {
        const int e0 = g * 3;
        const int ecnt = (g == 2) ? 2 : 3;
        k_gemm_bf16<0><<<dim3(HIDN / 128, CAPE / 128, ecnt), 256, 0, stream>>>(
            xn2bf, W1T, b1, Hbuf, nullptr, tokslot, gateslot, DM, HIDN, e0);
        k_gemm_bf16<1><<<dim3(CAPE / 128, DM / 128, ecnt), 256, 0, stream>>>(
            Hbuf, W2T, b2, nullptr, out, tokslot, gateslot, HIDN, DM, e0);
    }
}

// Round 10
// 4082.714 us; speedup vs baseline: 1.4107x; 1.0586x over previous
//
#include <hip/hip_runtime.h>
#include <hip/hip_bf16.h>

#define NTOK 32768
#define TSEQ 4096
#define DM   1024
#define NHEAD 16
#define NEXP 8
#define CAPE 5120
#define HIDN 4096
#define GTOK 8192         // tokens per batch-group (2 sequences)
#define KSPL 5120         // split-GEMM logical K (3*1024 + 2*1024)
#define KW   2048         // dedup W-stack row stride (w0 | w1)

#ifndef __has_builtin
#define __has_builtin(x) 0
#endif
#if __has_builtin(__builtin_amdgcn_global_load_lds)
#define HAVE_GLOAD 1
#else
#define HAVE_GLOAD 0
#endif

typedef __attribute__((ext_vector_type(8))) short bf16x8;
typedef __attribute__((ext_vector_type(4))) float f32x4;

#define WAITCNT8() asm volatile("s_waitcnt vmcnt(8)" ::: "memory")
#define WAITCNT4() asm volatile("s_waitcnt vmcnt(4)" ::: "memory")
#define WAITCNT0() asm volatile("s_waitcnt vmcnt(0)" ::: "memory")
#define RAWBAR()   do { asm volatile("" ::: "memory"); __builtin_amdgcn_s_barrier(); asm volatile("" ::: "memory"); } while (0)

__device__ __forceinline__ float phi_f(float v) { return v > 0.f ? v + 1.f : expf(v); }

__device__ __forceinline__ unsigned short f2bf_bits(float f) {
    __hip_bfloat16 h = __float2bfloat16(f);
    union { __hip_bfloat16 h; unsigned short s; } u;
    u.h = h;
    return u.s;
}
__device__ __forceinline__ float bf_to_f(unsigned short s) {
    unsigned int u = ((unsigned int)s) << 16;
    union { unsigned int u; float f; } w; w.u = u;
    return w.f;
}

__global__ void k_ws_flag(float* out, float v) { if (threadIdx.x == 0) out[0] = v; }

__global__ void k_zero(int* p, int n) {
    int i = blockIdx.x * 256 + threadIdx.x;
    if (i < n) p[i] = 0;
}

// ---------------- rope table ----------------
__global__ __launch_bounds__(256) void k_rope_table(float* __restrict__ ct, float* __restrict__ st)
{
    const int idx = blockIdx.x * 256 + threadIdx.x;
    const int t = idx >> 5, j = idx & 31;
    const float inv = (float)(1.0 / pow(10000.0, (double)j / 32.0));
    float sn, cn;
    sincosf((float)t * inv, &sn, &cn);
    ct[idx] = cn; st[idx] = sn;
}

// ---------------- build dedup W stacks: BT[n][0..1024)=w0, [1024..2048)=w1 ----------------
struct WPack { const float* W[5]; };
__global__ __launch_bounds__(256) void k_build_wstack(WPack P, __hip_bfloat16* __restrict__ BTbase)
{
    __shared__ float t_[32][33];
    const int z = blockIdx.z;
    const float* Wm = P.W[z];
    __hip_bfloat16* BT = BTbase + (size_t)z * DM * KW;
    const int n0 = blockIdx.x * 32, k0 = blockIdx.y * 32;
    const int c = threadIdx.x & 31, r0 = (threadIdx.x >> 5);   // 32 x 8
#pragma unroll
    for (int i = 0; i < 4; ++i) { int r = r0 + i * 8; t_[r][c] = Wm[(size_t)(k0 + r) * DM + n0 + c]; }
    __syncthreads();
#pragma unroll
    for (int i = 0; i < 4; ++i) {
        int r = r0 + i * 8;                       // local n
        float val = t_[c][r];                     // W[k0+c][n0+r]
        unsigned short b0 = f2bf_bits(val);
        float res = val - bf_to_f(b0);
        unsigned short b1 = f2bf_bits(res);
        __hip_bfloat16 h0, h1;
        union { __hip_bfloat16 h; unsigned short s; } u0, u1;
        u0.s = b0; u1.s = b1; h0 = u0.h; h1 = u1.h;
        const size_t nrow = (size_t)(n0 + r) * KW + (k0 + c);
        BT[nrow]        = h0;
        BT[nrow + 1024] = h1;
    }
}

// ---------------- split rows into 3 bf16 planes (rmsnorm-scaled) ----------------
template<bool NORM>
__global__ __launch_bounds__(256) void k_rms_split(const float* __restrict__ X,
                                                   const float* __restrict__ nscale,
                                                   __hip_bfloat16* __restrict__ Xs)
{
    const int row = blockIdx.x;
    const int tid = threadIdx.x;
    const float* xr = X + (size_t)row * DM;
    float4 v = ((const float4*)xr)[tid];
    float r = 1.f;
    if (NORM) {
        float s = v.x * v.x + v.y * v.y + v.z * v.z + v.w * v.w;
        for (int off = 32; off; off >>= 1) s += __shfl_xor(s, off);
        __shared__ float redw[4];
        __shared__ float rbc;
        if ((tid & 63) == 0) redw[tid >> 6] = s;
        __syncthreads();
        if (tid == 0) {
            float tot = redw[0] + redw[1] + redw[2] + redw[3];
            rbc = (float)(1.0 / sqrt((double)tot * (1.0 / 1024.0)));
        }
        __syncthreads();
        r = rbc;
    }
    float c[4] = {v.x, v.y, v.z, v.w};
    if (NORM) {
        float4 ns = ((const float4*)nscale)[tid];
        c[0] *= r * ns.x; c[1] *= r * ns.y; c[2] *= r * ns.z; c[3] *= r * ns.w;
    }
    ushort4 p0, p1, p2;
    unsigned short* q0 = (unsigned short*)&p0;
    unsigned short* q1 = (unsigned short*)&p1;
    unsigned short* q2 = (unsigned short*)&p2;
#pragma unroll
    for (int i = 0; i < 4; ++i) {
        float x = c[i];
        unsigned short b0 = f2bf_bits(x);
        float r1 = x - bf_to_f(b0);
        unsigned short b1 = f2bf_bits(r1);
        float r2 = r1 - bf_to_f(b1);
        unsigned short b2 = f2bf_bits(r2);
        q0[i] = b0; q1[i] = b1; q2[i] = b2;
    }
    __hip_bfloat16* base = Xs + (size_t)row * 3072;
    ((ushort4*)(base))[tid] = p0;
    ((ushort4*)(base + 1024))[tid] = p1;
    ((ushort4*)(base + 2048))[tid] = p2;
}

// ---------------- rmsnorm stats + bf16 normalized rows ----------------
__global__ __launch_bounds__(256) void k_rmsnorm_stats(const float* __restrict__ X,
                                                       float* __restrict__ rn,
                                                       const float* __restrict__ nscale,
                                                       __hip_bfloat16* __restrict__ xbf)
{
    const int row = blockIdx.x;
    const int tid = threadIdx.x;
    const float* xr = X + (size_t)row * DM;
    float4 v = ((const float4*)xr)[tid];
    float s = v.x * v.x + v.y * v.y + v.z * v.z + v.w * v.w;
    for (int off = 32; off; off >>= 1) s += __shfl_xor(s, off);
    __shared__ float redw[4];
    __shared__ float rbc;
    if ((tid & 63) == 0) redw[tid >> 6] = s;
    __syncthreads();
    if (tid == 0) {
        float tot = redw[0] + redw[1] + redw[2] + redw[3];
        float r = (float)(1.0 / sqrt((double)tot * (1.0 / 1024.0)));
        rn[row] = r; rbc = r;
    }
    __syncthreads();
    float r = rbc;
    float4 ns = ((const float4*)nscale)[tid];
    ushort4 o;
    o.x = f2bf_bits(v.x * r * ns.x);
    o.y = f2bf_bits(v.y * r * ns.y);
    o.z = f2bf_bits(v.z * r * ns.z);
    o.w = f2bf_bits(v.w * r * ns.w);
    ((ushort4*)(xbf + (size_t)row * DM))[tid] = o;
}

#if HAVE_GLOAD
__device__ __forceinline__ void gload16(const __hip_bfloat16* g, __hip_bfloat16* l)
{
    __builtin_amdgcn_global_load_lds((const __attribute__((address_space(1))) unsigned int*)g,
                                     (__attribute__((address_space(3))) unsigned int*)l, 16, 0, 0);
}
#endif

// ====== GEMM cores: 3-deep counted-vmcnt pipeline + dedup B + mat-inner grid ======

// ---------------- split-precision projection GEMM ----------------
// NMAT=4 grid: (n=8, mat=4, m=64) -> per-XCD: 4 mats of one m-tile are adjacent
// dispatches sharing the A tile (L2-hot); A fetched once per XCD, not 4x.
struct ProjPack {
    const __hip_bfloat16* BT[4];
    const float* bias[4];
    float* C[4];
};

template<int NMAT, bool RESID>
__global__ __launch_bounds__(256) void k_gemm_proj(const __hip_bfloat16* __restrict__ A,
                                                   ProjPack P,
                                                   const float* __restrict__ resid)
{
    const int z = (NMAT == 4) ? blockIdx.y : 0;
    const __hip_bfloat16* BT = P.BT[z];
    const float* bias = P.bias[z];
    float* C = P.C[z];
    const int m0 = ((NMAT == 4) ? blockIdx.z : blockIdx.y) * 128;
    const int n0 = blockIdx.x * 128;
    const int tid = threadIdx.x;
    __shared__ alignas(16) __hip_bfloat16 As[3][128 * 32];
    __shared__ alignas(16) __hip_bfloat16 Bs[3][128 * 32];

    const int lane = tid & 63, wv = tid >> 6;
    const int lr = lane & 15, lgp = lane >> 4;
    const int wm = (wv >> 1) * 64, wn = (wv & 1) * 64;

    f32x4 acc[4][4];
#pragma unroll
    for (int i = 0; i < 4; ++i)
#pragma unroll
        for (int j = 0; j < 4; ++j) acc[i][j] = (f32x4){0.f, 0.f, 0.f, 0.f};

    int a_off[4], b_off[4];
#pragma unroll
    for (int i = 0; i < 4; ++i) {
        int mrow = wm + i * 16 + lr;
        a_off[i] = mrow * 32 + ((lgp ^ (mrow & 3)) * 8);
        int nrow = wn + i * 16 + lr;
        b_off[i] = nrow * 32 + ((lgp ^ (nrow & 3)) * 8);
    }

    constexpr int T = KSPL / 32;   // 160

#if HAVE_GLOAD
    const int rA0 = wv * 32 + (lane >> 2), rA1 = rA0 + 16;
    const int ch = lane & 3;
    const __hip_bfloat16* srcA0 = A + (size_t)(m0 + rA0) * 3072 + ((ch ^ (rA0 & 3)) * 8);
    const __hip_bfloat16* srcA1 = A + (size_t)(m0 + rA1) * 3072 + ((ch ^ (rA1 & 3)) * 8);
    const __hip_bfloat16* srcB0 = BT + (size_t)(n0 + rA0) * KW + ((ch ^ (rA0 & 3)) * 8);
    const __hip_bfloat16* srcB1 = BT + (size_t)(n0 + rA1) * KW + ((ch ^ (rA1 & 3)) * 8);
    const int ldsO0 = (wv * 32) * 32;
    const int ldsO1 = (wv * 32 + 16) * 32;

    auto STAGE = [&](int tile, int buf) {
        const int kb = tile * 32;
        const int acol = (kb < 3072) ? kb : (kb - 3072);
        const int bcol = ((kb < 3072) ? 0 : 1024) + (kb & 1023);
        gload16(srcA0 + acol, &As[buf][ldsO0]);
        gload16(srcA1 + acol, &As[buf][ldsO1]);
        gload16(srcB0 + bcol, &Bs[buf][ldsO0]);
        gload16(srcB1 + bcol, &Bs[buf][ldsO1]);
    };

    STAGE(0, 0); STAGE(1, 1); STAGE(2, 2);
    int buf = 0;
    for (int t = 0; t < T; ++t) {
        if (t <= T - 3)      { WAITCNT8(); }
        else if (t == T - 2) { WAITCNT4(); }
        else                 { WAITCNT0(); }
        RAWBAR();
        bf16x8 af[4], bfr[4];
#pragma unroll
        for (int i = 0; i < 4; ++i) af[i] = *(const bf16x8*)(&As[buf][0] + a_off[i]);
#pragma unroll
        for (int j = 0; j < 4; ++j) bfr[j] = *(const bf16x8*)(&Bs[buf][0] + b_off[j]);
#pragma unroll
        for (int i = 0; i < 4; ++i)
#pragma unroll
            for (int j = 0; j < 4; ++j)
                acc[i][j] = __builtin_amdgcn_mfma_f32_16x16x32_bf16(af[i], bfr[j], acc[i][j], 0, 0, 0);
        if (t + 3 < T) {
            RAWBAR();
            STAGE(t + 3, buf);
        }
        buf = (buf == 2) ? 0 : buf + 1;
    }
#else
    const int ar = tid >> 1, ac0 = (tid & 1) * 2;
    const __hip_bfloat16* Arow = A + (size_t)(m0 + ar) * 3072;
    const __hip_bfloat16* Brow = BT + (size_t)(n0 + ar) * KW;
    for (int t = 0; t < T; ++t) {
        const int kb = t * 32;
        const int acol = (kb < 3072) ? kb : (kb - 3072);
        const int bcol = ((kb < 3072) ? 0 : 1024) + (kb & 1023);
        __syncthreads();
        uint4 av0 = *(const uint4*)(Arow + acol + ac0 * 8);
        uint4 av1 = *(const uint4*)(Arow + acol + ac0 * 8 + 8);
        uint4 bv0 = *(const uint4*)(Brow + bcol + ac0 * 8);
        uint4 bv1 = *(const uint4*)(Brow + bcol + ac0 * 8 + 8);
        *(uint4*)(&As[0][0] + ar * 32 + ((ac0    ) ^ (ar & 3)) * 8) = av0;
        *(uint4*)(&As[0][0] + ar * 32 + ((ac0 + 1) ^ (ar & 3)) * 8) = av1;
        *(uint4*)(&Bs[0][0] + ar * 32 + ((ac0    ) ^ (ar & 3)) * 8) = bv0;
        *(uint4*)(&Bs[0][0] + ar * 32 + ((ac0 + 1) ^ (ar & 3)) * 8) = bv1;
        __syncthreads();
        bf16x8 af[4], bfr[4];
#pragma unroll
        for (int i = 0; i < 4; ++i) af[i] = *(const bf16x8*)(&As[0][0] + a_off[i]);
#pragma unroll
        for (int j = 0; j < 4; ++j) bfr[j] = *(const bf16x8*)(&Bs[0][0] + b_off[j]);
#pragma unroll
        for (int i = 0; i < 4; ++i)
#pragma unroll
            for (int j = 0; j < 4; ++j)
                acc[i][j] = __builtin_amdgcn_mfma_f32_16x16x32_bf16(af[i], bfr[j], acc[i][j], 0, 0, 0);
    }
#endif

#pragma unroll
    for (int i = 0; i < 4; ++i)
#pragma unroll
        for (int j = 0; j < 4; ++j) {
            const int col = n0 + wn + j * 16 + lr;
            const float bval = bias[col];
#pragma unroll
            for (int r = 0; r < 4; ++r) {
                const int rloc = wm + i * 16 + lgp * 4 + r;
                float v = acc[i][j][r] + bval;
                if (RESID) v += resid[(size_t)(m0 + rloc) * DM + col];
                C[(size_t)(m0 + rloc) * DM + col] = v;
            }
        }
}

// ---------------- bf16 MFMA GEMM for experts ----------------
// MODE 0: grid (n, m, e): Hbuf[le][slot] = gelu(xn2bf[tok] @ W1T[e]^T + b1[e])
// MODE 1: grid (m, n, e) [swapped for XCD A-locality]: out[tok] += gate*(Hbuf@W2T^T + b2)
template<int MODE>
__global__ __launch_bounds__(256) void k_gemm_bf16(const __hip_bfloat16* __restrict__ A,
                                                   const __hip_bfloat16* __restrict__ BT,
                                                   const float* __restrict__ bias,
                                                   __hip_bfloat16* __restrict__ Hout,
                                                   float* __restrict__ Fout,
                                                   const int* __restrict__ tokslot,
                                                   const float* __restrict__ gateslot,
                                                   int K, int Nout, int e0)
{
    const int le = blockIdx.z;
    const int e = e0 + le;
    const int m0 = (MODE == 1 ? blockIdx.x : blockIdx.y) * 128;
    const int n0 = (MODE == 1 ? blockIdx.y : blockIdx.x) * 128;
    const int tid = threadIdx.x;
    __shared__ alignas(16) __hip_bfloat16 As[3][128 * 32];
    __shared__ alignas(16) __hip_bfloat16 Bs[3][128 * 32];
    __shared__ int s_tok[128];
    __shared__ float s_gate[128];
    if (tid < 128) {
        s_tok[tid] = tokslot[e * CAPE + m0 + tid];
        s_gate[tid] = gateslot[e * CAPE + m0 + tid];
    }
    __syncthreads();

    const int lane = tid & 63, wv = tid >> 6;
    const int lr = lane & 15, lgp = lane >> 4;
    const int wm = (wv >> 1) * 64, wn = (wv & 1) * 64;

    f32x4 acc[4][4];
#pragma unroll
    for (int i = 0; i < 4; ++i)
#pragma unroll
        for (int j = 0; j < 4; ++j) acc[i][j] = (f32x4){0.f, 0.f, 0.f, 0.f};

    int a_off[4], b_off[4];
#pragma unroll
    for (int i = 0; i < 4; ++i) {
        int mrow = wm + i * 16 + lr;
        a_off[i] = mrow * 32 + ((lgp ^ (mrow & 3)) * 8);
        int nrow = wn + i * 16 + lr;
        b_off[i] = nrow * 32 + ((lgp ^ (nrow & 3)) * 8);
    }

#if HAVE_GLOAD
    const int rA0 = wv * 32 + (lane >> 2), rA1 = rA0 + 16;
    const int ch = lane & 3;
    const __hip_bfloat16 *srcA0, *srcA1;
    if (MODE == 0) {
        srcA0 = A + (size_t)s_tok[rA0] * K + ((ch ^ (rA0 & 3)) * 8);
        srcA1 = A + (size_t)s_tok[rA1] * K + ((ch ^ (rA1 & 3)) * 8);
    } else {
        srcA0 = A + ((size_t)le * CAPE + m0 + rA0) * K + ((ch ^ (rA0 & 3)) * 8);
        srcA1 = A + ((size_t)le * CAPE + m0 + rA1) * K + ((ch ^ (rA1 & 3)) * 8);
    }
    const __hip_bfloat16* srcB0 = BT + ((size_t)e * Nout + n0 + rA0) * K + ((ch ^ (rA0 & 3)) * 8);
    const __hip_bfloat16* srcB1 = BT + ((size_t)e * Nout + n0 + rA1) * K + ((ch ^ (rA1 & 3)) * 8);
    const int ldsO0 = (wv * 32) * 32;
    const int ldsO1 = (wv * 32 + 16) * 32;

    auto STAGE = [&](int tile, int buf) {
        const int kb = tile * 32;
        gload16(srcA0 + kb, &As[buf][ldsO0]);
        gload16(srcA1 + kb, &As[buf][ldsO1]);
        gload16(srcB0 + kb, &Bs[buf][ldsO0]);
        gload16(srcB1 + kb, &Bs[buf][ldsO1]);
    };

    const int T = K / 32;
    STAGE(0, 0); STAGE(1, 1); STAGE(2, 2);
    int buf = 0;
    for (int t = 0; t < T; ++t) {
        if (t <= T - 3)      { WAITCNT8(); }
        else if (t == T - 2) { WAITCNT4(); }
        else                 { WAITCNT0(); }
        RAWBAR();
        bf16x8 af[4], bfr[4];
#pragma unroll
        for (int i = 0; i < 4; ++i) af[i] = *(const bf16x8*)(&As[buf][0] + a_off[i]);
#pragma unroll
        for (int j = 0; j < 4; ++j) bfr[j] = *(const bf16x8*)(&Bs[buf][0] + b_off[j]);
#pragma unroll
        for (int i = 0; i < 4; ++i)
#pragma unroll
            for (int j = 0; j < 4; ++j)
                acc[i][j] = __builtin_amdgcn_mfma_f32_16x16x32_bf16(af[i], bfr[j], acc[i][j], 0, 0, 0);
        if (t + 3 < T) {
            RAWBAR();
            STAGE(t + 3, buf);
        }
        buf = (buf == 2) ? 0 : buf + 1;
    }
#else
    const int ar = tid >> 1, ac0 = (tid & 1) * 2;
    const __hip_bfloat16* Arow;
    if (MODE == 0) Arow = A + (size_t)s_tok[ar] * K;
    else           Arow = A + ((size_t)le * CAPE + m0 + ar) * K;
    const __hip_bfloat16* Brow = BT + ((size_t)e * Nout + n0 + ar) * K;
    for (int k0 = 0; k0 < K; k0 += 32) {
        __syncthreads();
        uint4 av0 = *(const uint4*)(Arow + k0 + ac0 * 8);
        uint4 av1 = *(const uint4*)(Arow + k0 + ac0 * 8 + 8);
        uint4 bv0 = *(const uint4*)(Brow + k0 + ac0 * 8);
        uint4 bv1 = *(const uint4*)(Brow + k0 + ac0 * 8 + 8);
        *(uint4*)(&As[0][0] + ar * 32 + ((ac0    ) ^ (ar & 3)) * 8) = av0;
        *(uint4*)(&As[0][0] + ar * 32 + ((ac0 + 1) ^ (ar & 3)) * 8) = av1;
        *(uint4*)(&Bs[0][0] + ar * 32 + ((ac0    ) ^ (ar & 3)) * 8) = bv0;
        *(uint4*)(&Bs[0][0] + ar * 32 + ((ac0 + 1) ^ (ar & 3)) * 8) = bv1;
        __syncthreads();
        bf16x8 af[4], bfr[4];
#pragma unroll
        for (int i = 0; i < 4; ++i) af[i] = *(const bf16x8*)(&As[0][0] + a_off[i]);
#pragma unroll
        for (int j = 0; j < 4; ++j) bfr[j] = *(const bf16x8*)(&Bs[0][0] + b_off[j]);
#pragma unroll
        for (int i = 0; i < 4; ++i)
#pragma unroll
            for (int j = 0; j < 4; ++j)
                acc[i][j] = __builtin_amdgcn_mfma_f32_16x16x32_bf16(af[i], bfr[j], acc[i][j], 0, 0, 0);
    }
#endif

#pragma unroll
    for (int i = 0; i < 4; ++i)
#pragma unroll
        for (int j = 0; j < 4; ++j) {
            const int col = n0 + wn + j * 16 + lr;
            const float bval = bias[(size_t)e * Nout + col];
#pragma unroll
            for (int r = 0; r < 4; ++r) {
                const int rloc = wm + i * 16 + lgp * 4 + r;
                float v = acc[i][j][r] + bval;
                if (MODE == 0) {
                    v = 0.5f * v * (1.f + erff(v * 0.70710678118654752f));
                    Hout[((size_t)le * CAPE + m0 + rloc) * Nout + col] = __float2bfloat16(v);
                } else {
                    const float g = s_gate[rloc];
                    if (g != 0.f) atomicAdd(&Fout[(size_t)s_tok[rloc] * DM + col], v * g);
                }
            }
        }
}

// ---------------- attention pass 1: S_c = K_c^T V_c (in place over K), Z_c into V row0 ----------------
__global__ __launch_bounds__(256) void k_scan_kv(float* KS, float* Vz,
                                                 const float* __restrict__ ct,
                                                 const float* __restrict__ st)
{
    const int c = blockIdx.x, bh = blockIdx.y;
    const int h = bh & 15, b = bh >> 4;
    const int tid = threadIdx.x;
    __shared__ float ks[64][68];
    __shared__ float vs[64][68];
    const size_t rowbase = ((size_t)b * TSEQ + c * 64) * DM + h * 64;
#pragma unroll
    for (int p = 0; p < 8; ++p) {
        int idx = p * 256 + tid;
        int t = idx >> 5, j = idx & 31;
        const size_t base = rowbase + (size_t)t * DM + j;
        float cn = ct[(c * 64 + t) * 32 + j];
        float sn = st[(c * 64 + t) * 32 + j];
        float k1 = KS[base], k2 = KS[base + 32];
        ks[t][j]      = phi_f(k1 * cn - k2 * sn);
        ks[t][j + 32] = phi_f(k1 * sn + k2 * cn);
    }
#pragma unroll
    for (int p = 0; p < 4; ++p) {
        int idx = p * 256 + tid;
        int t = idx >> 4, e4 = (idx & 15) * 4;
        *(float4*)&vs[t][e4] = *(const float4*)&Vz[rowbase + (size_t)t * DM + e4];
    }
    __syncthreads();
    const int e = tid & 63, dg = tid >> 6;
    float acc[16] = {};
    for (int t = 0; t < 64; ++t) {
        float vv = vs[t][e];
#pragma unroll
        for (int qq = 0; qq < 4; ++qq) {
            float4 kq = *(const float4*)&ks[t][dg * 16 + qq * 4];
            acc[qq * 4 + 0] = fmaf(kq.x, vv, acc[qq * 4 + 0]);
            acc[qq * 4 + 1] = fmaf(kq.y, vv, acc[qq * 4 + 1]);
            acc[qq * 4 + 2] = fmaf(kq.z, vv, acc[qq * 4 + 2]);
            acc[qq * 4 + 3] = fmaf(kq.w, vv, acc[qq * 4 + 3]);
        }
    }
#pragma unroll
    for (int i = 0; i < 16; ++i) {
        int d = dg * 16 + i;
        KS[rowbase + (size_t)d * DM + e] = acc[i];
    }
    if (tid < 64) {
        float z = 0.f;
        for (int t = 0; t < 64; ++t) z += ks[t][tid];
        Vz[rowbase + tid] = z;
    }
}

// ---------------- attention pass 2: inclusive prefix over chunks ----------------
__global__ __launch_bounds__(256) void k_scan_prefix(float* S)
{
    const int sg = blockIdx.x, bh = blockIdx.y;
    const int h = bh & 15, b = bh >> 4;
    const int idx = sg * 256 + threadIdx.x;
    const int d = idx >> 6, e = idx & 63;
    const size_t base = (size_t)b * TSEQ * DM + h * 64 + (size_t)d * DM + e;
    float acc = 0.f;
    for (int c = 0; c < 64; ++c) {
        size_t p = base + (size_t)c * 64 * DM;
        acc += S[p];
        S[p] = acc;
    }
}

__global__ void k_zprefix(float* Vz)
{
    const int bh = blockIdx.x;
    const int h = bh & 15, b = bh >> 4;
    const int d = threadIdx.x;
    const size_t base = (size_t)b * TSEQ * DM + h * 64 + d;
    float acc = 0.f;
    for (int c = 0; c < 64; ++c) {
        size_t p = base + (size_t)c * 64 * DM;
        acc += Vz[p];
        Vz[p] = acc;
    }
}

// ---------------- attention pass 3: O = g*(q@S)/(q.Z+eps), split to 3 bf16 planes in Xs ----------------
__global__ __launch_bounds__(256) void k_scan_out(const float* __restrict__ Q,
                                                  const float* __restrict__ S,
                                                  const float* __restrict__ Zv,
                                                  const float* __restrict__ G,
                                                  __hip_bfloat16* __restrict__ Xs,
                                                  const float* __restrict__ ct,
                                                  const float* __restrict__ st)
{
    const int c = blockIdx.x, bh = blockIdx.y;
    const int h = bh & 15, b = bh >> 4;
    const int tid = threadIdx.x;
    __shared__ float qs[64][69];
    __shared__ float Ss[64][68];
    __shared__ float den[64], Zl[64];
    const size_t rowbase = ((size_t)b * TSEQ + c * 64) * DM + h * 64;
#pragma unroll
    for (int p = 0; p < 8; ++p) {
        int idx = p * 256 + tid;
        int t = idx >> 5, j = idx & 31;
        const size_t base = rowbase + (size_t)t * DM + j;
        float cn = ct[(c * 64 + t) * 32 + j];
        float sn = st[(c * 64 + t) * 32 + j];
        float q1 = Q[base], q2 = Q[base + 32];
        qs[t][j]      = phi_f(q1 * cn - q2 * sn);
        qs[t][j + 32] = phi_f(q1 * sn + q2 * cn);
    }
#pragma unroll
    for (int p = 0; p < 4; ++p) {
        int idx = p * 256 + tid;
        int d = idx >> 4, e4 = (idx & 15) * 4;
        *(float4*)&Ss[d][e4] = *(const float4*)&S[rowbase + (size_t)d * DM + e4];
    }
    const int e = tid & 63, tg = tid >> 6;
    float greg[16];
#pragma unroll
    for (int i = 0; i < 16; ++i)
        greg[i] = G[rowbase + (size_t)(tg * 16 + i) * DM + e];
    if (tid < 64) Zl[tid] = Zv[rowbase + tid];
    __syncthreads();
    if (tid < 64) {
        float dd = 0.f;
        for (int d = 0; d < 64; ++d) dd += qs[tid][d] * Zl[d];
        den[tid] = dd + 1e-6f;
    }
    __syncthreads();
    float acc[16] = {};
    for (int d = 0; d < 64; ++d) {
        float sv = Ss[d][e];
#pragma unroll
        for (int i = 0; i < 16; ++i)
            acc[i] = fmaf(qs[tg * 16 + i][d], sv, acc[i]);
    }
    unsigned short* Xu = (unsigned short*)Xs;
#pragma unroll
    for (int i = 0; i < 16; ++i) {
        int t = tg * 16 + i;
        float g = 1.f / (1.f + expf(-greg[i]));
        float o = g * acc[i] / den[t];
        unsigned short b0 = f2bf_bits(o);
        float r1 = o - bf_to_f(b0);
        unsigned short b1 = f2bf_bits(r1);
        float r2 = r1 - bf_to_f(b1);
        unsigned short b2 = f2bf_bits(r2);
        const size_t xb = (size_t)(b * TSEQ + c * 64 + t) * 3072 + h * 64 + e;
        Xu[xb] = b0;
        Xu[xb + 1024] = b1;
        Xu[xb + 2048] = b2;
    }
}

// ---------------- router ----------------
__global__ __launch_bounds__(256) void k_router(const float* __restrict__ X2,
                                                const float* __restrict__ rn2,
                                                const float* __restrict__ ns2,
                                                const float* __restrict__ rW,
                                                const float* __restrict__ rb,
                                                int* __restrict__ route_e,
                                                float* __restrict__ route_g,
                                                float* __restrict__ probs)
{
    const int tok = blockIdx.x * 4 + (threadIdx.x >> 6);
    const int lane = threadIdx.x & 63;
    const float* xr = X2 + (size_t)tok * DM;
    const float rn = rn2[tok];
    float lg[8] = {};
    for (int d = lane; d < DM; d += 64) {
        float xv = xr[d] * rn * ns2[d];
        const float4* w4 = (const float4*)(rW + (size_t)d * 8);
        float4 w0 = w4[0], w1 = w4[1];
        lg[0] += xv * w0.x; lg[1] += xv * w0.y; lg[2] += xv * w0.z; lg[3] += xv * w0.w;
        lg[4] += xv * w1.x; lg[5] += xv * w1.y; lg[6] += xv * w1.z; lg[7] += xv * w1.w;
    }
#pragma unroll
    for (int e = 0; e < 8; ++e)
        for (int off = 32; off; off >>= 1) lg[e] += __shfl_xor(lg[e], off);
    if (lane == 0) {
        float pe[8]; float mx = -1e30f, s = 0.f;
#pragma unroll
        for (int e = 0; e < 8; ++e) { lg[e] += rb[e]; mx = fmaxf(mx, lg[e]); }
#pragma unroll
        for (int e = 0; e < 8; ++e) { pe[e] = expf(lg[e] - mx); s += pe[e]; }
#pragma unroll
        for (int e = 0; e < 8; ++e) { pe[e] /= s; probs[(size_t)tok * 8 + e] = pe[e]; }
        int i1 = 0; float p1 = pe[0];
#pragma unroll
        for (int e = 1; e < 8; ++e) if (pe[e] > p1) { p1 = pe[e]; i1 = e; }
        int i2 = -1; float p2 = -1.f;
#pragma unroll
        for (int e = 0; e < 8; ++e) if (e != i1 && pe[e] > p2) { p2 = pe[e]; i2 = e; }
        const float gsum = p1 + p2;
        route_e[tok * 2] = i1; route_e[tok * 2 + 1] = i2;
        route_g[tok * 2] = p1 / gsum; route_g[tok * 2 + 1] = p2 / gsum;
    }
}

// ---------------- capacity routing ----------------
__global__ __launch_bounds__(256) void k_count(const int* __restrict__ route_e, int* __restrict__ bcnt)
{
    __shared__ int c[8];
    const int tid = threadIdx.x;
    if (tid < 8) c[tid] = 0;
    __syncthreads();
    atomicAdd(&c[route_e[blockIdx.x * 256 + tid]], 1);
    __syncthreads();
    if (tid < 8) bcnt[blockIdx.x * 8 + tid] = c[tid];
}

__global__ void k_scan_blocks(const int* __restrict__ bcnt, int* __restrict__ bbase, int* __restrict__ ctot)
{
    const int e = threadIdx.x;
    if (e < 8) {
        int run = 0;
        for (int b = 0; b < 256; ++b) { bbase[b * 8 + e] = run; run += bcnt[b * 8 + e]; }
        ctot[e] = run;
    }
}

__global__ __launch_bounds__(256) void k_place(const int* __restrict__ route_e,
                                               const float* __restrict__ route_g,
                                               const int* __restrict__ bbase,
                                               int* __restrict__ tokslot,
                                               float* __restrict__ gateslot)
{
    const int tid = threadIdx.x;
    const int a = blockIdx.x * 256 + tid;
    const int e = route_e[a];
    __shared__ int se[256];
    se[tid] = e;
    __syncthreads();
    int rank = 0;
    for (int j = 0; j < tid; ++j) rank += (se[j] == e) ? 1 : 0;
    const int slot = bbase[blockIdx.x * 8 + e] + rank;
    if (slot < CAPE) {
        tokslot[e * CAPE + slot] = a >> 1;
        gateslot[e * CAPE + slot] = route_g[a];
    }
}

// ---------------- aux loss ----------------
__global__ __launch_bounds__(256) void k_aux(const float* __restrict__ probs,
                                             const int* __restrict__ ctot,
                                             float* __restrict__ out_aux)
{
    const int tid = threadIdx.x;
    float part[8] = {};
    for (int i = tid; i < NTOK; i += 256) {
        const float* p = probs + (size_t)i * 8;
#pragma unroll
        for (int e = 0; e < 8; ++e) part[e] += p[e];
    }
    __shared__ float red[256];
    __shared__ float accs[8];
    for (int e = 0; e < 8; ++e) {
        red[tid] = part[e];
        __syncthreads();
        for (int s = 128; s; s >>= 1) { if (tid < s) red[tid] += red[tid + s]; __syncthreads(); }
        if (tid == 0) accs[e] = red[0];
        __syncthreads();
    }
    if (tid == 0) {
        float isum = 0.f, lsum = 0.f, l[8];
        for (int e = 0; e < 8; ++e) isum += accs[e];
        for (int e = 0; e < 8; ++e) { l[e] = fminf((float)ctot[e], (float)CAPE); lsum += l[e]; }
        float aux = 0.f;
        for (int e = 0; e < 8; ++e) aux += (accs[e] / isum) * (l[e] / lsum);
        out_aux[0] = aux * 64.f;
    }
}

// ---------------- f32 -> bf16 transpose (per expert z) ----------------
__global__ void k_transpose_bf16(const float* __restrict__ src, __hip_bfloat16* __restrict__ dst,
                                 int K_, int N_)
{
    __shared__ float t_[32][33];
    const int z = blockIdx.z;
    const float* s = src + (size_t)z * K_ * N_;
    __hip_bfloat16* d = dst + (size_t)z * K_ * N_;
    const int n0 = blockIdx.x * 32, k0 = blockIdx.y * 32;
    const int c = threadIdx.x, r0 = threadIdx.y;
#pragma unroll
    for (int i = 0; i < 4; ++i) { int r = r0 + i * 8; t_[r][c] = s[(size_t)(k0 + r) * N_ + n0 + c]; }
    __syncthreads();
#pragma unroll
    for (int i = 0; i < 4; ++i) { int r = r0 + i * 8; d[(size_t)(n0 + r) * K_ + k0 + c] = __float2bfloat16(t_[c][r]); }
}

extern "C" void kernel_launch(void* const* d_in, const int* in_sizes, int n_in,
                              void* d_out, int out_size, void* d_ws, size_t ws_size,
                              hipStream_t stream)
{
    (void)in_sizes; (void)n_in; (void)out_size;
    const float* x   = (const float*)d_in[0];
    const float* ns1 = (const float*)d_in[1];
    const float* ns2 = (const float*)d_in[2];
    const float* Wq  = (const float*)d_in[3];
    const float* bq  = (const float*)d_in[4];
    const float* Wk  = (const float*)d_in[5];
    const float* bk  = (const float*)d_in[6];
    const float* Wv  = (const float*)d_in[7];
    const float* bv  = (const float*)d_in[8];
    const float* Wg  = (const float*)d_in[9];
    const float* bg  = (const float*)d_in[10];
    const float* Wo  = (const float*)d_in[11];
    const float* bo  = (const float*)d_in[12];
    const float* rW  = (const float*)d_in[13];
    const float* rb  = (const float*)d_in[14];
    const float* W1  = (const float*)d_in[15];
    const float* b1  = (const float*)d_in[16];
    const float* W2  = (const float*)d_in[17];
    const float* b2  = (const float*)d_in[18];
    float* out = (float*)d_out;
    char* wsb = (char*)d_ws;

    constexpr size_t MiB = 1024ull * 1024ull;
    constexpr size_t R = (size_t)NTOK * DM * 4;        // 128 MiB
    constexpr size_t TAIL = 3 * R;
    constexpr size_t OFF_RN1  = TAIL;
    constexpr size_t OFF_RN2  = OFF_RN1 + (size_t)NTOK * 4;
    constexpr size_t OFF_PROB = OFF_RN2 + (size_t)NTOK * 4;
    constexpr size_t OFF_RE   = OFF_PROB + (size_t)NTOK * 8 * 4;
    constexpr size_t OFF_RG   = OFF_RE + (size_t)NTOK * 2 * 4;
    constexpr size_t OFF_BCNT = OFF_RG + (size_t)NTOK * 2 * 4;
    constexpr size_t OFF_BBASE= OFF_BCNT + 256 * 8 * 4;
    constexpr size_t OFF_CTOT = OFF_BBASE + 256 * 8 * 4;
    constexpr size_t OFF_TOK  = OFF_CTOT + 4096;
    constexpr size_t OFF_GATE = OFF_TOK + (size_t)NEXP * CAPE * 4;
    constexpr size_t REQUIRED = OFF_GATE + (size_t)NEXP * CAPE * 4;

    if (ws_size < REQUIRED) {
        k_ws_flag<<<1, 64, 0, stream>>>(out, (float)(ws_size >> 20));
        return;
    }

    // main region layout (within [0, 3R))
    __hip_bfloat16* xn2bf = (__hip_bfloat16*)(wsb);                 // 64 MiB persistent
    __hip_bfloat16* WST   = (__hip_bfloat16*)(wsb + 64 * MiB);      // 5 x 4 MiB = 20 MiB (dedup)
    __hip_bfloat16* Xs    = (__hip_bfloat16*)(wsb + 114 * MiB);     // 48 MiB per-group
    float* qg = (float*)(wsb + 162 * MiB);                          // 32 MiB
    float* kg = (float*)(wsb + 194 * MiB);                          // 32 MiB
    float* gg = (float*)(wsb + 226 * MiB);                          // 32 MiB (ends 258)
    __hip_bfloat16* W1T  = (__hip_bfloat16*)(wsb + 64 * MiB);       // 64 MiB (after WST dead)
    __hip_bfloat16* W2T  = (__hip_bfloat16*)(wsb + 128 * MiB);      // 64 MiB
    __hip_bfloat16* Hbuf = (__hip_bfloat16*)(wsb + 192 * MiB);      // 120 MiB (ends 312)

    float* rn2 = (float*)(wsb + OFF_RN2);
    float* probs = (float*)(wsb + OFF_PROB);
    float* rope_ct = (float*)(wsb + OFF_PROB);
    float* rope_st = (float*)(wsb + OFF_PROB + (size_t)TSEQ * 32 * 4);
    int*   route_e = (int*)(wsb + OFF_RE);
    float* route_g = (float*)(wsb + OFF_RG);
    int*   bcnt  = (int*)(wsb + OFF_BCNT);
    int*   bbase = (int*)(wsb + OFF_BBASE);
    int*   ctot  = (int*)(wsb + OFF_CTOT);
    int*   tokslot  = (int*)(wsb + OFF_TOK);
    float* gateslot = (float*)(wsb + OFF_GATE);

    // 0. rope table + dedup weight stacks (w0|w1)
    k_rope_table<<<512, 256, 0, stream>>>(rope_ct, rope_st);
    {
        WPack WP; WP.W[0] = Wq; WP.W[1] = Wk; WP.W[2] = Wg; WP.W[3] = Wv; WP.W[4] = Wo;
        k_build_wstack<<<dim3(32, 32, 5), 256, 0, stream>>>(WP, WST);
    }

    // 1. per-group: rms-split -> QKVG -> attn (O split fused) -> Wo+resid -> rmsnorm2
    for (int gi = 0; gi < 4; ++gi) {
        const size_t tok0 = (size_t)gi * GTOK;
        const float* xg = x + tok0 * DM;
        float* vg = out + tok0 * DM;

        k_rms_split<true><<<GTOK, 256, 0, stream>>>(xg, ns1, Xs);

        ProjPack P;
        P.BT[0] = WST;                   P.bias[0] = bq; P.C[0] = qg;
        P.BT[1] = WST + (size_t)DM * KW; P.bias[1] = bk; P.C[1] = kg;
        P.BT[2] = WST + 2ull * DM * KW;  P.bias[2] = bg; P.C[2] = gg;
        P.BT[3] = WST + 3ull * DM * KW;  P.bias[3] = bv; P.C[3] = vg;
        // grid: (n=8, mat=4, m=64) -> mats adjacent per XCD -> A L2 reuse
        k_gemm_proj<4, false><<<dim3(8, 4, GTOK / 128), 256, 0, stream>>>(Xs, P, nullptr);

        k_scan_kv<<<dim3(64, 32), 256, 0, stream>>>(kg, vg, rope_ct, rope_st);
        k_scan_prefix<<<dim3(16, 32), 256, 0, stream>>>(kg);
        k_zprefix<<<32, 64, 0, stream>>>(vg);
        k_scan_out<<<dim3(64, 32), 256, 0, stream>>>(qg, kg, vg, gg, Xs, rope_ct, rope_st);

        ProjPack P2;
        P2.BT[0] = WST + 4ull * DM * KW; P2.bias[0] = bo; P2.C[0] = vg;  // x2 -> d_out slice
        P2.BT[1] = P2.BT[2] = P2.BT[3] = P2.BT[0];
        P2.bias[1] = P2.bias[2] = P2.bias[3] = bo;
        P2.C[1] = P2.C[2] = P2.C[3] = vg;
        k_gemm_proj<1, true><<<dim3(8, GTOK / 128, 1), 256, 0, stream>>>(Xs, P2, xg);

        k_rmsnorm_stats<<<GTOK, 256, 0, stream>>>(vg, rn2 + tok0, ns2, xn2bf + tok0 * DM);
    }

    // 2. router (fp32) — overwrites rope table region with probs
    k_router<<<NTOK / 4, 256, 0, stream>>>(out, rn2, ns2, rW, rb, route_e, route_g, probs);

    // 3. capacity routing
    k_count<<<256, 256, 0, stream>>>(route_e, bcnt);
    k_scan_blocks<<<1, 64, 0, stream>>>(bcnt, bbase, ctot);
    k_zero<<<(NEXP * CAPE * 2 + 255) / 256, 256, 0, stream>>>(tokslot, NEXP * CAPE * 2);
    k_place<<<256, 256, 0, stream>>>(route_e, route_g, bbase, tokslot, gateslot);

    // 4. aux loss scalar
    k_aux<<<1, 256, 0, stream>>>(probs, ctot, out + (size_t)NTOK * DM);

    // 5. MoE expert weights (bf16, transposed) + expert MLP in groups of {3,3,2}
    k_transpose_bf16<<<dim3(HIDN / 32, DM / 32, NEXP), dim3(32, 8), 0, stream>>>(W1, W1T, DM, HIDN);
    k_transpose_bf16<<<dim3(DM / 32, HIDN / 32, NEXP), dim3(32, 8), 0, stream>>>(W2, W2T, HIDN, DM);

    for (int g = 0; g < 3; ++g) {
        const int e0 = g * 3;
        const int ecnt = (g == 2) ? 2 : 3;
        k_gemm_bf16<0><<<dim3(HIDN / 128, CAPE / 128, ecnt), 256, 0, stream>>>(
            xn2bf, W1T, b1, Hbuf, nullptr, tokslot, gateslot, DM, HIDN, e0);
        k_gemm_bf16<1><<<dim3(CAPE / 128, DM / 128, ecnt), 256, 0, stream>>>(
            Hbuf, W2T, b2, nullptr, out, tokslot, gateslot, HIDN, DM, e0);
    }
}

// Round 11
// 4036.131 us; speedup vs baseline: 1.4270x; 1.0115x over previous
//
#include <hip/hip_runtime.h>
#include <hip/hip_bf16.h>

#define NTOK 32768
#define TSEQ 4096
#define DM   1024
#define NHEAD 16
#define NEXP 8
#define CAPE 5120
#define HIDN 4096
#define GTOK 8192         // tokens per batch-group (2 sequences)
#define KSPL 5120         // split-GEMM logical K (3*1024 + 2*1024)
#define KW   2048         // dedup W-stack row stride (w0 | w1)

#ifndef __has_builtin
#define __has_builtin(x) 0
#endif
#if __has_builtin(__builtin_amdgcn_global_load_lds)
#define HAVE_GLOAD 1
#else
#define HAVE_GLOAD 0
#endif

typedef __attribute__((ext_vector_type(8))) short bf16x8;
typedef __attribute__((ext_vector_type(4))) float f32x4;

#define WAITCNT8() asm volatile("s_waitcnt vmcnt(8)" ::: "memory")
#define WAITCNT4() asm volatile("s_waitcnt vmcnt(4)" ::: "memory")
#define WAITCNT0() asm volatile("s_waitcnt vmcnt(0)" ::: "memory")
#define RAWBAR()   do { asm volatile("" ::: "memory"); __builtin_amdgcn_s_barrier(); asm volatile("" ::: "memory"); } while (0)

// bank-spread chunk permutation: slot s of row r holds global chunk s ^ CHP(r)
// CHP(r)=(r>>1)&3 gives 8 distinct bank-starts over 8 consecutive rows (2-way = free)
#define CHP(r) (((r) >> 1) & 3)

__device__ __forceinline__ float phi_f(float v) { return v > 0.f ? v + 1.f : expf(v); }

__device__ __forceinline__ unsigned short f2bf_bits(float f) {
    __hip_bfloat16 h = __float2bfloat16(f);
    union { __hip_bfloat16 h; unsigned short s; } u;
    u.h = h;
    return u.s;
}
__device__ __forceinline__ float bf_to_f(unsigned short s) {
    unsigned int u = ((unsigned int)s) << 16;
    union { unsigned int u; float f; } w; w.u = u;
    return w.f;
}

__global__ void k_ws_flag(float* out, float v) { if (threadIdx.x == 0) out[0] = v; }

__global__ void k_zero(int* p, int n) {
    int i = blockIdx.x * 256 + threadIdx.x;
    if (i < n) p[i] = 0;
}

// ---------------- rope table ----------------
__global__ __launch_bounds__(256) void k_rope_table(float* __restrict__ ct, float* __restrict__ st)
{
    const int idx = blockIdx.x * 256 + threadIdx.x;
    const int t = idx >> 5, j = idx & 31;
    const float inv = (float)(1.0 / pow(10000.0, (double)j / 32.0));
    float sn, cn;
    sincosf((float)t * inv, &sn, &cn);
    ct[idx] = cn; st[idx] = sn;
}

// ---------------- build dedup W stacks: BT[n][0..1024)=w0, [1024..2048)=w1 ----------------
struct WPack { const float* W[5]; };
__global__ __launch_bounds__(256) void k_build_wstack(WPack P, __hip_bfloat16* __restrict__ BTbase)
{
    __shared__ float t_[32][33];
    const int z = blockIdx.z;
    const float* Wm = P.W[z];
    __hip_bfloat16* BT = BTbase + (size_t)z * DM * KW;
    const int n0 = blockIdx.x * 32, k0 = blockIdx.y * 32;
    const int c = threadIdx.x & 31, r0 = (threadIdx.x >> 5);   // 32 x 8
#pragma unroll
    for (int i = 0; i < 4; ++i) { int r = r0 + i * 8; t_[r][c] = Wm[(size_t)(k0 + r) * DM + n0 + c]; }
    __syncthreads();
#pragma unroll
    for (int i = 0; i < 4; ++i) {
        int r = r0 + i * 8;                       // local n
        float val = t_[c][r];                     // W[k0+c][n0+r]
        unsigned short b0 = f2bf_bits(val);
        float res = val - bf_to_f(b0);
        unsigned short b1 = f2bf_bits(res);
        __hip_bfloat16 h0, h1;
        union { __hip_bfloat16 h; unsigned short s; } u0, u1;
        u0.s = b0; u1.s = b1; h0 = u0.h; h1 = u1.h;
        const size_t nrow = (size_t)(n0 + r) * KW + (k0 + c);
        BT[nrow]        = h0;
        BT[nrow + 1024] = h1;
    }
}

// ---------------- split rows into 3 bf16 planes (rmsnorm-scaled) ----------------
template<bool NORM>
__global__ __launch_bounds__(256) void k_rms_split(const float* __restrict__ X,
                                                   const float* __restrict__ nscale,
                                                   __hip_bfloat16* __restrict__ Xs)
{
    const int row = blockIdx.x;
    const int tid = threadIdx.x;
    const float* xr = X + (size_t)row * DM;
    float4 v = ((const float4*)xr)[tid];
    float r = 1.f;
    if (NORM) {
        float s = v.x * v.x + v.y * v.y + v.z * v.z + v.w * v.w;
        for (int off = 32; off; off >>= 1) s += __shfl_xor(s, off);
        __shared__ float redw[4];
        __shared__ float rbc;
        if ((tid & 63) == 0) redw[tid >> 6] = s;
        __syncthreads();
        if (tid == 0) {
            float tot = redw[0] + redw[1] + redw[2] + redw[3];
            rbc = (float)(1.0 / sqrt((double)tot * (1.0 / 1024.0)));
        }
        __syncthreads();
        r = rbc;
    }
    float c[4] = {v.x, v.y, v.z, v.w};
    if (NORM) {
        float4 ns = ((const float4*)nscale)[tid];
        c[0] *= r * ns.x; c[1] *= r * ns.y; c[2] *= r * ns.z; c[3] *= r * ns.w;
    }
    ushort4 p0, p1, p2;
    unsigned short* q0 = (unsigned short*)&p0;
    unsigned short* q1 = (unsigned short*)&p1;
    unsigned short* q2 = (unsigned short*)&p2;
#pragma unroll
    for (int i = 0; i < 4; ++i) {
        float x = c[i];
        unsigned short b0 = f2bf_bits(x);
        float r1 = x - bf_to_f(b0);
        unsigned short b1 = f2bf_bits(r1);
        float r2 = r1 - bf_to_f(b1);
        unsigned short b2 = f2bf_bits(r2);
        q0[i] = b0; q1[i] = b1; q2[i] = b2;
    }
    __hip_bfloat16* base = Xs + (size_t)row * 3072;
    ((ushort4*)(base))[tid] = p0;
    ((ushort4*)(base + 1024))[tid] = p1;
    ((ushort4*)(base + 2048))[tid] = p2;
}

// ---------------- rmsnorm stats + bf16 normalized rows ----------------
__global__ __launch_bounds__(256) void k_rmsnorm_stats(const float* __restrict__ X,
                                                       float* __restrict__ rn,
                                                       const float* __restrict__ nscale,
                                                       __hip_bfloat16* __restrict__ xbf)
{
    const int row = blockIdx.x;
    const int tid = threadIdx.x;
    const float* xr = X + (size_t)row * DM;
    float4 v = ((const float4*)xr)[tid];
    float s = v.x * v.x + v.y * v.y + v.z * v.z + v.w * v.w;
    for (int off = 32; off; off >>= 1) s += __shfl_xor(s, off);
    __shared__ float redw[4];
    __shared__ float rbc;
    if ((tid & 63) == 0) redw[tid >> 6] = s;
    __syncthreads();
    if (tid == 0) {
        float tot = redw[0] + redw[1] + redw[2] + redw[3];
        float r = (float)(1.0 / sqrt((double)tot * (1.0 / 1024.0)));
        rn[row] = r; rbc = r;
    }
    __syncthreads();
    float r = rbc;
    float4 ns = ((const float4*)nscale)[tid];
    ushort4 o;
    o.x = f2bf_bits(v.x * r * ns.x);
    o.y = f2bf_bits(v.y * r * ns.y);
    o.z = f2bf_bits(v.z * r * ns.z);
    o.w = f2bf_bits(v.w * r * ns.w);
    ((ushort4*)(xbf + (size_t)row * DM))[tid] = o;
}

#if HAVE_GLOAD
__device__ __forceinline__ void gload16(const __hip_bfloat16* g, __hip_bfloat16* l)
{
    __builtin_amdgcn_global_load_lds((const __attribute__((address_space(1))) unsigned int*)g,
                                     (__attribute__((address_space(3))) unsigned int*)l, 16, 0, 0);
}
#endif

// ====== GEMM cores: 3-deep counted-vmcnt pipeline + bank-spread CHP swizzle ======

// ---------------- split-precision projection GEMM ----------------
struct ProjPack {
    const __hip_bfloat16* BT[4];
    const float* bias[4];
    float* C[4];
};

template<int NMAT, bool RESID>
__global__ __launch_bounds__(256) void k_gemm_proj(const __hip_bfloat16* __restrict__ A,
                                                   ProjPack P,
                                                   const float* __restrict__ resid)
{
    const int z = (NMAT == 4) ? blockIdx.y : 0;
    const __hip_bfloat16* BT = P.BT[z];
    const float* bias = P.bias[z];
    float* C = P.C[z];
    const int m0 = ((NMAT == 4) ? blockIdx.z : blockIdx.y) * 128;
    const int n0 = blockIdx.x * 128;
    const int tid = threadIdx.x;
    __shared__ alignas(16) __hip_bfloat16 As[3][128 * 32];
    __shared__ alignas(16) __hip_bfloat16 Bs[3][128 * 32];

    const int lane = tid & 63, wv = tid >> 6;
    const int lr = lane & 15, lgp = lane >> 4;
    const int wm = (wv >> 1) * 64, wn = (wv & 1) * 64;

    f32x4 acc[4][4];
#pragma unroll
    for (int i = 0; i < 4; ++i)
#pragma unroll
        for (int j = 0; j < 4; ++j) acc[i][j] = (f32x4){0.f, 0.f, 0.f, 0.f};

    int a_off[4], b_off[4];
#pragma unroll
    for (int i = 0; i < 4; ++i) {
        int mrow = wm + i * 16 + lr;
        a_off[i] = mrow * 32 + ((lgp ^ CHP(mrow)) * 8);
        int nrow = wn + i * 16 + lr;
        b_off[i] = nrow * 32 + ((lgp ^ CHP(nrow)) * 8);
    }

    constexpr int T = KSPL / 32;   // 160

#if HAVE_GLOAD
    const int rA0 = wv * 32 + (lane >> 2), rA1 = rA0 + 16;
    const int ch = lane & 3;
    const __hip_bfloat16* srcA0 = A + (size_t)(m0 + rA0) * 3072 + ((ch ^ CHP(rA0)) * 8);
    const __hip_bfloat16* srcA1 = A + (size_t)(m0 + rA1) * 3072 + ((ch ^ CHP(rA1)) * 8);
    const __hip_bfloat16* srcB0 = BT + (size_t)(n0 + rA0) * KW + ((ch ^ CHP(rA0)) * 8);
    const __hip_bfloat16* srcB1 = BT + (size_t)(n0 + rA1) * KW + ((ch ^ CHP(rA1)) * 8);
    const int ldsO0 = (wv * 32) * 32;
    const int ldsO1 = (wv * 32 + 16) * 32;

    auto STAGE = [&](int tile, int buf) {
        const int kb = tile * 32;
        const int acol = (kb < 3072) ? kb : (kb - 3072);
        const int bcol = ((kb < 3072) ? 0 : 1024) + (kb & 1023);
        gload16(srcA0 + acol, &As[buf][ldsO0]);
        gload16(srcA1 + acol, &As[buf][ldsO1]);
        gload16(srcB0 + bcol, &Bs[buf][ldsO0]);
        gload16(srcB1 + bcol, &Bs[buf][ldsO1]);
    };

    STAGE(0, 0); STAGE(1, 1); STAGE(2, 2);
    int buf = 0;
    for (int t = 0; t < T; ++t) {
        if (t <= T - 3)      { WAITCNT8(); }
        else if (t == T - 2) { WAITCNT4(); }
        else                 { WAITCNT0(); }
        RAWBAR();
        bf16x8 af[4], bfr[4];
#pragma unroll
        for (int i = 0; i < 4; ++i) af[i] = *(const bf16x8*)(&As[buf][0] + a_off[i]);
#pragma unroll
        for (int j = 0; j < 4; ++j) bfr[j] = *(const bf16x8*)(&Bs[buf][0] + b_off[j]);
#pragma unroll
        for (int i = 0; i < 4; ++i)
#pragma unroll
            for (int j = 0; j < 4; ++j)
                acc[i][j] = __builtin_amdgcn_mfma_f32_16x16x32_bf16(af[i], bfr[j], acc[i][j], 0, 0, 0);
        if (t + 3 < T) {
            RAWBAR();
            STAGE(t + 3, buf);
        }
        buf = (buf == 2) ? 0 : buf + 1;
    }
#else
    const int ar = tid >> 1, ac0 = (tid & 1) * 2;
    const __hip_bfloat16* Arow = A + (size_t)(m0 + ar) * 3072;
    const __hip_bfloat16* Brow = BT + (size_t)(n0 + ar) * KW;
    for (int t = 0; t < T; ++t) {
        const int kb = t * 32;
        const int acol = (kb < 3072) ? kb : (kb - 3072);
        const int bcol = ((kb < 3072) ? 0 : 1024) + (kb & 1023);
        __syncthreads();
        uint4 av0 = *(const uint4*)(Arow + acol + ac0 * 8);
        uint4 av1 = *(const uint4*)(Arow + acol + ac0 * 8 + 8);
        uint4 bv0 = *(const uint4*)(Brow + bcol + ac0 * 8);
        uint4 bv1 = *(const uint4*)(Brow + bcol + ac0 * 8 + 8);
        *(uint4*)(&As[0][0] + ar * 32 + ((ac0      ^ CHP(ar)) * 8)) = av0;
        *(uint4*)(&As[0][0] + ar * 32 + (((ac0 + 1) ^ CHP(ar)) * 8)) = av1;
        *(uint4*)(&Bs[0][0] + ar * 32 + ((ac0      ^ CHP(ar)) * 8)) = bv0;
        *(uint4*)(&Bs[0][0] + ar * 32 + (((ac0 + 1) ^ CHP(ar)) * 8)) = bv1;
        __syncthreads();
        bf16x8 af[4], bfr[4];
#pragma unroll
        for (int i = 0; i < 4; ++i) af[i] = *(const bf16x8*)(&As[0][0] + a_off[i]);
#pragma unroll
        for (int j = 0; j < 4; ++j) bfr[j] = *(const bf16x8*)(&Bs[0][0] + b_off[j]);
#pragma unroll
        for (int i = 0; i < 4; ++i)
#pragma unroll
            for (int j = 0; j < 4; ++j)
                acc[i][j] = __builtin_amdgcn_mfma_f32_16x16x32_bf16(af[i], bfr[j], acc[i][j], 0, 0, 0);
    }
#endif

#pragma unroll
    for (int i = 0; i < 4; ++i)
#pragma unroll
        for (int j = 0; j < 4; ++j) {
            const int col = n0 + wn + j * 16 + lr;
            const float bval = bias[col];
#pragma unroll
            for (int r = 0; r < 4; ++r) {
                const int rloc = wm + i * 16 + lgp * 4 + r;
                float v = acc[i][j][r] + bval;
                if (RESID) v += resid[(size_t)(m0 + rloc) * DM + col];
                C[(size_t)(m0 + rloc) * DM + col] = v;
            }
        }
}

// ---------------- bf16 MFMA GEMM for experts ----------------
// MODE 0: grid (n, m, e): Hbuf[le][slot] = gelu(xn2bf[tok] @ W1T[e]^T + b1[e])
// MODE 1: grid (m, n, e) [swapped for XCD A-locality]: out[tok] += gate*(Hbuf@W2T^T + b2)
template<int MODE>
__global__ __launch_bounds__(256) void k_gemm_bf16(const __hip_bfloat16* __restrict__ A,
                                                   const __hip_bfloat16* __restrict__ BT,
                                                   const float* __restrict__ bias,
                                                   __hip_bfloat16* __restrict__ Hout,
                                                   float* __restrict__ Fout,
                                                   const int* __restrict__ tokslot,
                                                   const float* __restrict__ gateslot,
                                                   int K, int Nout, int e0)
{
    const int le = blockIdx.z;
    const int e = e0 + le;
    const int m0 = (MODE == 1 ? blockIdx.x : blockIdx.y) * 128;
    const int n0 = (MODE == 1 ? blockIdx.y : blockIdx.x) * 128;
    const int tid = threadIdx.x;
    __shared__ alignas(16) __hip_bfloat16 As[3][128 * 32];
    __shared__ alignas(16) __hip_bfloat16 Bs[3][128 * 32];
    __shared__ int s_tok[128];
    __shared__ float s_gate[128];
    if (tid < 128) {
        s_tok[tid] = tokslot[e * CAPE + m0 + tid];
        s_gate[tid] = gateslot[e * CAPE + m0 + tid];
    }
    __syncthreads();

    const int lane = tid & 63, wv = tid >> 6;
    const int lr = lane & 15, lgp = lane >> 4;
    const int wm = (wv >> 1) * 64, wn = (wv & 1) * 64;

    f32x4 acc[4][4];
#pragma unroll
    for (int i = 0; i < 4; ++i)
#pragma unroll
        for (int j = 0; j < 4; ++j) acc[i][j] = (f32x4){0.f, 0.f, 0.f, 0.f};

    int a_off[4], b_off[4];
#pragma unroll
    for (int i = 0; i < 4; ++i) {
        int mrow = wm + i * 16 + lr;
        a_off[i] = mrow * 32 + ((lgp ^ CHP(mrow)) * 8);
        int nrow = wn + i * 16 + lr;
        b_off[i] = nrow * 32 + ((lgp ^ CHP(nrow)) * 8);
    }

#if HAVE_GLOAD
    const int rA0 = wv * 32 + (lane >> 2), rA1 = rA0 + 16;
    const int ch = lane & 3;
    const __hip_bfloat16 *srcA0, *srcA1;
    if (MODE == 0) {
        srcA0 = A + (size_t)s_tok[rA0] * K + ((ch ^ CHP(rA0)) * 8);
        srcA1 = A + (size_t)s_tok[rA1] * K + ((ch ^ CHP(rA1)) * 8);
    } else {
        srcA0 = A + ((size_t)le * CAPE + m0 + rA0) * K + ((ch ^ CHP(rA0)) * 8);
        srcA1 = A + ((size_t)le * CAPE + m0 + rA1) * K + ((ch ^ CHP(rA1)) * 8);
    }
    const __hip_bfloat16* srcB0 = BT + ((size_t)e * Nout + n0 + rA0) * K + ((ch ^ CHP(rA0)) * 8);
    const __hip_bfloat16* srcB1 = BT + ((size_t)e * Nout + n0 + rA1) * K + ((ch ^ CHP(rA1)) * 8);
    const int ldsO0 = (wv * 32) * 32;
    const int ldsO1 = (wv * 32 + 16) * 32;

    auto STAGE = [&](int tile, int buf) {
        const int kb = tile * 32;
        gload16(srcA0 + kb, &As[buf][ldsO0]);
        gload16(srcA1 + kb, &As[buf][ldsO1]);
        gload16(srcB0 + kb, &Bs[buf][ldsO0]);
        gload16(srcB1 + kb, &Bs[buf][ldsO1]);
    };

    const int T = K / 32;
    STAGE(0, 0); STAGE(1, 1); STAGE(2, 2);
    int buf = 0;
    for (int t = 0; t < T; ++t) {
        if (t <= T - 3)      { WAITCNT8(); }
        else if (t == T - 2) { WAITCNT4(); }
        else                 { WAITCNT0(); }
        RAWBAR();
        bf16x8 af[4], bfr[4];
#pragma unroll
        for (int i = 0; i < 4; ++i) af[i] = *(const bf16x8*)(&As[buf][0] + a_off[i]);
#pragma unroll
        for (int j = 0; j < 4; ++j) bfr[j] = *(const bf16x8*)(&Bs[buf][0] + b_off[j]);
#pragma unroll
        for (int i = 0; i < 4; ++i)
#pragma unroll
            for (int j = 0; j < 4; ++j)
                acc[i][j] = __builtin_amdgcn_mfma_f32_16x16x32_bf16(af[i], bfr[j], acc[i][j], 0, 0, 0);
        if (t + 3 < T) {
            RAWBAR();
            STAGE(t + 3, buf);
        }
        buf = (buf == 2) ? 0 : buf + 1;
    }
#else
    const int ar = tid >> 1, ac0 = (tid & 1) * 2;
    const __hip_bfloat16* Arow;
    if (MODE == 0) Arow = A + (size_t)s_tok[ar] * K;
    else           Arow = A + ((size_t)le * CAPE + m0 + ar) * K;
    const __hip_bfloat16* Brow = BT + ((size_t)e * Nout + n0 + ar) * K;
    for (int k0 = 0; k0 < K; k0 += 32) {
        __syncthreads();
        uint4 av0 = *(const uint4*)(Arow + k0 + ac0 * 8);
        uint4 av1 = *(const uint4*)(Arow + k0 + ac0 * 8 + 8);
        uint4 bv0 = *(const uint4*)(Brow + k0 + ac0 * 8);
        uint4 bv1 = *(const uint4*)(Brow + k0 + ac0 * 8 + 8);
        *(uint4*)(&As[0][0] + ar * 32 + ((ac0      ^ CHP(ar)) * 8)) = av0;
        *(uint4*)(&As[0][0] + ar * 32 + (((ac0 + 1) ^ CHP(ar)) * 8)) = av1;
        *(uint4*)(&Bs[0][0] + ar * 32 + ((ac0      ^ CHP(ar)) * 8)) = bv0;
        *(uint4*)(&Bs[0][0] + ar * 32 + (((ac0 + 1) ^ CHP(ar)) * 8)) = bv1;
        __syncthreads();
        bf16x8 af[4], bfr[4];
#pragma unroll
        for (int i = 0; i < 4; ++i) af[i] = *(const bf16x8*)(&As[0][0] + a_off[i]);
#pragma unroll
        for (int j = 0; j < 4; ++j) bfr[j] = *(const bf16x8*)(&Bs[0][0] + b_off[j]);
#pragma unroll
        for (int i = 0; i < 4; ++i)
#pragma unroll
            for (int j = 0; j < 4; ++j)
                acc[i][j] = __builtin_amdgcn_mfma_f32_16x16x32_bf16(af[i], bfr[j], acc[i][j], 0, 0, 0);
    }
#endif

#pragma unroll
    for (int i = 0; i < 4; ++i)
#pragma unroll
        for (int j = 0; j < 4; ++j) {
            const int col = n0 + wn + j * 16 + lr;
            const float bval = bias[(size_t)e * Nout + col];
#pragma unroll
            for (int r = 0; r < 4; ++r) {
                const int rloc = wm + i * 16 + lgp * 4 + r;
                float v = acc[i][j][r] + bval;
                if (MODE == 0) {
                    v = 0.5f * v * (1.f + erff(v * 0.70710678118654752f));
                    Hout[((size_t)le * CAPE + m0 + rloc) * Nout + col] = __float2bfloat16(v);
                } else {
                    const float g = s_gate[rloc];
                    if (g != 0.f) atomicAdd(&Fout[(size_t)s_tok[rloc] * DM + col], v * g);
                }
            }
        }
}

// ---------------- attention pass 1: S_c = K_c^T V_c (in place over K), Z_c into V row0 ----------------
__global__ __launch_bounds__(256) void k_scan_kv(float* KS, float* Vz,
                                                 const float* __restrict__ ct,
                                                 const float* __restrict__ st)
{
    const int c = blockIdx.x, bh = blockIdx.y;
    const int h = bh & 15, b = bh >> 4;
    const int tid = threadIdx.x;
    __shared__ float ks[64][68];
    __shared__ float vs[64][68];
    const size_t rowbase = ((size_t)b * TSEQ + c * 64) * DM + h * 64;
#pragma unroll
    for (int p = 0; p < 8; ++p) {
        int idx = p * 256 + tid;
        int t = idx >> 5, j = idx & 31;
        const size_t base = rowbase + (size_t)t * DM + j;
        float cn = ct[(c * 64 + t) * 32 + j];
        float sn = st[(c * 64 + t) * 32 + j];
        float k1 = KS[base], k2 = KS[base + 32];
        ks[t][j]      = phi_f(k1 * cn - k2 * sn);
        ks[t][j + 32] = phi_f(k1 * sn + k2 * cn);
    }
#pragma unroll
    for (int p = 0; p < 4; ++p) {
        int idx = p * 256 + tid;
        int t = idx >> 4, e4 = (idx & 15) * 4;
        *(float4*)&vs[t][e4] = *(const float4*)&Vz[rowbase + (size_t)t * DM + e4];
    }
    __syncthreads();
    const int e = tid & 63, dg = tid >> 6;
    float acc[16] = {};
    for (int t = 0; t < 64; ++t) {
        float vv = vs[t][e];
#pragma unroll
        for (int qq = 0; qq < 4; ++qq) {
            float4 kq = *(const float4*)&ks[t][dg * 16 + qq * 4];
            acc[qq * 4 + 0] = fmaf(kq.x, vv, acc[qq * 4 + 0]);
            acc[qq * 4 + 1] = fmaf(kq.y, vv, acc[qq * 4 + 1]);
            acc[qq * 4 + 2] = fmaf(kq.z, vv, acc[qq * 4 + 2]);
            acc[qq * 4 + 3] = fmaf(kq.w, vv, acc[qq * 4 + 3]);
        }
    }
#pragma unroll
    for (int i = 0; i < 16; ++i) {
        int d = dg * 16 + i;
        KS[rowbase + (size_t)d * DM + e] = acc[i];
    }
    if (tid < 64) {
        float z = 0.f;
        for (int t = 0; t < 64; ++t) z += ks[t][tid];
        Vz[rowbase + tid] = z;
    }
}

// ---------------- attention pass 2: inclusive prefix over chunks ----------------
__global__ __launch_bounds__(256) void k_scan_prefix(float* S)
{
    const int sg = blockIdx.x, bh = blockIdx.y;
    const int h = bh & 15, b = bh >> 4;
    const int idx = sg * 256 + threadIdx.x;
    const int d = idx >> 6, e = idx & 63;
    const size_t base = (size_t)b * TSEQ * DM + h * 64 + (size_t)d * DM + e;
    float acc = 0.f;
    for (int c = 0; c < 64; ++c) {
        size_t p = base + (size_t)c * 64 * DM;
        acc += S[p];
        S[p] = acc;
    }
}

__global__ void k_zprefix(float* Vz)
{
    const int bh = blockIdx.x;
    const int h = bh & 15, b = bh >> 4;
    const int d = threadIdx.x;
    const size_t base = (size_t)b * TSEQ * DM + h * 64 + d;
    float acc = 0.f;
    for (int c = 0; c < 64; ++c) {
        size_t p = base + (size_t)c * 64 * DM;
        acc += Vz[p];
        Vz[p] = acc;
    }
}

// ---------------- attention pass 3: O = g*(q@S)/(q.Z+eps), split to 3 bf16 planes in Xs ----------------
__global__ __launch_bounds__(256) void k_scan_out(const float* __restrict__ Q,
                                                  const float* __restrict__ S,
                                                  const float* __restrict__ Zv,
                                                  const float* __restrict__ G,
                                                  __hip_bfloat16* __restrict__ Xs,
                                                  const float* __restrict__ ct,
                                                  const float* __restrict__ st)
{
    const int c = blockIdx.x, bh = blockIdx.y;
    const int h = bh & 15, b = bh >> 4;
    const int tid = threadIdx.x;
    __shared__ float qs[64][69];
    __shared__ float Ss[64][68];
    __shared__ float den[64], Zl[64];
    const size_t rowbase = ((size_t)b * TSEQ + c * 64) * DM + h * 64;
#pragma unroll
    for (int p = 0; p < 8; ++p) {
        int idx = p * 256 + tid;
        int t = idx >> 5, j = idx & 31;
        const size_t base = rowbase + (size_t)t * DM + j;
        float cn = ct[(c * 64 + t) * 32 + j];
        float sn = st[(c * 64 + t) * 32 + j];
        float q1 = Q[base], q2 = Q[base + 32];
        qs[t][j]      = phi_f(q1 * cn - q2 * sn);
        qs[t][j + 32] = phi_f(q1 * sn + q2 * cn);
    }
#pragma unroll
    for (int p = 0; p < 4; ++p) {
        int idx = p * 256 + tid;
        int d = idx >> 4, e4 = (idx & 15) * 4;
        *(float4*)&Ss[d][e4] = *(const float4*)&S[rowbase + (size_t)d * DM + e4];
    }
    const int e = tid & 63, tg = tid >> 6;
    float greg[16];
#pragma unroll
    for (int i = 0; i < 16; ++i)
        greg[i] = G[rowbase + (size_t)(tg * 16 + i) * DM + e];
    if (tid < 64) Zl[tid] = Zv[rowbase + tid];
    __syncthreads();
    if (tid < 64) {
        float dd = 0.f;
        for (int d = 0; d < 64; ++d) dd += qs[tid][d] * Zl[d];
        den[tid] = dd + 1e-6f;
    }
    __syncthreads();
    float acc[16] = {};
    for (int d = 0; d < 64; ++d) {
        float sv = Ss[d][e];
#pragma unroll
        for (int i = 0; i < 16; ++i)
            acc[i] = fmaf(qs[tg * 16 + i][d], sv, acc[i]);
    }
    unsigned short* Xu = (unsigned short*)Xs;
#pragma unroll
    for (int i = 0; i < 16; ++i) {
        int t = tg * 16 + i;
        float g = 1.f / (1.f + expf(-greg[i]));
        float o = g * acc[i] / den[t];
        unsigned short b0 = f2bf_bits(o);
        float r1 = o - bf_to_f(b0);
        unsigned short b1 = f2bf_bits(r1);
        float r2 = r1 - bf_to_f(b1);
        unsigned short b2 = f2bf_bits(r2);
        const size_t xb = (size_t)(b * TSEQ + c * 64 + t) * 3072 + h * 64 + e;
        Xu[xb] = b0;
        Xu[xb + 1024] = b1;
        Xu[xb + 2048] = b2;
    }
}

// ---------------- router ----------------
__global__ __launch_bounds__(256) void k_router(const float* __restrict__ X2,
                                                const float* __restrict__ rn2,
                                                const float* __restrict__ ns2,
                                                const float* __restrict__ rW,
                                                const float* __restrict__ rb,
                                                int* __restrict__ route_e,
                                                float* __restrict__ route_g,
                                                float* __restrict__ probs)
{
    const int tok = blockIdx.x * 4 + (threadIdx.x >> 6);
    const int lane = threadIdx.x & 63;
    const float* xr = X2 + (size_t)tok * DM;
    const float rn = rn2[tok];
    float lg[8] = {};
    for (int d = lane; d < DM; d += 64) {
        float xv = xr[d] * rn * ns2[d];
        const float4* w4 = (const float4*)(rW + (size_t)d * 8);
        float4 w0 = w4[0], w1 = w4[1];
        lg[0] += xv * w0.x; lg[1] += xv * w0.y; lg[2] += xv * w0.z; lg[3] += xv * w0.w;
        lg[4] += xv * w1.x; lg[5] += xv * w1.y; lg[6] += xv * w1.z; lg[7] += xv * w1.w;
    }
#pragma unroll
    for (int e = 0; e < 8; ++e)
        for (int off = 32; off; off >>= 1) lg[e] += __shfl_xor(lg[e], off);
    if (lane == 0) {
        float pe[8]; float mx = -1e30f, s = 0.f;
#pragma unroll
        for (int e = 0; e < 8; ++e) { lg[e] += rb[e]; mx = fmaxf(mx, lg[e]); }
#pragma unroll
        for (int e = 0; e < 8; ++e) { pe[e] = expf(lg[e] - mx); s += pe[e]; }
#pragma unroll
        for (int e = 0; e < 8; ++e) { pe[e] /= s; probs[(size_t)tok * 8 + e] = pe[e]; }
        int i1 = 0; float p1 = pe[0];
#pragma unroll
        for (int e = 1; e < 8; ++e) if (pe[e] > p1) { p1 = pe[e]; i1 = e; }
        int i2 = -1; float p2 = -1.f;
#pragma unroll
        for (int e = 0; e < 8; ++e) if (e != i1 && pe[e] > p2) { p2 = pe[e]; i2 = e; }
        const float gsum = p1 + p2;
        route_e[tok * 2] = i1; route_e[tok * 2 + 1] = i2;
        route_g[tok * 2] = p1 / gsum; route_g[tok * 2 + 1] = p2 / gsum;
    }
}

// ---------------- capacity routing ----------------
__global__ __launch_bounds__(256) void k_count(const int* __restrict__ route_e, int* __restrict__ bcnt)
{
    __shared__ int c[8];
    const int tid = threadIdx.x;
    if (tid < 8) c[tid] = 0;
    __syncthreads();
    atomicAdd(&c[route_e[blockIdx.x * 256 + tid]], 1);
    __syncthreads();
    if (tid < 8) bcnt[blockIdx.x * 8 + tid] = c[tid];
}

__global__ void k_scan_blocks(const int* __restrict__ bcnt, int* __restrict__ bbase, int* __restrict__ ctot)
{
    const int e = threadIdx.x;
    if (e < 8) {
        int run = 0;
        for (int b = 0; b < 256; ++b) { bbase[b * 8 + e] = run; run += bcnt[b * 8 + e]; }
        ctot[e] = run;
    }
}

__global__ __launch_bounds__(256) void k_place(const int* __restrict__ route_e,
                                               const float* __restrict__ route_g,
                                               const int* __restrict__ bbase,
                                               int* __restrict__ tokslot,
                                               float* __restrict__ gateslot)
{
    const int tid = threadIdx.x;
    const int a = blockIdx.x * 256 + tid;
    const int e = route_e[a];
    __shared__ int se[256];
    se[tid] = e;
    __syncthreads();
    int rank = 0;
    for (int j = 0; j < tid; ++j) rank += (se[j] == e) ? 1 : 0;
    const int slot = bbase[blockIdx.x * 8 + e] + rank;
    if (slot < CAPE) {
        tokslot[e * CAPE + slot] = a >> 1;
        gateslot[e * CAPE + slot] = route_g[a];
    }
}

// ---------------- aux loss ----------------
__global__ __launch_bounds__(256) void k_aux(const float* __restrict__ probs,
                                             const int* __restrict__ ctot,
                                             float* __restrict__ out_aux)
{
    const int tid = threadIdx.x;
    float part[8] = {};
    for (int i = tid; i < NTOK; i += 256) {
        const float* p = probs + (size_t)i * 8;
#pragma unroll
        for (int e = 0; e < 8; ++e) part[e] += p[e];
    }
    __shared__ float red[256];
    __shared__ float accs[8];
    for (int e = 0; e < 8; ++e) {
        red[tid] = part[e];
        __syncthreads();
        for (int s = 128; s; s >>= 1) { if (tid < s) red[tid] += red[tid + s]; __syncthreads(); }
        if (tid == 0) accs[e] = red[0];
        __syncthreads();
    }
    if (tid == 0) {
        float isum = 0.f, lsum = 0.f, l[8];
        for (int e = 0; e < 8; ++e) isum += accs[e];
        for (int e = 0; e < 8; ++e) { l[e] = fminf((float)ctot[e], (float)CAPE); lsum += l[e]; }
        float aux = 0.f;
        for (int e = 0; e < 8; ++e) aux += (accs[e] / isum) * (l[e] / lsum);
        out_aux[0] = aux * 64.f;
    }
}

// ---------------- f32 -> bf16 transpose (per expert z) ----------------
__global__ void k_transpose_bf16(const float* __restrict__ src, __hip_bfloat16* __restrict__ dst,
                                 int K_, int N_)
{
    __shared__ float t_[32][33];
    const int z = blockIdx.z;
    const float* s = src + (size_t)z * K_ * N_;
    __hip_bfloat16* d = dst + (size_t)z * K_ * N_;
    const int n0 = blockIdx.x * 32, k0 = blockIdx.y * 32;
    const int c = threadIdx.x, r0 = threadIdx.y;
#pragma unroll
    for (int i = 0; i < 4; ++i) { int r = r0 + i * 8; t_[r][c] = s[(size_t)(k0 + r) * N_ + n0 + c]; }
    __syncthreads();
#pragma unroll
    for (int i = 0; i < 4; ++i) { int r = r0 + i * 8; d[(size_t)(n0 + r) * K_ + k0 + c] = __float2bfloat16(t_[c][r]); }
}

extern "C" void kernel_launch(void* const* d_in, const int* in_sizes, int n_in,
                              void* d_out, int out_size, void* d_ws, size_t ws_size,
                              hipStream_t stream)
{
    (void)in_sizes; (void)n_in; (void)out_size;
    const float* x   = (const float*)d_in[0];
    const float* ns1 = (const float*)d_in[1];
    const float* ns2 = (const float*)d_in[2];
    const float* Wq  = (const float*)d_in[3];
    const float* bq  = (const float*)d_in[4];
    const float* Wk  = (const float*)d_in[5];
    const float* bk  = (const float*)d_in[6];
    const float* Wv  = (const float*)d_in[7];
    const float* bv  = (const float*)d_in[8];
    const float* Wg  = (const float*)d_in[9];
    const float* bg  = (const float*)d_in[10];
    const float* Wo  = (const float*)d_in[11];
    const float* bo  = (const float*)d_in[12];
    const float* rW  = (const float*)d_in[13];
    const float* rb  = (const float*)d_in[14];
    const float* W1  = (const float*)d_in[15];
    const float* b1  = (const float*)d_in[16];
    const float* W2  = (const float*)d_in[17];
    const float* b2  = (const float*)d_in[18];
    float* out = (float*)d_out;
    char* wsb = (char*)d_ws;

    constexpr size_t MiB = 1024ull * 1024ull;
    constexpr size_t R = (size_t)NTOK * DM * 4;        // 128 MiB
    constexpr size_t TAIL = 3 * R;
    constexpr size_t OFF_RN1  = TAIL;
    constexpr size_t OFF_RN2  = OFF_RN1 + (size_t)NTOK * 4;
    constexpr size_t OFF_PROB = OFF_RN2 + (size_t)NTOK * 4;
    constexpr size_t OFF_RE   = OFF_PROB + (size_t)NTOK * 8 * 4;
    constexpr size_t OFF_RG   = OFF_RE + (size_t)NTOK * 2 * 4;
    constexpr size_t OFF_BCNT = OFF_RG + (size_t)NTOK * 2 * 4;
    constexpr size_t OFF_BBASE= OFF_BCNT + 256 * 8 * 4;
    constexpr size_t OFF_CTOT = OFF_BBASE + 256 * 8 * 4;
    constexpr size_t OFF_TOK  = OFF_CTOT + 4096;
    constexpr size_t OFF_GATE = OFF_TOK + (size_t)NEXP * CAPE * 4;
    constexpr size_t REQUIRED = OFF_GATE + (size_t)NEXP * CAPE * 4;

    if (ws_size < REQUIRED) {
        k_ws_flag<<<1, 64, 0, stream>>>(out, (float)(ws_size >> 20));
        return;
    }

    // main region layout (within [0, 3R))
    __hip_bfloat16* xn2bf = (__hip_bfloat16*)(wsb);                 // 64 MiB persistent
    __hip_bfloat16* WST   = (__hip_bfloat16*)(wsb + 64 * MiB);      // 5 x 4 MiB = 20 MiB (dedup)
    __hip_bfloat16* Xs    = (__hip_bfloat16*)(wsb + 114 * MiB);     // 48 MiB per-group
    float* qg = (float*)(wsb + 162 * MiB);                          // 32 MiB
    float* kg = (float*)(wsb + 194 * MiB);                          // 32 MiB
    float* gg = (float*)(wsb + 226 * MiB);                          // 32 MiB (ends 258)
    __hip_bfloat16* W1T  = (__hip_bfloat16*)(wsb + 64 * MiB);       // 64 MiB (after WST dead)
    __hip_bfloat16* W2T  = (__hip_bfloat16*)(wsb + 128 * MiB);      // 64 MiB
    __hip_bfloat16* Hbuf = (__hip_bfloat16*)(wsb + 192 * MiB);      // 120 MiB (ends 312)

    float* rn2 = (float*)(wsb + OFF_RN2);
    float* probs = (float*)(wsb + OFF_PROB);
    float* rope_ct = (float*)(wsb + OFF_PROB);
    float* rope_st = (float*)(wsb + OFF_PROB + (size_t)TSEQ * 32 * 4);
    int*   route_e = (int*)(wsb + OFF_RE);
    float* route_g = (float*)(wsb + OFF_RG);
    int*   bcnt  = (int*)(wsb + OFF_BCNT);
    int*   bbase = (int*)(wsb + OFF_BBASE);
    int*   ctot  = (int*)(wsb + OFF_CTOT);
    int*   tokslot  = (int*)(wsb + OFF_TOK);
    float* gateslot = (float*)(wsb + OFF_GATE);

    // 0. rope table + dedup weight stacks (w0|w1)
    k_rope_table<<<512, 256, 0, stream>>>(rope_ct, rope_st);
    {
        WPack WP; WP.W[0] = Wq; WP.W[1] = Wk; WP.W[2] = Wg; WP.W[3] = Wv; WP.W[4] = Wo;
        k_build_wstack<<<dim3(32, 32, 5), 256, 0, stream>>>(WP, WST);
    }

    // 1. per-group: rms-split -> QKVG -> attn (O split fused) -> Wo+resid -> rmsnorm2
    for (int gi = 0; gi < 4; ++gi) {
        const size_t tok0 = (size_t)gi * GTOK;
        const float* xg = x + tok0 * DM;
        float* vg = out + tok0 * DM;

        k_rms_split<true><<<GTOK, 256, 0, stream>>>(xg, ns1, Xs);

        ProjPack P;
        P.BT[0] = WST;                   P.bias[0] = bq; P.C[0] = qg;
        P.BT[1] = WST + (size_t)DM * KW; P.bias[1] = bk; P.C[1] = kg;
        P.BT[2] = WST + 2ull * DM * KW;  P.bias[2] = bg; P.C[2] = gg;
        P.BT[3] = WST + 3ull * DM * KW;  P.bias[3] = bv; P.C[3] = vg;
        // grid: (n=8, mat=4, m=64) -> mats adjacent per XCD -> A L2 reuse
        k_gemm_proj<4, false><<<dim3(8, 4, GTOK / 128), 256, 0, stream>>>(Xs, P, nullptr);

        k_scan_kv<<<dim3(64, 32), 256, 0, stream>>>(kg, vg, rope_ct, rope_st);
        k_scan_prefix<<<dim3(16, 32), 256, 0, stream>>>(kg);
        k_zprefix<<<32, 64, 0, stream>>>(vg);
        k_scan_out<<<dim3(64, 32), 256, 0, stream>>>(qg, kg, vg, gg, Xs, rope_ct, rope_st);

        ProjPack P2;
        P2.BT[0] = WST + 4ull * DM * KW; P2.bias[0] = bo; P2.C[0] = vg;  // x2 -> d_out slice
        P2.BT[1] = P2.BT[2] = P2.BT[3] = P2.BT[0];
        P2.bias[1] = P2.bias[2] = P2.bias[3] = bo;
        P2.C[1] = P2.C[2] = P2.C[3] = vg;
        k_gemm_proj<1, true><<<dim3(8, GTOK / 128, 1), 256, 0, stream>>>(Xs, P2, xg);

        k_rmsnorm_stats<<<GTOK, 256, 0, stream>>>(vg, rn2 + tok0, ns2, xn2bf + tok0 * DM);
    }

    // 2. router (fp32) — overwrites rope table region with probs
    k_router<<<NTOK / 4, 256, 0, stream>>>(out, rn2, ns2, rW, rb, route_e, route_g, probs);

    // 3. capacity routing
    k_count<<<256, 256, 0, stream>>>(route_e, bcnt);
    k_scan_blocks<<<1, 64, 0, stream>>>(bcnt, bbase, ctot);
    k_zero<<<(NEXP * CAPE * 2 + 255) / 256, 256, 0, stream>>>(tokslot, NEXP * CAPE * 2);
    k_place<<<256, 256, 0, stream>>>(route_e, route_g, bbase, tokslot, gateslot);

    // 4. aux loss scalar
    k_aux<<<1, 256, 0, stream>>>(probs, ctot, out + (size_t)NTOK * DM);

    // 5. MoE expert weights (bf16, transposed) + expert MLP in groups of {3,3,2}
    k_transpose_bf16<<<dim3(HIDN / 32, DM / 32, NEXP), dim3(32, 8), 0, stream>>>(W1, W1T, DM, HIDN);
    k_transpose_bf16<<<dim3(DM / 32, HIDN / 32, NEXP), dim3(32, 8), 0, stream>>>(W2, W2T, HIDN, DM);

    for (int g = 0; g < 3; ++g) {
        const int e0 = g * 3;
        const int ecnt = (g == 2) ? 2 : 3;
        k_gemm_bf16<0><<<dim3(HIDN / 128, CAPE / 128, ecnt), 256, 0, stream>>>(
            xn2bf, W1T, b1, Hbuf, nullptr, tokslot, gateslot, DM, HIDN, e0);
        k_gemm_bf16<1><<<dim3(CAPE / 128, DM / 128, ecnt), 256, 0, stream>>>(
            Hbuf, W2T, b2, nullptr, out, tokslot, gateslot, HIDN, DM, e0);
    }
}

// Round 13
// 3994.114 us; speedup vs baseline: 1.4420x; 1.0105x over previous
//
#include <hip/hip_runtime.h>
#include <hip/hip_bf16.h>

#define NTOK 32768
#define TSEQ 4096
#define DM   1024
#define NHEAD 16
#define NEXP 8
#define CAPE 5120
#define HIDN 4096
#define GTOK 8192         // tokens per batch-group (2 sequences)
#define KSPL 5120         // split-GEMM logical K (3*1024 + 2*1024)
#define KW   2048         // dedup W-stack row stride (w0 | w1)

#ifndef __has_builtin
#define __has_builtin(x) 0
#endif
#if __has_builtin(__builtin_amdgcn_global_load_lds)
#define HAVE_GLOAD 1
#else
#define HAVE_GLOAD 0
#endif

typedef __attribute__((ext_vector_type(8))) short bf16x8;
typedef __attribute__((ext_vector_type(4))) float f32x4;

#define WAITCNT8() asm volatile("s_waitcnt vmcnt(8)" ::: "memory")
#define WAITCNT4() asm volatile("s_waitcnt vmcnt(4)" ::: "memory")
#define WAITCNT0() asm volatile("s_waitcnt vmcnt(0)" ::: "memory")
#define RAWBAR()   do { asm volatile("" ::: "memory"); __builtin_amdgcn_s_barrier(); asm volatile("" ::: "memory"); } while (0)

// bank-spread chunk permutation for 32-el rows (4 chunks):
#define CHP(r) (((r) >> 1) & 3)

__device__ __forceinline__ float phi_f(float v) { return v > 0.f ? v + 1.f : expf(v); }

__device__ __forceinline__ unsigned short f2bf_bits(float f) {
    __hip_bfloat16 h = __float2bfloat16(f);
    union { __hip_bfloat16 h; unsigned short s; } u;
    u.h = h;
    return u.s;
}
__device__ __forceinline__ float bf_to_f(unsigned short s) {
    unsigned int u = ((unsigned int)s) << 16;
    union { unsigned int u; float f; } w; w.u = u;
    return w.f;
}

__global__ void k_ws_flag(float* out, float v) { if (threadIdx.x == 0) out[0] = v; }

__global__ void k_zero(int* p, int n) {
    int i = blockIdx.x * 256 + threadIdx.x;
    if (i < n) p[i] = 0;
}

// ---------------- rope table ----------------
__global__ __launch_bounds__(256) void k_rope_table(float* __restrict__ ct, float* __restrict__ st)
{
    const int idx = blockIdx.x * 256 + threadIdx.x;
    const int t = idx >> 5, j = idx & 31;
    const float inv = (float)(1.0 / pow(10000.0, (double)j / 32.0));
    float sn, cn;
    sincosf((float)t * inv, &sn, &cn);
    ct[idx] = cn; st[idx] = sn;
}

// ---------------- build dedup W stacks: BT[n][0..1024)=w0, [1024..2048)=w1 ----------------
struct WPack { const float* W[5]; };
__global__ __launch_bounds__(256) void k_build_wstack(WPack P, __hip_bfloat16* __restrict__ BTbase)
{
    __shared__ float t_[32][33];
    const int z = blockIdx.z;
    const float* Wm = P.W[z];
    __hip_bfloat16* BT = BTbase + (size_t)z * DM * KW;
    const int n0 = blockIdx.x * 32, k0 = blockIdx.y * 32;
    const int c = threadIdx.x & 31, r0 = (threadIdx.x >> 5);   // 32 x 8
#pragma unroll
    for (int i = 0; i < 4; ++i) { int r = r0 + i * 8; t_[r][c] = Wm[(size_t)(k0 + r) * DM + n0 + c]; }
    __syncthreads();
#pragma unroll
    for (int i = 0; i < 4; ++i) {
        int r = r0 + i * 8;                       // local n
        float val = t_[c][r];                     // W[k0+c][n0+r]
        unsigned short b0 = f2bf_bits(val);
        float res = val - bf_to_f(b0);
        unsigned short b1 = f2bf_bits(res);
        __hip_bfloat16 h0, h1;
        union { __hip_bfloat16 h; unsigned short s; } u0, u1;
        u0.s = b0; u1.s = b1; h0 = u0.h; h1 = u1.h;
        const size_t nrow = (size_t)(n0 + r) * KW + (k0 + c);
        BT[nrow]        = h0;
        BT[nrow + 1024] = h1;
    }
}

// ---------------- split rows into 3 bf16 planes (rmsnorm-scaled) ----------------
template<bool NORM>
__global__ __launch_bounds__(256) void k_rms_split(const float* __restrict__ X,
                                                   const float* __restrict__ nscale,
                                                   __hip_bfloat16* __restrict__ Xs)
{
    const int row = blockIdx.x;
    const int tid = threadIdx.x;
    const float* xr = X + (size_t)row * DM;
    float4 v = ((const float4*)xr)[tid];
    float r = 1.f;
    if (NORM) {
        float s = v.x * v.x + v.y * v.y + v.z * v.z + v.w * v.w;
        for (int off = 32; off; off >>= 1) s += __shfl_xor(s, off);
        __shared__ float redw[4];
        __shared__ float rbc;
        if ((tid & 63) == 0) redw[tid >> 6] = s;
        __syncthreads();
        if (tid == 0) {
            float tot = redw[0] + redw[1] + redw[2] + redw[3];
            rbc = (float)(1.0 / sqrt((double)tot * (1.0 / 1024.0)));
        }
        __syncthreads();
        r = rbc;
    }
    float c[4] = {v.x, v.y, v.z, v.w};
    if (NORM) {
        float4 ns = ((const float4*)nscale)[tid];
        c[0] *= r * ns.x; c[1] *= r * ns.y; c[2] *= r * ns.z; c[3] *= r * ns.w;
    }
    ushort4 p0, p1, p2;
    unsigned short* q0 = (unsigned short*)&p0;
    unsigned short* q1 = (unsigned short*)&p1;
    unsigned short* q2 = (unsigned short*)&p2;
#pragma unroll
    for (int i = 0; i < 4; ++i) {
        float x = c[i];
        unsigned short b0 = f2bf_bits(x);
        float r1 = x - bf_to_f(b0);
        unsigned short b1 = f2bf_bits(r1);
        float r2 = r1 - bf_to_f(b1);
        unsigned short b2 = f2bf_bits(r2);
        q0[i] = b0; q1[i] = b1; q2[i] = b2;
    }
    __hip_bfloat16* base = Xs + (size_t)row * 3072;
    ((ushort4*)(base))[tid] = p0;
    ((ushort4*)(base + 1024))[tid] = p1;
    ((ushort4*)(base + 2048))[tid] = p2;
}

// ---------------- rmsnorm stats + bf16 normalized rows ----------------
__global__ __launch_bounds__(256) void k_rmsnorm_stats(const float* __restrict__ X,
                                                       float* __restrict__ rn,
                                                       const float* __restrict__ nscale,
                                                       __hip_bfloat16* __restrict__ xbf)
{
    const int row = blockIdx.x;
    const int tid = threadIdx.x;
    const float* xr = X + (size_t)row * DM;
    float4 v = ((const float4*)xr)[tid];
    float s = v.x * v.x + v.y * v.y + v.z * v.z + v.w * v.w;
    for (int off = 32; off; off >>= 1) s += __shfl_xor(s, off);
    __shared__ float redw[4];
    __shared__ float rbc;
    if ((tid & 63) == 0) redw[tid >> 6] = s;
    __syncthreads();
    if (tid == 0) {
        float tot = redw[0] + redw[1] + redw[2] + redw[3];
        float r = (float)(1.0 / sqrt((double)tot * (1.0 / 1024.0)));
        rn[row] = r; rbc = r;
    }
    __syncthreads();
    float r = rbc;
    float4 ns = ((const float4*)nscale)[tid];
    ushort4 o;
    o.x = f2bf_bits(v.x * r * ns.x);
    o.y = f2bf_bits(v.y * r * ns.y);
    o.z = f2bf_bits(v.z * r * ns.z);
    o.w = f2bf_bits(v.w * r * ns.w);
    ((ushort4*)(xbf + (size_t)row * DM))[tid] = o;
}

#if HAVE_GLOAD
__device__ __forceinline__ void gload16(const __hip_bfloat16* g, __hip_bfloat16* l)
{
    __builtin_amdgcn_global_load_lds((const __attribute__((address_space(1))) unsigned int*)g,
                                     (__attribute__((address_space(3))) unsigned int*)l, 16, 0, 0);
}
#endif

// ====== GEMM cores: 3-deep counted-vmcnt pipeline + bank-spread CHP swizzle ======

// ---------------- split-precision projection GEMM ----------------
// NMAT=4 grid: (n=8, mat=4, m=64)  [mat-inner: A L2-hot per XCD]
// NMAT=1 grid: (m=64, n=8)         [m-outer: XCD=m%8, A fetched once per XCD]
struct ProjPack {
    const __hip_bfloat16* BT[4];
    const float* bias[4];
    float* C[4];
};

template<int NMAT, bool RESID>
__global__ __launch_bounds__(256) void k_gemm_proj(const __hip_bfloat16* __restrict__ A,
                                                   ProjPack P,
                                                   const float* __restrict__ resid)
{
    const int z = (NMAT == 4) ? blockIdx.y : 0;
    const __hip_bfloat16* BT = P.BT[z];
    const float* bias = P.bias[z];
    float* C = P.C[z];
    const int m0 = ((NMAT == 4) ? blockIdx.z : blockIdx.x) * 128;
    const int n0 = ((NMAT == 4) ? blockIdx.x : blockIdx.y) * 128;
    const int tid = threadIdx.x;
    __shared__ alignas(16) __hip_bfloat16 As[3][128 * 32];
    __shared__ alignas(16) __hip_bfloat16 Bs[3][128 * 32];

    const int lane = tid & 63, wv = tid >> 6;
    const int lr = lane & 15, lgp = lane >> 4;
    const int wm = (wv >> 1) * 64, wn = (wv & 1) * 64;

    f32x4 acc[4][4];
#pragma unroll
    for (int i = 0; i < 4; ++i)
#pragma unroll
        for (int j = 0; j < 4; ++j) acc[i][j] = (f32x4){0.f, 0.f, 0.f, 0.f};

    int a_off[4], b_off[4];
#pragma unroll
    for (int i = 0; i < 4; ++i) {
        int mrow = wm + i * 16 + lr;
        a_off[i] = mrow * 32 + ((lgp ^ CHP(mrow)) * 8);
        int nrow = wn + i * 16 + lr;
        b_off[i] = nrow * 32 + ((lgp ^ CHP(nrow)) * 8);
    }

    constexpr int T = KSPL / 32;   // 160

#if HAVE_GLOAD
    const int rA0 = wv * 32 + (lane >> 2), rA1 = rA0 + 16;
    const int ch = lane & 3;
    const __hip_bfloat16* srcA0 = A + (size_t)(m0 + rA0) * 3072 + ((ch ^ CHP(rA0)) * 8);
    const __hip_bfloat16* srcA1 = A + (size_t)(m0 + rA1) * 3072 + ((ch ^ CHP(rA1)) * 8);
    const __hip_bfloat16* srcB0 = BT + (size_t)(n0 + rA0) * KW + ((ch ^ CHP(rA0)) * 8);
    const __hip_bfloat16* srcB1 = BT + (size_t)(n0 + rA1) * KW + ((ch ^ CHP(rA1)) * 8);
    const int ldsO0 = (wv * 32) * 32;
    const int ldsO1 = (wv * 32 + 16) * 32;

    auto STAGE = [&](int tile, int buf) {
        const int kb = tile * 32;
        const int acol = (kb < 3072) ? kb : (kb - 3072);
        const int bcol = ((kb < 3072) ? 0 : 1024) + (kb & 1023);
        gload16(srcA0 + acol, &As[buf][ldsO0]);
        gload16(srcA1 + acol, &As[buf][ldsO1]);
        gload16(srcB0 + bcol, &Bs[buf][ldsO0]);
        gload16(srcB1 + bcol, &Bs[buf][ldsO1]);
    };

    STAGE(0, 0); STAGE(1, 1); STAGE(2, 2);
    int buf = 0;
    for (int t = 0; t < T; ++t) {
        if (t <= T - 3)      { WAITCNT8(); }
        else if (t == T - 2) { WAITCNT4(); }
        else                 { WAITCNT0(); }
        RAWBAR();
        bf16x8 af[4], bfr[4];
#pragma unroll
        for (int i = 0; i < 4; ++i) af[i] = *(const bf16x8*)(&As[buf][0] + a_off[i]);
#pragma unroll
        for (int j = 0; j < 4; ++j) bfr[j] = *(const bf16x8*)(&Bs[buf][0] + b_off[j]);
#pragma unroll
        for (int i = 0; i < 4; ++i)
#pragma unroll
            for (int j = 0; j < 4; ++j)
                acc[i][j] = __builtin_amdgcn_mfma_f32_16x16x32_bf16(af[i], bfr[j], acc[i][j], 0, 0, 0);
        if (t + 3 < T) {
            RAWBAR();
            STAGE(t + 3, buf);
        }
        buf = (buf == 2) ? 0 : buf + 1;
    }
#else
    const int ar = tid >> 1, ac0 = (tid & 1) * 2;
    const __hip_bfloat16* Arow = A + (size_t)(m0 + ar) * 3072;
    const __hip_bfloat16* Brow = BT + (size_t)(n0 + ar) * KW;
    for (int t = 0; t < T; ++t) {
        const int kb = t * 32;
        const int acol = (kb < 3072) ? kb : (kb - 3072);
        const int bcol = ((kb < 3072) ? 0 : 1024) + (kb & 1023);
        __syncthreads();
        uint4 av0 = *(const uint4*)(Arow + acol + ac0 * 8);
        uint4 av1 = *(const uint4*)(Arow + acol + ac0 * 8 + 8);
        uint4 bv0 = *(const uint4*)(Brow + bcol + ac0 * 8);
        uint4 bv1 = *(const uint4*)(Brow + bcol + ac0 * 8 + 8);
        *(uint4*)(&As[0][0] + ar * 32 + ((ac0      ^ CHP(ar)) * 8)) = av0;
        *(uint4*)(&As[0][0] + ar * 32 + (((ac0 + 1) ^ CHP(ar)) * 8)) = av1;
        *(uint4*)(&Bs[0][0] + ar * 32 + ((ac0      ^ CHP(ar)) * 8)) = bv0;
        *(uint4*)(&Bs[0][0] + ar * 32 + (((ac0 + 1) ^ CHP(ar)) * 8)) = bv1;
        __syncthreads();
        bf16x8 af[4], bfr[4];
#pragma unroll
        for (int i = 0; i < 4; ++i) af[i] = *(const bf16x8*)(&As[0][0] + a_off[i]);
#pragma unroll
        for (int j = 0; j < 4; ++j) bfr[j] = *(const bf16x8*)(&Bs[0][0] + b_off[j]);
#pragma unroll
        for (int i = 0; i < 4; ++i)
#pragma unroll
            for (int j = 0; j < 4; ++j)
                acc[i][j] = __builtin_amdgcn_mfma_f32_16x16x32_bf16(af[i], bfr[j], acc[i][j], 0, 0, 0);
    }
#endif

#pragma unroll
    for (int i = 0; i < 4; ++i)
#pragma unroll
        for (int j = 0; j < 4; ++j) {
            const int col = n0 + wn + j * 16 + lr;
            const float bval = bias[col];
#pragma unroll
            for (int r = 0; r < 4; ++r) {
                const int rloc = wm + i * 16 + lgp * 4 + r;
                float v = acc[i][j][r] + bval;
                if (RESID) v += resid[(size_t)(m0 + rloc) * DM + col];
                C[(size_t)(m0 + rloc) * DM + col] = v;
            }
        }
}

// ---------------- bf16 MFMA GEMM for experts ----------------
// MODE 0: grid (n, m, e): Hbuf[le][slot] = gelu(xn2bf[tok] @ W1T[e]^T + b1[e])
// MODE 1: grid (m, n, e) [swapped for XCD A-locality]: out[tok] += gate*(Hbuf@W2T^T + b2)
template<int MODE>
__global__ __launch_bounds__(256) void k_gemm_bf16(const __hip_bfloat16* __restrict__ A,
                                                   const __hip_bfloat16* __restrict__ BT,
                                                   const float* __restrict__ bias,
                                                   __hip_bfloat16* __restrict__ Hout,
                                                   float* __restrict__ Fout,
                                                   const int* __restrict__ tokslot,
                                                   const float* __restrict__ gateslot,
                                                   int K, int Nout, int e0)
{
    const int le = blockIdx.z;
    const int e = e0 + le;
    const int m0 = (MODE == 1 ? blockIdx.x : blockIdx.y) * 128;
    const int n0 = (MODE == 1 ? blockIdx.y : blockIdx.x) * 128;
    const int tid = threadIdx.x;
    __shared__ alignas(16) __hip_bfloat16 As[3][128 * 32];
    __shared__ alignas(16) __hip_bfloat16 Bs[3][128 * 32];
    __shared__ int s_tok[128];
    __shared__ float s_gate[128];
    if (tid < 128) {
        s_tok[tid] = tokslot[e * CAPE + m0 + tid];
        s_gate[tid] = gateslot[e * CAPE + m0 + tid];
    }
    __syncthreads();

    const int lane = tid & 63, wv = tid >> 6;
    const int lr = lane & 15, lgp = lane >> 4;
    const int wm = (wv >> 1) * 64, wn = (wv & 1) * 64;

    f32x4 acc[4][4];
#pragma unroll
    for (int i = 0; i < 4; ++i)
#pragma unroll
        for (int j = 0; j < 4; ++j) acc[i][j] = (f32x4){0.f, 0.f, 0.f, 0.f};

    int a_off[4], b_off[4];
#pragma unroll
    for (int i = 0; i < 4; ++i) {
        int mrow = wm + i * 16 + lr;
        a_off[i] = mrow * 32 + ((lgp ^ CHP(mrow)) * 8);
        int nrow = wn + i * 16 + lr;
        b_off[i] = nrow * 32 + ((lgp ^ CHP(nrow)) * 8);
    }

#if HAVE_GLOAD
    const int rA0 = wv * 32 + (lane >> 2), rA1 = rA0 + 16;
    const int ch = lane & 3;
    const __hip_bfloat16 *srcA0, *srcA1;
    if (MODE == 0) {
        srcA0 = A + (size_t)s_tok[rA0] * K + ((ch ^ CHP(rA0)) * 8);
        srcA1 = A + (size_t)s_tok[rA1] * K + ((ch ^ CHP(rA1)) * 8);
    } else {
        srcA0 = A + ((size_t)le * CAPE + m0 + rA0) * K + ((ch ^ CHP(rA0)) * 8);
        srcA1 = A + ((size_t)le * CAPE + m0 + rA1) * K + ((ch ^ CHP(rA1)) * 8);
    }
    const __hip_bfloat16* srcB0 = BT + ((size_t)e * Nout + n0 + rA0) * K + ((ch ^ CHP(rA0)) * 8);
    const __hip_bfloat16* srcB1 = BT + ((size_t)e * Nout + n0 + rA1) * K + ((ch ^ CHP(rA1)) * 8);
    const int ldsO0 = (wv * 32) * 32;
    const int ldsO1 = (wv * 32 + 16) * 32;

    auto STAGE = [&](int tile, int buf) {
        const int kb = tile * 32;
        gload16(srcA0 + kb, &As[buf][ldsO0]);
        gload16(srcA1 + kb, &As[buf][ldsO1]);
        gload16(srcB0 + kb, &Bs[buf][ldsO0]);
        gload16(srcB1 + kb, &Bs[buf][ldsO1]);
    };

    const int T = K / 32;
    STAGE(0, 0); STAGE(1, 1); STAGE(2, 2);
    int buf = 0;
    for (int t = 0; t < T; ++t) {
        if (t <= T - 3)      { WAITCNT8(); }
        else if (t == T - 2) { WAITCNT4(); }
        else                 { WAITCNT0(); }
        RAWBAR();
        bf16x8 af[4], bfr[4];
#pragma unroll
        for (int i = 0; i < 4; ++i) af[i] = *(const bf16x8*)(&As[buf][0] + a_off[i]);
#pragma unroll
        for (int j = 0; j < 4; ++j) bfr[j] = *(const bf16x8*)(&Bs[buf][0] + b_off[j]);
#pragma unroll
        for (int i = 0; i < 4; ++i)
#pragma unroll
            for (int j = 0; j < 4; ++j)
                acc[i][j] = __builtin_amdgcn_mfma_f32_16x16x32_bf16(af[i], bfr[j], acc[i][j], 0, 0, 0);
        if (t + 3 < T) {
            RAWBAR();
            STAGE(t + 3, buf);
        }
        buf = (buf == 2) ? 0 : buf + 1;
    }
#else
    const int ar = tid >> 1, ac0 = (tid & 1) * 2;
    const __hip_bfloat16* Arow;
    if (MODE == 0) Arow = A + (size_t)s_tok[ar] * K;
    else           Arow = A + ((size_t)le * CAPE + m0 + ar) * K;
    const __hip_bfloat16* Brow = BT + ((size_t)e * Nout + n0 + ar) * K;
    for (int k0 = 0; k0 < K; k0 += 32) {
        __syncthreads();
        uint4 av0 = *(const uint4*)(Arow + k0 + ac0 * 8);
        uint4 av1 = *(const uint4*)(Arow + k0 + ac0 * 8 + 8);
        uint4 bv0 = *(const uint4*)(Brow + k0 + ac0 * 8);
        uint4 bv1 = *(const uint4*)(Brow + k0 + ac0 * 8 + 8);
        *(uint4*)(&As[0][0] + ar * 32 + ((ac0      ^ CHP(ar)) * 8)) = av0;
        *(uint4*)(&As[0][0] + ar * 32 + (((ac0 + 1) ^ CHP(ar)) * 8)) = av1;
        *(uint4*)(&Bs[0][0] + ar * 32 + ((ac0      ^ CHP(ar)) * 8)) = bv0;
        *(uint4*)(&Bs[0][0] + ar * 32 + (((ac0 + 1) ^ CHP(ar)) * 8)) = bv1;
        __syncthreads();
        bf16x8 af[4], bfr[4];
#pragma unroll
        for (int i = 0; i < 4; ++i) af[i] = *(const bf16x8*)(&As[0][0] + a_off[i]);
#pragma unroll
        for (int j = 0; j < 4; ++j) bfr[j] = *(const bf16x8*)(&Bs[0][0] + b_off[j]);
#pragma unroll
        for (int i = 0; i < 4; ++i)
#pragma unroll
            for (int j = 0; j < 4; ++j)
                acc[i][j] = __builtin_amdgcn_mfma_f32_16x16x32_bf16(af[i], bfr[j], acc[i][j], 0, 0, 0);
    }
#endif

#pragma unroll
    for (int i = 0; i < 4; ++i)
#pragma unroll
        for (int j = 0; j < 4; ++j) {
            const int col = n0 + wn + j * 16 + lr;
            const float bval = bias[(size_t)e * Nout + col];
#pragma unroll
            for (int r = 0; r < 4; ++r) {
                const int rloc = wm + i * 16 + lgp * 4 + r;
                float v = acc[i][j][r] + bval;
                if (MODE == 0) {
                    v = 0.5f * v * (1.f + erff(v * 0.70710678118654752f));
                    Hout[((size_t)le * CAPE + m0 + rloc) * Nout + col] = __float2bfloat16(v);
                } else {
                    const float g = s_gate[rloc];
                    if (g != 0.f) atomicAdd(&Fout[(size_t)s_tok[rloc] * DM + col], v * g);
                }
            }
        }
}

// ---------------- attention pass 1: S_c = K_c^T V_c (in place over K), Z_c into V row0 ----------------
__global__ __launch_bounds__(256) void k_scan_kv(float* KS, float* Vz,
                                                 const float* __restrict__ ct,
                                                 const float* __restrict__ st)
{
    const int c = blockIdx.x, bh = blockIdx.y;
    const int h = bh & 15, b = bh >> 4;
    const int tid = threadIdx.x;
    __shared__ float ks[64][68];
    __shared__ float vs[64][68];
    const size_t rowbase = ((size_t)b * TSEQ + c * 64) * DM + h * 64;
#pragma unroll
    for (int p = 0; p < 8; ++p) {
        int idx = p * 256 + tid;
        int t = idx >> 5, j = idx & 31;
        const size_t base = rowbase + (size_t)t * DM + j;
        float cn = ct[(c * 64 + t) * 32 + j];
        float sn = st[(c * 64 + t) * 32 + j];
        float k1 = KS[base], k2 = KS[base + 32];
        ks[t][j]      = phi_f(k1 * cn - k2 * sn);
        ks[t][j + 32] = phi_f(k1 * sn + k2 * cn);
    }
#pragma unroll
    for (int p = 0; p < 4; ++p) {
        int idx = p * 256 + tid;
        int t = idx >> 4, e4 = (idx & 15) * 4;
        *(float4*)&vs[t][e4] = *(const float4*)&Vz[rowbase + (size_t)t * DM + e4];
    }
    __syncthreads();
    const int e = tid & 63, dg = tid >> 6;
    float acc[16] = {};
    for (int t = 0; t < 64; ++t) {
        float vv = vs[t][e];
#pragma unroll
        for (int qq = 0; qq < 4; ++qq) {
            float4 kq = *(const float4*)&ks[t][dg * 16 + qq * 4];
            acc[qq * 4 + 0] = fmaf(kq.x, vv, acc[qq * 4 + 0]);
            acc[qq * 4 + 1] = fmaf(kq.y, vv, acc[qq * 4 + 1]);
            acc[qq * 4 + 2] = fmaf(kq.z, vv, acc[qq * 4 + 2]);
            acc[qq * 4 + 3] = fmaf(kq.w, vv, acc[qq * 4 + 3]);
        }
    }
#pragma unroll
    for (int i = 0; i < 16; ++i) {
        int d = dg * 16 + i;
        KS[rowbase + (size_t)d * DM + e] = acc[i];
    }
    if (tid < 64) {
        float z = 0.f;
        for (int t = 0; t < 64; ++t) z += ks[t][tid];
        Vz[rowbase + tid] = z;
    }
}

// ---------------- attention pass 2: inclusive prefix over chunks ----------------
__global__ __launch_bounds__(256) void k_scan_prefix(float* S)
{
    const int sg = blockIdx.x, bh = blockIdx.y;
    const int h = bh & 15, b = bh >> 4;
    const int idx = sg * 256 + threadIdx.x;
    const int d = idx >> 6, e = idx & 63;
    const size_t base = (size_t)b * TSEQ * DM + h * 64 + (size_t)d * DM + e;
    float acc = 0.f;
    for (int c = 0; c < 64; ++c) {
        size_t p = base + (size_t)c * 64 * DM;
        acc += S[p];
        S[p] = acc;
    }
}

__global__ void k_zprefix(float* Vz)
{
    const int bh = blockIdx.x;
    const int h = bh & 15, b = bh >> 4;
    const int d = threadIdx.x;
    const size_t base = (size_t)b * TSEQ * DM + h * 64 + d;
    float acc = 0.f;
    for (int c = 0; c < 64; ++c) {
        size_t p = base + (size_t)c * 64 * DM;
        acc += Vz[p];
        Vz[p] = acc;
    }
}

// ---------------- attention pass 3: O = g*(q@S)/(q.Z+eps), split to 3 bf16 planes in Xs ----------------
__global__ __launch_bounds__(256) void k_scan_out(const float* __restrict__ Q,
                                                  const float* __restrict__ S,
                                                  const float* __restrict__ Zv,
                                                  const float* __restrict__ G,
                                                  __hip_bfloat16* __restrict__ Xs,
                                                  const float* __restrict__ ct,
                                                  const float* __restrict__ st)
{
    const int c = blockIdx.x, bh = blockIdx.y;
    const int h = bh & 15, b = bh >> 4;
    const int tid = threadIdx.x;
    __shared__ float qs[64][69];
    __shared__ float Ss[64][68];
    __shared__ float den[64], Zl[64];
    const size_t rowbase = ((size_t)b * TSEQ + c * 64) * DM + h * 64;
#pragma unroll
    for (int p = 0; p < 8; ++p) {
        int idx = p * 256 + tid;
        int t = idx >> 5, j = idx & 31;
        const size_t base = rowbase + (size_t)t * DM + j;
        float cn = ct[(c * 64 + t) * 32 + j];
        float sn = st[(c * 64 + t) * 32 + j];
        float q1 = Q[base], q2 = Q[base + 32];
        qs[t][j]      = phi_f(q1 * cn - q2 * sn);
        qs[t][j + 32] = phi_f(q1 * sn + q2 * cn);
    }
#pragma unroll
    for (int p = 0; p < 4; ++p) {
        int idx = p * 256 + tid;
        int d = idx >> 4, e4 = (idx & 15) * 4;
        *(float4*)&Ss[d][e4] = *(const float4*)&S[rowbase + (size_t)d * DM + e4];
    }
    const int e = tid & 63, tg = tid >> 6;
    float greg[16];
#pragma unroll
    for (int i = 0; i < 16; ++i)
        greg[i] = G[rowbase + (size_t)(tg * 16 + i) * DM + e];
    if (tid < 64) Zl[tid] = Zv[rowbase + tid];
    __syncthreads();
    if (tid < 64) {
        float dd = 0.f;
        for (int d = 0; d < 64; ++d) dd += qs[tid][d] * Zl[d];
        den[tid] = dd + 1e-6f;
    }
    __syncthreads();
    float acc[16] = {};
    for (int d = 0; d < 64; ++d) {
        float sv = Ss[d][e];
#pragma unroll
        for (int i = 0; i < 16; ++i)
            acc[i] = fmaf(qs[tg * 16 + i][d], sv, acc[i]);
    }
    unsigned short* Xu = (unsigned short*)Xs;
#pragma unroll
    for (int i = 0; i < 16; ++i) {
        int t = tg * 16 + i;
        float g = 1.f / (1.f + expf(-greg[i]));
        float o = g * acc[i] / den[t];
        unsigned short b0 = f2bf_bits(o);
        float r1 = o - bf_to_f(b0);
        unsigned short b1 = f2bf_bits(r1);
        float r2 = r1 - bf_to_f(b1);
        unsigned short b2 = f2bf_bits(r2);
        const size_t xb = (size_t)(b * TSEQ + c * 64 + t) * 3072 + h * 64 + e;
        Xu[xb] = b0;
        Xu[xb + 1024] = b1;
        Xu[xb + 2048] = b2;
    }
}

// ---------------- router ----------------
__global__ __launch_bounds__(256) void k_router(const float* __restrict__ X2,
                                                const float* __restrict__ rn2,
                                                const float* __restrict__ ns2,
                                                const float* __restrict__ rW,
                                                const float* __restrict__ rb,
                                                int* __restrict__ route_e,
                                                float* __restrict__ route_g,
                                                float* __restrict__ probs)
{
    const int tok = blockIdx.x * 4 + (threadIdx.x >> 6);
    const int lane = threadIdx.x & 63;
    const float* xr = X2 + (size_t)tok * DM;
    const float rn = rn2[tok];
    float lg[8] = {};
    for (int d = lane; d < DM; d += 64) {
        float xv = xr[d] * rn * ns2[d];
        const float4* w4 = (const float4*)(rW + (size_t)d * 8);
        float4 w0 = w4[0], w1 = w4[1];
        lg[0] += xv * w0.x; lg[1] += xv * w0.y; lg[2] += xv * w0.z; lg[3] += xv * w0.w;
        lg[4] += xv * w1.x; lg[5] += xv * w1.y; lg[6] += xv * w1.z; lg[7] += xv * w1.w;
    }
#pragma unroll
    for (int e = 0; e < 8; ++e)
        for (int off = 32; off; off >>= 1) lg[e] += __shfl_xor(lg[e], off);
    if (lane == 0) {
        float pe[8]; float mx = -1e30f, s = 0.f;
#pragma unroll
        for (int e = 0; e < 8; ++e) { lg[e] += rb[e]; mx = fmaxf(mx, lg[e]); }
#pragma unroll
        for (int e = 0; e < 8; ++e) { pe[e] = expf(lg[e] - mx); s += pe[e]; }
#pragma unroll
        for (int e = 0; e < 8; ++e) { pe[e] /= s; probs[(size_t)tok * 8 + e] = pe[e]; }
        int i1 = 0; float p1 = pe[0];
#pragma unroll
        for (int e = 1; e < 8; ++e) if (pe[e] > p1) { p1 = pe[e]; i1 = e; }
        int i2 = -1; float p2 = -1.f;
#pragma unroll
        for (int e = 0; e < 8; ++e) if (e != i1 && pe[e] > p2) { p2 = pe[e]; i2 = e; }
        const float gsum = p1 + p2;
        route_e[tok * 2] = i1; route_e[tok * 2 + 1] = i2;
        route_g[tok * 2] = p1 / gsum; route_g[tok * 2 + 1] = p2 / gsum;
    }
}

// ---------------- capacity routing ----------------
__global__ __launch_bounds__(256) void k_count(const int* __restrict__ route_e, int* __restrict__ bcnt)
{
    __shared__ int c[8];
    const int tid = threadIdx.x;
    if (tid < 8) c[tid] = 0;
    __syncthreads();
    atomicAdd(&c[route_e[blockIdx.x * 256 + tid]], 1);
    __syncthreads();
    if (tid < 8) bcnt[blockIdx.x * 8 + tid] = c[tid];
}

__global__ void k_scan_blocks(const int* __restrict__ bcnt, int* __restrict__ bbase, int* __restrict__ ctot)
{
    const int e = threadIdx.x;
    if (e < 8) {
        int run = 0;
        for (int b = 0; b < 256; ++b) { bbase[b * 8 + e] = run; run += bcnt[b * 8 + e]; }
        ctot[e] = run;
    }
}

__global__ __launch_bounds__(256) void k_place(const int* __restrict__ route_e,
                                               const float* __restrict__ route_g,
                                               const int* __restrict__ bbase,
                                               int* __restrict__ tokslot,
                                               float* __restrict__ gateslot)
{
    const int tid = threadIdx.x;
    const int a = blockIdx.x * 256 + tid;
    const int e = route_e[a];
    __shared__ int se[256];
    se[tid] = e;
    __syncthreads();
    int rank = 0;
    for (int j = 0; j < tid; ++j) rank += (se[j] == e) ? 1 : 0;
    const int slot = bbase[blockIdx.x * 8 + e] + rank;
    if (slot < CAPE) {
        tokslot[e * CAPE + slot] = a >> 1;
        gateslot[e * CAPE + slot] = route_g[a];
    }
}

// ---------------- aux loss ----------------
__global__ __launch_bounds__(256) void k_aux(const float* __restrict__ probs,
                                             const int* __restrict__ ctot,
                                             float* __restrict__ out_aux)
{
    const int tid = threadIdx.x;
    float part[8] = {};
    for (int i = tid; i < NTOK; i += 256) {
        const float* p = probs + (size_t)i * 8;
#pragma unroll
        for (int e = 0; e < 8; ++e) part[e] += p[e];
    }
    __shared__ float red[256];
    __shared__ float accs[8];
    for (int e = 0; e < 8; ++e) {
        red[tid] = part[e];
        __syncthreads();
        for (int s = 128; s; s >>= 1) { if (tid < s) red[tid] += red[tid + s]; __syncthreads(); }
        if (tid == 0) accs[e] = red[0];
        __syncthreads();
    }
    if (tid == 0) {
        float isum = 0.f, lsum = 0.f, l[8];
        for (int e = 0; e < 8; ++e) isum += accs[e];
        for (int e = 0; e < 8; ++e) { l[e] = fminf((float)ctot[e], (float)CAPE); lsum += l[e]; }
        float aux = 0.f;
        for (int e = 0; e < 8; ++e) aux += (accs[e] / isum) * (l[e] / lsum);
        out_aux[0] = aux * 64.f;
    }
}

// ---------------- f32 -> bf16 transpose (per expert z) ----------------
__global__ void k_transpose_bf16(const float* __restrict__ src, __hip_bfloat16* __restrict__ dst,
                                 int K_, int N_)
{
    __shared__ float t_[32][33];
    const int z = blockIdx.z;
    const float* s = src + (size_t)z * K_ * N_;
    __hip_bfloat16* d = dst + (size_t)z * K_ * N_;
    const int n0 = blockIdx.x * 32, k0 = blockIdx.y * 32;
    const int c = threadIdx.x, r0 = threadIdx.y;
#pragma unroll
    for (int i = 0; i < 4; ++i) { int r = r0 + i * 8; t_[r][c] = s[(size_t)(k0 + r) * N_ + n0 + c]; }
    __syncthreads();
#pragma unroll
    for (int i = 0; i < 4; ++i) { int r = r0 + i * 8; d[(size_t)(n0 + r) * K_ + k0 + c] = __float2bfloat16(t_[c][r]); }
}

extern "C" void kernel_launch(void* const* d_in, const int* in_sizes, int n_in,
                              void* d_out, int out_size, void* d_ws, size_t ws_size,
                              hipStream_t stream)
{
    (void)in_sizes; (void)n_in; (void)out_size;
    const float* x   = (const float*)d_in[0];
    const float* ns1 = (const float*)d_in[1];
    const float* ns2 = (const float*)d_in[2];
    const float* Wq  = (const float*)d_in[3];
    const float* bq  = (const float*)d_in[4];
    const float* Wk  = (const float*)d_in[5];
    const float* bk  = (const float*)d_in[6];
    const float* Wv  = (const float*)d_in[7];
    const float* bv  = (const float*)d_in[8];
    const float* Wg  = (const float*)d_in[9];
    const float* bg  = (const float*)d_in[10];
    const float* Wo  = (const float*)d_in[11];
    const float* bo  = (const float*)d_in[12];
    const float* rW  = (const float*)d_in[13];
    const float* rb  = (const float*)d_in[14];
    const float* W1  = (const float*)d_in[15];
    const float* b1  = (const float*)d_in[16];
    const float* W2  = (const float*)d_in[17];
    const float* b2  = (const float*)d_in[18];
    float* out = (float*)d_out;
    char* wsb = (char*)d_ws;

    constexpr size_t MiB = 1024ull * 1024ull;
    constexpr size_t R = (size_t)NTOK * DM * 4;        // 128 MiB
    constexpr size_t TAIL = 3 * R;
    constexpr size_t OFF_RN1  = TAIL;
    constexpr size_t OFF_RN2  = OFF_RN1 + (size_t)NTOK * 4;
    constexpr size_t OFF_PROB = OFF_RN2 + (size_t)NTOK * 4;
    constexpr size_t OFF_RE   = OFF_PROB + (size_t)NTOK * 8 * 4;
    constexpr size_t OFF_RG   = OFF_RE + (size_t)NTOK * 2 * 4;
    constexpr size_t OFF_BCNT = OFF_RG + (size_t)NTOK * 2 * 4;
    constexpr size_t OFF_BBASE= OFF_BCNT + 256 * 8 * 4;
    constexpr size_t OFF_CTOT = OFF_BBASE + 256 * 8 * 4;
    constexpr size_t OFF_TOK  = OFF_CTOT + 4096;
    constexpr size_t OFF_GATE = OFF_TOK + (size_t)NEXP * CAPE * 4;
    constexpr size_t REQUIRED = OFF_GATE + (size_t)NEXP * CAPE * 4;

    if (ws_size < REQUIRED) {
        k_ws_flag<<<1, 64, 0, stream>>>(out, (float)(ws_size >> 20));
        return;
    }

    // main region layout (within [0, 3R))
    __hip_bfloat16* xn2bf = (__hip_bfloat16*)(wsb);                 // 64 MiB persistent
    __hip_bfloat16* WST   = (__hip_bfloat16*)(wsb + 64 * MiB);      // 5 x 4 MiB = 20 MiB (dedup)
    __hip_bfloat16* Xs    = (__hip_bfloat16*)(wsb + 114 * MiB);     // 48 MiB per-group
    float* qg = (float*)(wsb + 162 * MiB);                          // 32 MiB
    float* kg = (float*)(wsb + 194 * MiB);                          // 32 MiB
    float* gg = (float*)(wsb + 226 * MiB);                          // 32 MiB (ends 258)
    __hip_bfloat16* W1T  = (__hip_bfloat16*)(wsb + 64 * MiB);       // 64 MiB (after WST dead)
    __hip_bfloat16* W2T  = (__hip_bfloat16*)(wsb + 128 * MiB);      // 64 MiB
    __hip_bfloat16* Hbuf = (__hip_bfloat16*)(wsb + 192 * MiB);      // 120 MiB (ends 312)

    float* rn2 = (float*)(wsb + OFF_RN2);
    float* probs = (float*)(wsb + OFF_PROB);
    float* rope_ct = (float*)(wsb + OFF_PROB);
    float* rope_st = (float*)(wsb + OFF_PROB + (size_t)TSEQ * 32 * 4);
    int*   route_e = (int*)(wsb + OFF_RE);
    float* route_g = (float*)(wsb + OFF_RG);
    int*   bcnt  = (int*)(wsb + OFF_BCNT);
    int*   bbase = (int*)(wsb + OFF_BBASE);
    int*   ctot  = (int*)(wsb + OFF_CTOT);
    int*   tokslot  = (int*)(wsb + OFF_TOK);
    float* gateslot = (float*)(wsb + OFF_GATE);

    // 0. rope table + dedup weight stacks (w0|w1)
    k_rope_table<<<512, 256, 0, stream>>>(rope_ct, rope_st);
    {
        WPack WP; WP.W[0] = Wq; WP.W[1] = Wk; WP.W[2] = Wg; WP.W[3] = Wv; WP.W[4] = Wo;
        k_build_wstack<<<dim3(32, 32, 5), 256, 0, stream>>>(WP, WST);
    }

    // 1. per-group: rms-split -> QKVG -> attn (O split fused) -> Wo+resid -> rmsnorm2
    for (int gi = 0; gi < 4; ++gi) {
        const size_t tok0 = (size_t)gi * GTOK;
        const float* xg = x + tok0 * DM;
        float* vg = out + tok0 * DM;

        k_rms_split<true><<<GTOK, 256, 0, stream>>>(xg, ns1, Xs);

        ProjPack P;
        P.BT[0] = WST;                   P.bias[0] = bq; P.C[0] = qg;
        P.BT[1] = WST + (size_t)DM * KW; P.bias[1] = bk; P.C[1] = kg;
        P.BT[2] = WST + 2ull * DM * KW;  P.bias[2] = bg; P.C[2] = gg;
        P.BT[3] = WST + 3ull * DM * KW;  P.bias[3] = bv; P.C[3] = vg;
        // grid: (n=8, mat=4, m=64) -> mats adjacent per XCD -> A L2 reuse
        k_gemm_proj<4, false><<<dim3(8, 4, GTOK / 128), 256, 0, stream>>>(Xs, P, nullptr);

        k_scan_kv<<<dim3(64, 32), 256, 0, stream>>>(kg, vg, rope_ct, rope_st);
        k_scan_prefix<<<dim3(16, 32), 256, 0, stream>>>(kg);
        k_zprefix<<<32, 64, 0, stream>>>(vg);
        k_scan_out<<<dim3(64, 32), 256, 0, stream>>>(qg, kg, vg, gg, Xs, rope_ct, rope_st);

        ProjPack P2;
        P2.BT[0] = WST + 4ull * DM * KW; P2.bias[0] = bo; P2.C[0] = vg;  // x2 -> d_out slice
        P2.BT[1] = P2.BT[2] = P2.BT[3] = P2.BT[0];
        P2.bias[1] = P2.bias[2] = P2.bias[3] = bo;
        P2.C[1] = P2.C[2] = P2.C[3] = vg;
        // grid: (m=64, n=8) -> XCD = m%8 -> A fetched once per XCD, B L2-resident
        k_gemm_proj<1, true><<<dim3(GTOK / 128, 8, 1), 256, 0, stream>>>(Xs, P2, xg);

        k_rmsnorm_stats<<<GTOK, 256, 0, stream>>>(vg, rn2 + tok0, ns2, xn2bf + tok0 * DM);
    }

    // 2. router (fp32) — overwrites rope table region with probs
    k_router<<<NTOK / 4, 256, 0, stream>>>(out, rn2, ns2, rW, rb, route_e, route_g, probs);

    // 3. capacity routing
    k_count<<<256, 256, 0, stream>>>(route_e, bcnt);
    k_scan_blocks<<<1, 64, 0, stream>>>(bcnt, bbase, ctot);
    k_zero<<<(NEXP * CAPE * 2 + 255) / 256, 256, 0, stream>>>(tokslot, NEXP * CAPE * 2);
    k_place<<<256, 256, 0, stream>>>(route_e, route_g, bbase, tokslot, gateslot);

    // 4. aux loss scalar
    k_aux<<<1, 256, 0, stream>>>(probs, ctot, out + (size_t)NTOK * DM);

    // 5. MoE expert weights (bf16, transposed) + expert MLP in groups of {3,3,2}
    k_transpose_bf16<<<dim3(HIDN / 32, DM / 32, NEXP), dim3(32, 8), 0, stream>>>(W1, W1T, DM, HIDN);
    k_transpose_bf16<<<dim3(DM / 32, HIDN / 32, NEXP), dim3(32, 8), 0, stream>>>(W2, W2T, HIDN, DM);

    for (int g = 0; g < 3; ++g) {
        const int e0 = g * 3;
        const int ecnt = (g == 2) ? 2 : 3;
        k_gemm_bf16<0><<<dim3(HIDN / 128, CAPE / 128, ecnt), 256, 0, stream>>>(
            xn2bf, W1T, b1, Hbuf, nullptr, tokslot, gateslot, DM, HIDN, e0);
        k_gemm_bf16<1><<<dim3(CAPE / 128, DM / 128, ecnt), 256, 0, stream>>>(
            Hbuf, W2T, b2, nullptr, out, tokslot, gateslot, HIDN, DM, e0);
    }
}